// Round 11
// baseline (351.324 us; speedup 1.0000x reference)
//
#include <hip/hip_runtime.h>
#include <cstdint>

#define NB 8
#define NC 96
#define NC2 192
#define NPT 3136    // 56*56
#define NK 9
#define NSPL 16     // j-splits
#define NLIST 32    // lists per row: 16 j-splits x 2 lane-halves
#define NDEP 9      // per-lane list depth (>= NK for superset guarantee)
#define NCAND 16    // pooled candidate count per row
#define NROWS (NB * NPT)
#define RST 104     // fnT row stride (96 fn + sq at [96] + pad)
#define UV_WSTR 292 // k_uv LDS per-ob stride
#define OUT_WSTR 100// k_out LDS cc stride
#define FT_WSTR 76  // k_feat LDS per-ob stride
static constexpr float BN_EPS = 1e-5f;
typedef unsigned long long u64;
typedef float f32x16 __attribute__((ext_vector_type(16)));
typedef short short8 __attribute__((ext_vector_type(8)));

__device__ inline unsigned short f32_to_bf16_rne(float x) {
  unsigned u = __float_as_uint(x);
  unsigned r = (u + 0x7FFFu + ((u >> 16) & 1u)) >> 16;
  return (unsigned short)r;
}

__device__ inline unsigned score_to_key_exact(float s) {
  unsigned u = __float_as_uint(s);
  u ^= 0x80000000u | (unsigned)((int)u >> 31);  // monotone increasing map
  return ~u;                                    // descending score = ascending dist
}

// ---------------- K1: fold BN into weights, build fused weight layouts ----------------
// W1s: swizzled [ch8][ob16][cc12][oo6] for k_feat staging.
__global__ void k_fuse(const float* __restrict__ W1, const float* __restrict__ b1,
                       const float* __restrict__ g1, const float* __restrict__ be1,
                       const float* __restrict__ m1, const float* __restrict__ v1,
                       const float* __restrict__ Wg,
                       const float* __restrict__ W2, const float* __restrict__ b2,
                       const float* __restrict__ g2, const float* __restrict__ be2,
                       const float* __restrict__ m2, const float* __restrict__ v2,
                       float* __restrict__ W1s, float* __restrict__ b1f,
                       float* __restrict__ Wuv,
                       float* __restrict__ W2f, float* __restrict__ b2f) {
  int t = blockIdx.x * blockDim.x + threadIdx.x;
  int nth = gridDim.x * blockDim.x;
  for (int i = t; i < NC * NC; i += nth) {
    int ch = i / 1152, r = i % 1152;
    int ob = r / 72, r2 = r % 72;
    int cc = r2 / 6, oo = r2 % 6;
    int c = ch * 12 + cc, o = ob * 6 + oo;
    float inv = g1[o] / sqrtf(v1[o] + BN_EPS);
    W1s[i] = W1[o * NC + c] * inv;
  }
  for (int o = t; o < NC; o += nth) {
    float inv = g1[o] / sqrtf(v1[o] + BN_EPS);
    b1f[o] = b1[o] * inv + be1[o] - m1[o] * inv;
    float inv2v = g2[o] / sqrtf(v2[o] + BN_EPS);
    b2f[o] = b2[o] * inv2v + be2[o] - m2[o] * inv2v;
  }
  for (int i = t; i < NC * (2 * NC2); i += nth) {
    int c = i / (2 * NC2), o4 = i % (2 * NC2);
    float val;
    if (o4 < NC2) val = Wg[o4 * NC2 + c] - Wg[o4 * NC2 + NC + c];
    else          val = Wg[(o4 - NC2) * NC2 + NC + c];
    Wuv[i] = val;
  }
  for (int i = t; i < NC2 * NC; i += nth) {
    int c = i / NC, o = i % NC;
    float inv = g2[o] / sqrtf(v2[o] + BN_EPS);
    W2f[i] = W2[o * NC2 + c] * inv;
  }
}

// ------- K2: feat = BN(W1 x + b1); fnT = f32 fn rows (+sq); hiT/loT = bf16 split -------
__global__ __launch_bounds__(64, 4) void k_feat(const float* __restrict__ x,
                                                const float* __restrict__ W1s,
                                                const float* __restrict__ b1f,
                                                float* __restrict__ feat,
                                                float* __restrict__ fnT,
                                                unsigned short* __restrict__ hiT,
                                                unsigned short* __restrict__ loT) {
  int bid = blockIdx.x;      // 1568
  int b = bid & 7;
  int ng = bid >> 3;         // 0..195
  int n0 = ng * 16;
  int lane = threadIdx.x;
  int ob = lane & 15, nq = lane >> 4;

  __shared__ float w_lds[16 * FT_WSTR];  // 4864 B
  __shared__ float f_lds[12 * 16];       // 768 B

  const float* xb = x + (size_t)b * NC * NPT;
  float acc[4][6];
#pragma unroll
  for (int oo = 0; oo < 6; ++oo) {
    float bv = b1f[ob * 6 + oo];
#pragma unroll
    for (int q = 0; q < 4; ++q) acc[q][oo] = bv;
  }

  for (int ch = 0; ch < 8; ++ch) {
    __syncthreads();
    {
      const float* wsrc = W1s + ch * 1152;
#pragma unroll
      for (int it = 0; it < 5; ++it) {
        int i = it * 256 + lane * 4;
        if (it < 4 || lane < 32) {
          float4 v = *(const float4*)&wsrc[i];
          *(float4*)&w_lds[(i / 72) * FT_WSTR + (i % 72)] = v;
        }
      }
#pragma unroll
      for (int it = 0; it < 3; ++it) {
        int i = it * 64 + lane;
        f_lds[i] = xb[(size_t)(ch * 12 + (i >> 4)) * NPT + n0 + (i & 15)];
      }
    }
    __syncthreads();
#pragma unroll
    for (int cc = 0; cc < 12; ++cc) {
      float4 a = *(const float4*)&f_lds[cc * 16 + nq * 4];
      const float* wp = &w_lds[ob * FT_WSTR + cc * 6];
      float2 w01 = *(const float2*)&wp[0];
      float2 w23 = *(const float2*)&wp[2];
      float2 w45 = *(const float2*)&wp[4];
      float w[6] = {w01.x, w01.y, w23.x, w23.y, w45.x, w45.y};
#pragma unroll
      for (int oo = 0; oo < 6; ++oo) {
        acc[0][oo] = fmaf(w[oo], a.x, acc[0][oo]);
        acc[1][oo] = fmaf(w[oo], a.y, acc[1][oo]);
        acc[2][oo] = fmaf(w[oo], a.z, acc[2][oo]);
        acc[3][oo] = fmaf(w[oo], a.w, acc[3][oo]);
      }
    }
  }

  float sq[4];
#pragma unroll
  for (int q = 0; q < 4; ++q) {
    float s = 0.f;
#pragma unroll
    for (int oo = 0; oo < 6; ++oo) s += acc[q][oo] * acc[q][oo];
    sq[q] = s;
  }
#pragma unroll
  for (int m = 1; m < 16; m <<= 1) {
#pragma unroll
    for (int q = 0; q < 4; ++q) sq[q] += __shfl_xor(sq[q], m);
  }

  float* fb = feat + (size_t)b * NC * NPT;
  float vnn[4][6];
  float sqn[4];
#pragma unroll
  for (int q = 0; q < 4; ++q) {
    float den = fmaxf(sqrtf(sq[q]), 1e-12f);
    float s = 0.f;
#pragma unroll
    for (int oo = 0; oo < 6; ++oo) {
      float v = acc[q][oo] / den;
      vnn[q][oo] = v;
      s += v * v;
    }
    sqn[q] = s;
  }
#pragma unroll
  for (int m = 1; m < 16; m <<= 1) {
#pragma unroll
    for (int q = 0; q < 4; ++q) sqn[q] += __shfl_xor(sqn[q], m);
  }

#pragma unroll
  for (int q = 0; q < 4; ++q) {
    int n = n0 + nq * 4 + q;
#pragma unroll
    for (int oo = 0; oo < 6; ++oo)
      fb[(size_t)(ob * 6 + oo) * NPT + n] = acc[q][oo];
    float* fr = fnT + ((size_t)b * NPT + n) * RST;
#pragma unroll
    for (int oo = 0; oo < 6; ++oo) fr[ob * 6 + oo] = vnn[q][oo];
    if (ob == 0) fr[96] = sqn[q];
    unsigned short* hr = hiT + ((size_t)b * NPT + n) * NC + ob * 6;
    unsigned short* lr = loT + ((size_t)b * NPT + n) * NC + ob * 6;
#pragma unroll
    for (int p2 = 0; p2 < 3; ++p2) {
      float v0 = vnn[q][p2 * 2], v1 = vnn[q][p2 * 2 + 1];
      unsigned short h0 = f32_to_bf16_rne(v0);
      unsigned short h1 = f32_to_bf16_rne(v1);
      float hv0 = __uint_as_float(((unsigned)h0) << 16);
      float hv1 = __uint_as_float(((unsigned)h1) << 16);
      unsigned short l0 = f32_to_bf16_rne(v0 - hv0);
      unsigned short l1 = f32_to_bf16_rne(v1 - hv1);
      *(unsigned*)&hr[p2 * 2] = (unsigned)h0 | ((unsigned)h1 << 16);
      *(unsigned*)&lr[p2 * 2] = (unsigned)l0 | ((unsigned)l1 << 16);
    }
  }
}

// ---------------- K3: KNN candidate gen via compensated bf16 MFMA ----------------------
// 1-wave blocks: grid = 8b x 16jsplit x 98iblk = 12544 waves (12.25/SIMD available,
// VGPR~60 -> 8 resident/SIMD). acc0 initialized to +2.0 (keygen bias folded into MFMA).
// Selection: parallel rank-insert (med3 network) on packed positive-float keys.
__global__ __launch_bounds__(64, 4) void k_knn(const unsigned short* __restrict__ hiT,
                                               const unsigned short* __restrict__ loT,
                                               unsigned* __restrict__ pk) {
  int bid = blockIdx.x;
  int b = bid & 7;            // XCD affinity
  int r2 = bid >> 3;          // 0..1567
  int iblk = r2 % 98;
  int jsplit = r2 / 98;       // 0..15
  int lane = threadIdx.x;
  int col = lane & 31;
  int half = lane >> 5;
  int i = iblk * 32 + col;

  const unsigned short* hb = hiT + (size_t)b * NPT * NC;
  const unsigned short* lb = loT + (size_t)b * NPT * NC;

  short8 Bh[6], Bl[6];
  {
    const unsigned short* ih = hb + (size_t)i * NC + half * 8;
    const unsigned short* il = lb + (size_t)i * NC + half * 8;
#pragma unroll
    for (int ch = 0; ch < 6; ++ch) {
      Bh[ch] = *(const short8*)(ih + ch * 16);
      Bl[ch] = *(const short8*)(il + ch * 16);
    }
  }

  float kk[NDEP];
#pragma unroll
  for (int k = 0; k < NDEP; ++k) kk[k] = 0.0f;   // 0.0 < any real key (+1..3)

  int t0 = (98 * jsplit) >> 4, t1 = (98 * (jsplit + 1)) >> 4;
  int jbase = t0 * 32;
  for (int t = t0; t < t1; ++t) {
    int j0 = t * 32;
    const unsigned short* ah = hb + (size_t)(j0 + col) * NC + half * 8;
    const unsigned short* al = lb + (size_t)(j0 + col) * NC + half * 8;
    f32x16 acc0, acc1;
#pragma unroll
    for (int r = 0; r < 16; ++r) { acc0[r] = 2.0f; acc1[r] = 0.f; }
    {
      short8 A[6];
#pragma unroll
      for (int ch = 0; ch < 6; ++ch) A[ch] = *(const short8*)(ah + ch * 16);
#pragma unroll
      for (int ch = 0; ch < 6; ++ch)
        acc0 = __builtin_amdgcn_mfma_f32_32x32x16_bf16(A[ch], Bh[ch], acc0, 0, 0, 0);
#pragma unroll
      for (int ch = 0; ch < 6; ++ch)
        acc1 = __builtin_amdgcn_mfma_f32_32x32x16_bf16(A[ch], Bl[ch], acc1, 0, 0, 0);
    }
    {
      short8 A[6];
#pragma unroll
      for (int ch = 0; ch < 6; ++ch) A[ch] = *(const short8*)(al + ch * 16);
#pragma unroll
      for (int ch = 0; ch < 6; ++ch)
        acc0 = __builtin_amdgcn_mfma_f32_32x32x16_bf16(A[ch], Bh[ch], acc0, 0, 0, 0);
    }
    unsigned relbase = (unsigned)(j0 - jbase + 4 * half);
#pragma unroll
    for (int r = 0; r < 16; ++r) {
      float s = acc0[r] + acc1[r];            // = score + 2.0 (positive, in [1,3])
      unsigned kb = __float_as_uint(s);
      unsigned keyu = (kb & 0xFFFFFE00u) | (relbase + (unsigned)((r & 3) + 8 * (r >> 2)));
      float e = __uint_as_float(keyu);
#pragma unroll
      for (int s8 = NDEP - 1; s8 > 0; --s8)
        kk[s8] = __builtin_amdgcn_fmed3f(kk[s8 - 1], kk[s8], e);
      kk[0] = fmaxf(kk[0], e);
    }
  }

  unsigned* op = pk + (size_t)(jsplit * 2 + half) * NDEP * NROWS + ((size_t)b * NPT + i);
#pragma unroll
  for (int k = 0; k < NDEP; ++k) op[(size_t)k * NROWS] = __float_as_uint(kk[k]);
}

// ---------------- K3b: merge NLIST sorted 9-lists per row -> top-16 candidate set ------
__global__ __launch_bounds__(256) void k_nnmerge(const unsigned* __restrict__ pk,
                                                 int* __restrict__ cand) {
  int rg = blockIdx.x * 256 + threadIdx.x;
  if (rg >= NROWS) return;
  const unsigned* p = pk + rg;
  u64 kc[NCAND];
#pragma unroll
  for (int k = 0; k < NCAND; ++k) kc[k] = 0ull;
  for (int s = 0; s < NLIST; ++s) {
#pragma unroll
    for (int k = 0; k < NDEP; ++k) {
      u64 e = ((u64)p[(size_t)(s * NDEP + k) * NROWS] << 5) | (unsigned)s;
      if (e <= kc[NCAND - 1]) break;   // sorted desc source: rest can't qualify
      kc[NCAND - 1] = e;
#pragma unroll
      for (int q = NCAND - 1; q > 0; --q) {
        u64 xx = kc[q - 1], yy = kc[q];
        bool sw = yy > xx;
        kc[q - 1] = sw ? yy : xx;
        kc[q]     = sw ? xx : yy;
      }
    }
  }
  int* op = cand + (size_t)rg * NCAND;
#pragma unroll
  for (int k = 0; k < NCAND; ++k) {
    u64 e = kc[k];
    int s = (int)(e & 0x1F);
    int rel = (int)((e >> 5) & 0x1FF);
    int jb = (((98 * (s >> 1)) >> 4) << 5);
    op[k] = jb + rel;
  }
}

// ---------------- K3c: f32 rescore of 16 candidates -> exact top-9 ---------------------
__global__ __launch_bounds__(256) void k_rescore(const float* __restrict__ fnT,
                                                 const int* __restrict__ cand,
                                                 int* __restrict__ nn_idx) {
  __shared__ u64 kl[4][NCAND];
  int wid = threadIdx.x >> 6, lane = threadIdx.x & 63;
  int row = blockIdx.x * 4 + wid;            // 0..25087 (grid exact)
  int b = row / NPT;
  int c = lane >> 2, sub = lane & 3;
  int j = cand[(size_t)row * NCAND + c];
  const float* fi = fnT + (size_t)row * RST + sub * 24;
  const float* fj = fnT + (size_t)(b * NPT + j) * RST + sub * 24;
  float p = 0.f;
#pragma unroll
  for (int c4 = 0; c4 < 6; ++c4) {
    float4 a = *(const float4*)&fi[c4 * 4];
    float4 v = *(const float4*)&fj[c4 * 4];
    p = fmaf(a.x, v.x, p); p = fmaf(a.y, v.y, p);
    p = fmaf(a.z, v.z, p); p = fmaf(a.w, v.w, p);
  }
  p += __shfl_xor(p, 1);
  p += __shfl_xor(p, 2);
  if (sub == 0) {
    float sqj = fnT[(size_t)(b * NPT + j) * RST + 96];
    float score = fmaf(-0.5f, sqj, p);
    kl[wid][c] = ((u64)score_to_key_exact(score) << 32) | (unsigned)j;
  }
  __syncthreads();
  if (lane == 0) {
    u64 k9[NK];
#pragma unroll
    for (int k = 0; k < NK; ++k) k9[k] = ~0ull;
#pragma unroll
    for (int t = 0; t < NCAND; ++t) {
      u64 key = kl[wid][t];
      if (key < k9[NK - 1]) {
        k9[NK - 1] = key;
#pragma unroll
        for (int q = NK - 1; q > 0; --q) {
          u64 xx = k9[q - 1], yy = k9[q];
          bool sw = yy < xx;
          k9[q - 1] = sw ? yy : xx;
          k9[q]     = sw ? xx : yy;
        }
      }
    }
    int* op = nn_idx + (size_t)row * NK;
#pragma unroll
    for (int k = 0; k < NK; ++k) op[k] = (int)(unsigned)(k9[k] & 0xFFFFFFFFu);
  }
}

// ---------------- K4: uvt = [A;B] @ feat (+bg on u-half), transposed store -------------
__global__ __launch_bounds__(64, 2) void k_uv(const float* __restrict__ feat,
                                              const float* __restrict__ Wuv,
                                              const float* __restrict__ bg,
                                              float* __restrict__ uvt) {
  int bid = blockIdx.x;      // 1568
  int b = bid & 7;
  int ng = bid >> 3;         // 0..195
  int n0 = ng * 16;
  int lane = threadIdx.x;
  int ob = lane & 15, nq = lane >> 4;

  __shared__ float w_lds[16 * UV_WSTR];   // 18688 B
  __shared__ float f_lds[12 * 16];        // 768 B

  const float* fb = feat + (size_t)b * NC * NPT;
  float acc[4][24];
#pragma unroll
  for (int q = 0; q < 4; ++q)
#pragma unroll
    for (int oo = 0; oo < 24; ++oo) acc[q][oo] = 0.f;

  for (int ch = 0; ch < 8; ++ch) {
    __syncthreads();
    {
      const float* wsrc = Wuv + ch * 12 * 384;
#pragma unroll
      for (int it = 0; it < 18; ++it) {
        int i = lane * 4 + it * 256;
        float4 v = *(const float4*)&wsrc[i];
        int cc = i / 384, o = i % 384;
        *(float4*)&w_lds[(o / 24) * UV_WSTR + cc * 24 + (o % 24)] = v;
      }
#pragma unroll
      for (int it = 0; it < 3; ++it) {
        int i = lane + it * 64;
        int cc = i >> 4, nn = i & 15;
        f_lds[i] = fb[(size_t)(ch * 12 + cc) * NPT + n0 + nn];
      }
    }
    __syncthreads();
#pragma unroll
    for (int cc = 0; cc < 12; ++cc) {
      float4 a = *(const float4*)&f_lds[cc * 16 + nq * 4];
      const float* wp = &w_lds[ob * UV_WSTR + cc * 24];
#pragma unroll
      for (int o4 = 0; o4 < 6; ++o4) {
        float4 w = *(const float4*)&wp[o4 * 4];
#pragma unroll
        for (int e = 0; e < 4; ++e) {
          float we = ((const float*)&w)[e];
          acc[0][o4 * 4 + e] = fmaf(we, a.x, acc[0][o4 * 4 + e]);
          acc[1][o4 * 4 + e] = fmaf(we, a.y, acc[1][o4 * 4 + e]);
          acc[2][o4 * 4 + e] = fmaf(we, a.z, acc[2][o4 * 4 + e]);
          acc[3][o4 * 4 + e] = fmaf(we, a.w, acc[3][o4 * 4 + e]);
        }
      }
    }
  }

  float bias[24];
#pragma unroll
  for (int oo = 0; oo < 24; ++oo) bias[oo] = 0.f;
  if (ob < 8) {
#pragma unroll
    for (int o4 = 0; o4 < 6; ++o4) {
      float4 bv = *(const float4*)&bg[ob * 24 + o4 * 4];
      bias[o4 * 4 + 0] = bv.x; bias[o4 * 4 + 1] = bv.y;
      bias[o4 * 4 + 2] = bv.z; bias[o4 * 4 + 3] = bv.w;
    }
  }
#pragma unroll
  for (int q = 0; q < 4; ++q) {
    float* up = uvt + ((size_t)b * NPT + n0 + nq * 4 + q) * 384 + ob * 24;
#pragma unroll
    for (int o4 = 0; o4 < 6; ++o4) {
      float4 v;
      v.x = acc[q][o4 * 4 + 0] + bias[o4 * 4 + 0];
      v.y = acc[q][o4 * 4 + 1] + bias[o4 * 4 + 1];
      v.z = acc[q][o4 * 4 + 2] + bias[o4 * 4 + 2];
      v.w = acc[q][o4 * 4 + 3] + bias[o4 * 4 + 3];
      *(float4*)&up[o4 * 4] = v;
    }
  }
}

// ---------------- K5: agg_t[n][o] = relu(max_k (u[n][o] + v[idx[n][k]][o])) ------------
__global__ __launch_bounds__(192) void k_gather(const float* __restrict__ uvt,
                                                const int* __restrict__ nn_idx,
                                                float* __restrict__ aggt) {
  int bid = blockIdx.x;
  int b = bid & 7;      // XCD affinity for the per-batch v table
  int ng = bid >> 3;    // 0..783
  int tid = threadIdx.x;
  int nq = tid / 48, c4 = tid % 48;
  int n = ng * 4 + nq;
  const float* base = uvt + (size_t)b * NPT * 384;
  const int* ip = nn_idx + ((size_t)b * NPT + n) * NK;
  float4 u = *(const float4*)&base[(size_t)n * 384 + c4 * 4];
  float4 acc = make_float4(-1e30f, -1e30f, -1e30f, -1e30f);
#pragma unroll
  for (int k = 0; k < NK; ++k) {
    int j = ip[k];
    float4 v = *(const float4*)&base[(size_t)j * 384 + 192 + c4 * 4];
    acc.x = fmaxf(acc.x, u.x + v.x);
    acc.y = fmaxf(acc.y, u.y + v.y);
    acc.z = fmaxf(acc.z, u.z + v.z);
    acc.w = fmaxf(acc.w, u.w + v.w);
  }
  float4 o;
  o.x = fmaxf(acc.x, 0.f); o.y = fmaxf(acc.y, 0.f);
  o.z = fmaxf(acc.z, 0.f); o.w = fmaxf(acc.w, 0.f);
  *(float4*)&aggt[((size_t)b * NPT + n) * 192 + c4 * 4] = o;
}

// ---------------- K6: out = W2f @ agg + b2f + residual ---------------------------------
__global__ __launch_bounds__(64, 2) void k_out(const float* __restrict__ aggt,
                                               const float* __restrict__ W2f,
                                               const float* __restrict__ b2f,
                                               const float* __restrict__ x,
                                               float* __restrict__ out) {
  int bid = blockIdx.x;      // 1568
  int b = bid & 7;
  int ng = bid >> 3;
  int n0 = ng * 16;
  int lane = threadIdx.x;
  int ob = lane & 15, nq = lane >> 4;

  __shared__ float w_lds[24 * OUT_WSTR];  // 9600 B
  __shared__ float a_lds[24 * 16];        // 1536 B

  float acc[4][6];
#pragma unroll
  for (int q = 0; q < 4; ++q)
#pragma unroll
    for (int oo = 0; oo < 6; ++oo) acc[q][oo] = 0.f;

  const float* ab = aggt + ((size_t)b * NPT + n0) * 192;

  for (int ch = 0; ch < 8; ++ch) {
    __syncthreads();
    {
      const float* wsrc = W2f + ch * 24 * 96;
#pragma unroll
      for (int it = 0; it < 9; ++it) {
        int i = lane * 4 + it * 256;
        float4 v = *(const float4*)&wsrc[i];
        int cc = i / 96, o = i % 96;
        *(float4*)&w_lds[cc * OUT_WSTR + o] = v;
      }
#pragma unroll
      for (int it = 0; it < 2; ++it) {
        int i = lane + it * 64;
        if (i < 96) {
          int nn = i / 6, c4 = i % 6;
          float4 v = *(const float4*)&ab[(size_t)nn * 192 + ch * 24 + c4 * 4];
          a_lds[(c4 * 4 + 0) * 16 + nn] = v.x;
          a_lds[(c4 * 4 + 1) * 16 + nn] = v.y;
          a_lds[(c4 * 4 + 2) * 16 + nn] = v.z;
          a_lds[(c4 * 4 + 3) * 16 + nn] = v.w;
        }
      }
    }
    __syncthreads();
#pragma unroll
    for (int cc = 0; cc < 24; ++cc) {
      float4 a = *(const float4*)&a_lds[cc * 16 + nq * 4];
      const float* wp = &w_lds[cc * OUT_WSTR + ob * 6];
      float2 w01 = *(const float2*)&wp[0];
      float2 w23 = *(const float2*)&wp[2];
      float2 w45 = *(const float2*)&wp[4];
      float w[6] = {w01.x, w01.y, w23.x, w23.y, w45.x, w45.y};
#pragma unroll
      for (int oo = 0; oo < 6; ++oo) {
        acc[0][oo] = fmaf(w[oo], a.x, acc[0][oo]);
        acc[1][oo] = fmaf(w[oo], a.y, acc[1][oo]);
        acc[2][oo] = fmaf(w[oo], a.z, acc[2][oo]);
        acc[3][oo] = fmaf(w[oo], a.w, acc[3][oo]);
      }
    }
  }

  const float* xb = x + (size_t)b * NC * NPT;
  float* ob_out = out + (size_t)b * NC * NPT;
#pragma unroll
  for (int oo = 0; oo < 6; ++oo) {
    int o = ob * 6 + oo;
    float bb = b2f[o];
#pragma unroll
    for (int q = 0; q < 4; ++q) {
      int n = n0 + nq * 4 + q;
      ob_out[(size_t)o * NPT + n] = acc[q][oo] + bb + xb[(size_t)o * NPT + n];
    }
  }
}

extern "C" void kernel_launch(void* const* d_in, const int* in_sizes, int n_in,
                              void* d_out, int out_size, void* d_ws, size_t ws_size,
                              hipStream_t stream) {
  const float* x  = (const float*)d_in[0];
  const float* W1 = (const float*)d_in[1];
  const float* b1 = (const float*)d_in[2];
  const float* g1 = (const float*)d_in[3];
  const float* be1= (const float*)d_in[4];
  const float* m1 = (const float*)d_in[5];
  const float* v1 = (const float*)d_in[6];
  const float* Wg = (const float*)d_in[7];
  const float* bg = (const float*)d_in[8];
  const float* W2 = (const float*)d_in[9];
  const float* b2 = (const float*)d_in[10];
  const float* g2 = (const float*)d_in[11];
  const float* be2= (const float*)d_in[12];
  const float* m2 = (const float*)d_in[13];
  const float* v2 = (const float*)d_in[14];
  float* out = (float*)d_out;

  float* ws = (float*)d_ws;
  size_t off = 0;
  float* feat = ws + off; off += (size_t)NB * NC * NPT;             // 9.6 MB
  unsigned short* hiT = (unsigned short*)(ws + off); off += (size_t)NB * NPT * NC / 2;
  unsigned short* loT = (unsigned short*)(ws + off); off += (size_t)NB * NPT * NC / 2;
  float* uvt  = ws + off; off += (size_t)NB * NPT * 384;            // 38.5 MB
  float* aggt = ws + off; off += (size_t)NB * NPT * 192;            // 19.3 MB
  float* W1s  = ws + off; off += NC * NC;
  float* Wuv  = ws + off; off += NC * 2 * NC2;
  float* W2f  = ws + off; off += NC2 * NC;
  float* b1f  = ws + off; off += 128;
  float* b2f  = ws + off; off += 128;

  // Phase-disjoint overlays (unchanged):
  float* fnT    = aggt;
  unsigned* pk  = (unsigned*)uvt;   // 28.9 MB <= uvt 38.5 MB; [list][dep][row] layout
  int* cand     = (int*)hiT;
  int* nn_idx   = (int*)loT;

  k_fuse<<<dim3(64), 256, 0, stream>>>(W1, b1, g1, be1, m1, v1, Wg, W2, b2, g2, be2, m2, v2,
                                       W1s, b1f, Wuv, W2f, b2f);
  k_feat<<<dim3(NB * 196), 64, 0, stream>>>(x, W1s, b1f, feat, fnT, hiT, loT);
  k_knn<<<dim3(NB * 98 * NSPL), 64, 0, stream>>>(hiT, loT, pk);
  k_nnmerge<<<dim3((NROWS + 255) / 256), 256, 0, stream>>>(pk, cand);
  k_rescore<<<dim3(NROWS / 4), 256, 0, stream>>>(fnT, cand, nn_idx);
  k_uv<<<dim3(NB * 196), 64, 0, stream>>>(feat, Wuv, bg, uvt);
  k_gather<<<dim3(NB * NPT / 4), 192, 0, stream>>>(uvt, nn_idx, aggt);
  k_out<<<dim3(NB * 196), 64, 0, stream>>>(aggt, W2f, b2f, x, out);
}

// Round 12
// 285.275 us; speedup vs baseline: 1.2315x; 1.2315x over previous
//
#include <hip/hip_runtime.h>
#include <cstdint>

#define NB 8
#define NC 96
#define NC2 192
#define NPT 3136    // 56*56
#define NK 9
#define NSPL 16     // j-splits
#define NLIST 16    // lists per row after in-wave half-merge
#define NDEP 9      // per-list depth (>= NK for superset guarantee)
#define NCAND 16    // pooled candidate count per row
#define NROWS (NB * NPT)
#define RST 104     // fnT row stride (96 fn + sq at [96] + pad)
#define UV_WSTR 292 // k_uv LDS per-ob stride
#define OUT_WSTR 100// k_out LDS cc stride
#define FT_WSTR 76  // k_feat LDS per-ob stride
static constexpr float BN_EPS = 1e-5f;
typedef unsigned long long u64;
typedef float f32x16 __attribute__((ext_vector_type(16)));
typedef short short8 __attribute__((ext_vector_type(8)));

__device__ inline unsigned short f32_to_bf16_rne(float x) {
  unsigned u = __float_as_uint(x);
  unsigned r = (u + 0x7FFFu + ((u >> 16) & 1u)) >> 16;
  return (unsigned short)r;
}

__device__ inline unsigned score_to_key_exact(float s) {
  unsigned u = __float_as_uint(s);
  u ^= 0x80000000u | (unsigned)((int)u >> 31);  // monotone increasing map
  return ~u;                                    // descending score = ascending dist
}

__device__ inline u64 shfl_xor64(u64 x, int m) {
  unsigned lo = __shfl_xor((unsigned)x, m);
  unsigned hi = __shfl_xor((unsigned)(x >> 32), m);
  return ((u64)hi << 32) | lo;
}

// ---------------- K1: fold BN into weights, build fused weight layouts ----------------
// W1s: swizzled [ch8][ob16][cc12][oo6] for k_feat staging.
__global__ void k_fuse(const float* __restrict__ W1, const float* __restrict__ b1,
                       const float* __restrict__ g1, const float* __restrict__ be1,
                       const float* __restrict__ m1, const float* __restrict__ v1,
                       const float* __restrict__ Wg,
                       const float* __restrict__ W2, const float* __restrict__ b2,
                       const float* __restrict__ g2, const float* __restrict__ be2,
                       const float* __restrict__ m2, const float* __restrict__ v2,
                       float* __restrict__ W1s, float* __restrict__ b1f,
                       float* __restrict__ Wuv,
                       float* __restrict__ W2f, float* __restrict__ b2f) {
  int t = blockIdx.x * blockDim.x + threadIdx.x;
  int nth = gridDim.x * blockDim.x;
  for (int i = t; i < NC * NC; i += nth) {
    int ch = i / 1152, r = i % 1152;
    int ob = r / 72, r2 = r % 72;
    int cc = r2 / 6, oo = r2 % 6;
    int c = ch * 12 + cc, o = ob * 6 + oo;
    float inv = g1[o] / sqrtf(v1[o] + BN_EPS);
    W1s[i] = W1[o * NC + c] * inv;
  }
  for (int o = t; o < NC; o += nth) {
    float inv = g1[o] / sqrtf(v1[o] + BN_EPS);
    b1f[o] = b1[o] * inv + be1[o] - m1[o] * inv;
    float inv2v = g2[o] / sqrtf(v2[o] + BN_EPS);
    b2f[o] = b2[o] * inv2v + be2[o] - m2[o] * inv2v;
  }
  for (int i = t; i < NC * (2 * NC2); i += nth) {
    int c = i / (2 * NC2), o4 = i % (2 * NC2);
    float val;
    if (o4 < NC2) val = Wg[o4 * NC2 + c] - Wg[o4 * NC2 + NC + c];
    else          val = Wg[(o4 - NC2) * NC2 + NC + c];
    Wuv[i] = val;
  }
  for (int i = t; i < NC2 * NC; i += nth) {
    int c = i / NC, o = i % NC;
    float inv = g2[o] / sqrtf(v2[o] + BN_EPS);
    W2f[i] = W2[o * NC2 + c] * inv;
  }
}

// ------- K2: feat = BN(W1 x + b1); fnT = f32 fn rows (+sq); hiT/loT = bf16 split -------
__global__ __launch_bounds__(64, 4) void k_feat(const float* __restrict__ x,
                                                const float* __restrict__ W1s,
                                                const float* __restrict__ b1f,
                                                float* __restrict__ feat,
                                                float* __restrict__ fnT,
                                                unsigned short* __restrict__ hiT,
                                                unsigned short* __restrict__ loT) {
  int bid = blockIdx.x;      // 1568
  int b = bid & 7;
  int ng = bid >> 3;         // 0..195
  int n0 = ng * 16;
  int lane = threadIdx.x;
  int ob = lane & 15, nq = lane >> 4;

  __shared__ float w_lds[16 * FT_WSTR];  // 4864 B
  __shared__ float f_lds[12 * 16];       // 768 B

  const float* xb = x + (size_t)b * NC * NPT;
  float acc[4][6];
#pragma unroll
  for (int oo = 0; oo < 6; ++oo) {
    float bv = b1f[ob * 6 + oo];
#pragma unroll
    for (int q = 0; q < 4; ++q) acc[q][oo] = bv;
  }

  for (int ch = 0; ch < 8; ++ch) {
    __syncthreads();
    {
      const float* wsrc = W1s + ch * 1152;
#pragma unroll
      for (int it = 0; it < 5; ++it) {
        int i = it * 256 + lane * 4;
        if (it < 4 || lane < 32) {
          float4 v = *(const float4*)&wsrc[i];
          *(float4*)&w_lds[(i / 72) * FT_WSTR + (i % 72)] = v;
        }
      }
#pragma unroll
      for (int it = 0; it < 3; ++it) {
        int i = it * 64 + lane;
        f_lds[i] = xb[(size_t)(ch * 12 + (i >> 4)) * NPT + n0 + (i & 15)];
      }
    }
    __syncthreads();
#pragma unroll
    for (int cc = 0; cc < 12; ++cc) {
      float4 a = *(const float4*)&f_lds[cc * 16 + nq * 4];
      const float* wp = &w_lds[ob * FT_WSTR + cc * 6];
      float2 w01 = *(const float2*)&wp[0];
      float2 w23 = *(const float2*)&wp[2];
      float2 w45 = *(const float2*)&wp[4];
      float w[6] = {w01.x, w01.y, w23.x, w23.y, w45.x, w45.y};
#pragma unroll
      for (int oo = 0; oo < 6; ++oo) {
        acc[0][oo] = fmaf(w[oo], a.x, acc[0][oo]);
        acc[1][oo] = fmaf(w[oo], a.y, acc[1][oo]);
        acc[2][oo] = fmaf(w[oo], a.z, acc[2][oo]);
        acc[3][oo] = fmaf(w[oo], a.w, acc[3][oo]);
      }
    }
  }

  float sq[4];
#pragma unroll
  for (int q = 0; q < 4; ++q) {
    float s = 0.f;
#pragma unroll
    for (int oo = 0; oo < 6; ++oo) s += acc[q][oo] * acc[q][oo];
    sq[q] = s;
  }
#pragma unroll
  for (int m = 1; m < 16; m <<= 1) {
#pragma unroll
    for (int q = 0; q < 4; ++q) sq[q] += __shfl_xor(sq[q], m);
  }

  float* fb = feat + (size_t)b * NC * NPT;
  float vnn[4][6];
  float sqn[4];
#pragma unroll
  for (int q = 0; q < 4; ++q) {
    float den = fmaxf(sqrtf(sq[q]), 1e-12f);
    float s = 0.f;
#pragma unroll
    for (int oo = 0; oo < 6; ++oo) {
      float v = acc[q][oo] / den;
      vnn[q][oo] = v;
      s += v * v;
    }
    sqn[q] = s;
  }
#pragma unroll
  for (int m = 1; m < 16; m <<= 1) {
#pragma unroll
    for (int q = 0; q < 4; ++q) sqn[q] += __shfl_xor(sqn[q], m);
  }

#pragma unroll
  for (int q = 0; q < 4; ++q) {
    int n = n0 + nq * 4 + q;
#pragma unroll
    for (int oo = 0; oo < 6; ++oo)
      fb[(size_t)(ob * 6 + oo) * NPT + n] = acc[q][oo];
    float* fr = fnT + ((size_t)b * NPT + n) * RST;
#pragma unroll
    for (int oo = 0; oo < 6; ++oo) fr[ob * 6 + oo] = vnn[q][oo];
    if (ob == 0) fr[96] = sqn[q];
    unsigned short* hr = hiT + ((size_t)b * NPT + n) * NC + ob * 6;
    unsigned short* lr = loT + ((size_t)b * NPT + n) * NC + ob * 6;
#pragma unroll
    for (int p2 = 0; p2 < 3; ++p2) {
      float v0 = vnn[q][p2 * 2], v1 = vnn[q][p2 * 2 + 1];
      unsigned short h0 = f32_to_bf16_rne(v0);
      unsigned short h1 = f32_to_bf16_rne(v1);
      float hv0 = __uint_as_float(((unsigned)h0) << 16);
      float hv1 = __uint_as_float(((unsigned)h1) << 16);
      unsigned short l0 = f32_to_bf16_rne(v0 - hv0);
      unsigned short l1 = f32_to_bf16_rne(v1 - hv1);
      *(unsigned*)&hr[p2 * 2] = (unsigned)h0 | ((unsigned)h1 << 16);
      *(unsigned*)&lr[p2 * 2] = (unsigned)l0 | ((unsigned)l1 << 16);
    }
  }
}

// ---------------- K3: KNN candidate gen via compensated bf16 MFMA ----------------------
// 1-wave blocks: grid = 8b x 16jsplit x 98iblk = 12544 waves. Epilogue merges the two
// lane-half top-9s via the merge-path identity c[i] = max(a[i], b[8-i]) (top-9 of union
// of two sorted desc lists) -> 16 lists/row, stored row-contiguous for the merge kernel.
__global__ __launch_bounds__(64, 4) void k_knn(const unsigned short* __restrict__ hiT,
                                               const unsigned short* __restrict__ loT,
                                               unsigned* __restrict__ pk) {
  int bid = blockIdx.x;
  int b = bid & 7;            // XCD affinity
  int r2 = bid >> 3;          // 0..1567
  int iblk = r2 % 98;
  int jsplit = r2 / 98;       // 0..15
  int lane = threadIdx.x;
  int col = lane & 31;
  int half = lane >> 5;
  int i = iblk * 32 + col;

  const unsigned short* hb = hiT + (size_t)b * NPT * NC;
  const unsigned short* lb = loT + (size_t)b * NPT * NC;

  short8 Bh[6], Bl[6];
  {
    const unsigned short* ih = hb + (size_t)i * NC + half * 8;
    const unsigned short* il = lb + (size_t)i * NC + half * 8;
#pragma unroll
    for (int ch = 0; ch < 6; ++ch) {
      Bh[ch] = *(const short8*)(ih + ch * 16);
      Bl[ch] = *(const short8*)(il + ch * 16);
    }
  }

  float kk[NDEP];
#pragma unroll
  for (int k = 0; k < NDEP; ++k) kk[k] = 0.0f;   // 0.0 < any real key (+1..3)

  int t0 = (98 * jsplit) >> 4, t1 = (98 * (jsplit + 1)) >> 4;
  int jbase = t0 * 32;
  for (int t = t0; t < t1; ++t) {
    int j0 = t * 32;
    const unsigned short* ah = hb + (size_t)(j0 + col) * NC + half * 8;
    const unsigned short* al = lb + (size_t)(j0 + col) * NC + half * 8;
    f32x16 acc0, acc1;
#pragma unroll
    for (int r = 0; r < 16; ++r) { acc0[r] = 2.0f; acc1[r] = 0.f; }
    {
      short8 A[6];
#pragma unroll
      for (int ch = 0; ch < 6; ++ch) A[ch] = *(const short8*)(ah + ch * 16);
#pragma unroll
      for (int ch = 0; ch < 6; ++ch)
        acc0 = __builtin_amdgcn_mfma_f32_32x32x16_bf16(A[ch], Bh[ch], acc0, 0, 0, 0);
#pragma unroll
      for (int ch = 0; ch < 6; ++ch)
        acc1 = __builtin_amdgcn_mfma_f32_32x32x16_bf16(A[ch], Bl[ch], acc1, 0, 0, 0);
    }
    {
      short8 A[6];
#pragma unroll
      for (int ch = 0; ch < 6; ++ch) A[ch] = *(const short8*)(al + ch * 16);
#pragma unroll
      for (int ch = 0; ch < 6; ++ch)
        acc0 = __builtin_amdgcn_mfma_f32_32x32x16_bf16(A[ch], Bh[ch], acc0, 0, 0, 0);
    }
    unsigned relbase = (unsigned)(j0 - jbase + 4 * half);
#pragma unroll
    for (int r = 0; r < 16; ++r) {
      float s = acc0[r] + acc1[r];            // = score + 2.0 (positive, in [1,3])
      unsigned kb = __float_as_uint(s);
      unsigned keyu = (kb & 0xFFFFFE00u) | (relbase + (unsigned)((r & 3) + 8 * (r >> 2)));
      float e = __uint_as_float(keyu);
#pragma unroll
      for (int s8 = NDEP - 1; s8 > 0; --s8)
        kk[s8] = __builtin_amdgcn_fmed3f(kk[s8 - 1], kk[s8], e);
      kk[0] = fmaxf(kk[0], e);
    }
  }

  // in-wave half-merge: top-9 of the two disjoint half-lists (merge-path identity)
  float c[NDEP];
#pragma unroll
  for (int k = 0; k < NDEP; ++k) {
    float pv = __shfl_xor(kk[NDEP - 1 - k], 32);
    c[k] = fmaxf(kk[k], pv);
  }
  if (half == 0) {
    unsigned* op = pk + (size_t)((size_t)b * NPT + i) * (NLIST * NDEP) + jsplit * NDEP;
#pragma unroll
    for (int k = 0; k < NDEP; ++k) op[k] = __float_as_uint(c[k]);
  }
}

// ---------------- K3b: wave-per-row tournament -> top-16 candidate set -----------------
// Wave loads its row's 144 keys (36 coalesced uint4), decodes to strict-total-order
// u64 (key32<<16 | j), then 16 rounds of {local max4, butterfly max, invalidate}.
__global__ __launch_bounds__(256) void k_nnmerge(const unsigned* __restrict__ pk,
                                                 int* __restrict__ cand) {
  int wid = threadIdx.x >> 6, lane = threadIdx.x & 63;
  int row = blockIdx.x * 4 + wid;          // grid exact: NROWS/4
  const unsigned* p = pk + (size_t)row * (NLIST * NDEP);
  u64 e0 = 0, e1 = 0, e2 = 0, e3 = 0;
  if (lane < 36) {
    uint4 v = *(const uint4*)&p[lane * 4];
    int g0 = lane * 4;
    // decode: s = g/9 (jsplit), jb = ((98*s)>>4)<<5, j = jb + rel
    int s0 = g0 / 9, s1 = (g0 + 1) / 9, s2 = (g0 + 2) / 9, s3 = (g0 + 3) / 9;
    int jb0 = ((98 * s0) >> 4) << 5, jb1 = ((98 * s1) >> 4) << 5;
    int jb2 = ((98 * s2) >> 4) << 5, jb3 = ((98 * s3) >> 4) << 5;
    e0 = ((u64)v.x << 16) | (unsigned)(jb0 + (int)(v.x & 0x1FFu));
    e1 = ((u64)v.y << 16) | (unsigned)(jb1 + (int)(v.y & 0x1FFu));
    e2 = ((u64)v.z << 16) | (unsigned)(jb2 + (int)(v.z & 0x1FFu));
    e3 = ((u64)v.w << 16) | (unsigned)(jb3 + (int)(v.w & 0x1FFu));
  }
  int* op = cand + (size_t)row * NCAND;
  for (int r = 0; r < NCAND; ++r) {
    u64 a = e0 > e1 ? e0 : e1;
    u64 bmx = e2 > e3 ? e2 : e3;
    u64 loc = a > bmx ? a : bmx;
#pragma unroll
    for (int m = 1; m < 64; m <<= 1) {
      u64 o = shfl_xor64(loc, m);
      loc = o > loc ? o : loc;
    }
    e0 = (e0 == loc) ? 0 : e0;
    e1 = (e1 == loc) ? 0 : e1;
    e2 = (e2 == loc) ? 0 : e2;
    e3 = (e3 == loc) ? 0 : e3;
    if (lane == 0) op[r] = (int)(loc & 0xFFFFu);
  }
}

// ---------------- K3c: f32 rescore of 16 candidates -> exact top-9 ---------------------
__global__ __launch_bounds__(256) void k_rescore(const float* __restrict__ fnT,
                                                 const int* __restrict__ cand,
                                                 int* __restrict__ nn_idx) {
  __shared__ u64 kl[4][NCAND];
  int wid = threadIdx.x >> 6, lane = threadIdx.x & 63;
  int row = blockIdx.x * 4 + wid;            // 0..25087 (grid exact)
  int b = row / NPT;
  int c = lane >> 2, sub = lane & 3;
  int j = cand[(size_t)row * NCAND + c];
  const float* fi = fnT + (size_t)row * RST + sub * 24;
  const float* fj = fnT + (size_t)(b * NPT + j) * RST + sub * 24;
  float p = 0.f;
#pragma unroll
  for (int c4 = 0; c4 < 6; ++c4) {
    float4 a = *(const float4*)&fi[c4 * 4];
    float4 v = *(const float4*)&fj[c4 * 4];
    p = fmaf(a.x, v.x, p); p = fmaf(a.y, v.y, p);
    p = fmaf(a.z, v.z, p); p = fmaf(a.w, v.w, p);
  }
  p += __shfl_xor(p, 1);
  p += __shfl_xor(p, 2);
  if (sub == 0) {
    float sqj = fnT[(size_t)(b * NPT + j) * RST + 96];
    float score = fmaf(-0.5f, sqj, p);
    kl[wid][c] = ((u64)score_to_key_exact(score) << 32) | (unsigned)j;
  }
  __syncthreads();
  if (lane == 0) {
    u64 k9[NK];
#pragma unroll
    for (int k = 0; k < NK; ++k) k9[k] = ~0ull;
#pragma unroll
    for (int t = 0; t < NCAND; ++t) {
      u64 key = kl[wid][t];
      if (key < k9[NK - 1]) {
        k9[NK - 1] = key;
#pragma unroll
        for (int q = NK - 1; q > 0; --q) {
          u64 xx = k9[q - 1], yy = k9[q];
          bool sw = yy < xx;
          k9[q - 1] = sw ? yy : xx;
          k9[q]     = sw ? xx : yy;
        }
      }
    }
    int* op = nn_idx + (size_t)row * NK;
#pragma unroll
    for (int k = 0; k < NK; ++k) op[k] = (int)(unsigned)(k9[k] & 0xFFFFFFFFu);
  }
}

// ---------------- K4: uvt = [A;B] @ feat (+bg on u-half), transposed store -------------
__global__ __launch_bounds__(64, 2) void k_uv(const float* __restrict__ feat,
                                              const float* __restrict__ Wuv,
                                              const float* __restrict__ bg,
                                              float* __restrict__ uvt) {
  int bid = blockIdx.x;      // 1568
  int b = bid & 7;
  int ng = bid >> 3;         // 0..195
  int n0 = ng * 16;
  int lane = threadIdx.x;
  int ob = lane & 15, nq = lane >> 4;

  __shared__ float w_lds[16 * UV_WSTR];   // 18688 B
  __shared__ float f_lds[12 * 16];        // 768 B

  const float* fb = feat + (size_t)b * NC * NPT;
  float acc[4][24];
#pragma unroll
  for (int q = 0; q < 4; ++q)
#pragma unroll
    for (int oo = 0; oo < 24; ++oo) acc[q][oo] = 0.f;

  for (int ch = 0; ch < 8; ++ch) {
    __syncthreads();
    {
      const float* wsrc = Wuv + ch * 12 * 384;
#pragma unroll
      for (int it = 0; it < 18; ++it) {
        int i = lane * 4 + it * 256;
        float4 v = *(const float4*)&wsrc[i];
        int cc = i / 384, o = i % 384;
        *(float4*)&w_lds[(o / 24) * UV_WSTR + cc * 24 + (o % 24)] = v;
      }
#pragma unroll
      for (int it = 0; it < 3; ++it) {
        int i = lane + it * 64;
        int cc = i >> 4, nn = i & 15;
        f_lds[i] = fb[(size_t)(ch * 12 + cc) * NPT + n0 + nn];
      }
    }
    __syncthreads();
#pragma unroll
    for (int cc = 0; cc < 12; ++cc) {
      float4 a = *(const float4*)&f_lds[cc * 16 + nq * 4];
      const float* wp = &w_lds[ob * UV_WSTR + cc * 24];
#pragma unroll
      for (int o4 = 0; o4 < 6; ++o4) {
        float4 w = *(const float4*)&wp[o4 * 4];
#pragma unroll
        for (int e = 0; e < 4; ++e) {
          float we = ((const float*)&w)[e];
          acc[0][o4 * 4 + e] = fmaf(we, a.x, acc[0][o4 * 4 + e]);
          acc[1][o4 * 4 + e] = fmaf(we, a.y, acc[1][o4 * 4 + e]);
          acc[2][o4 * 4 + e] = fmaf(we, a.z, acc[2][o4 * 4 + e]);
          acc[3][o4 * 4 + e] = fmaf(we, a.w, acc[3][o4 * 4 + e]);
        }
      }
    }
  }

  float bias[24];
#pragma unroll
  for (int oo = 0; oo < 24; ++oo) bias[oo] = 0.f;
  if (ob < 8) {
#pragma unroll
    for (int o4 = 0; o4 < 6; ++o4) {
      float4 bv = *(const float4*)&bg[ob * 24 + o4 * 4];
      bias[o4 * 4 + 0] = bv.x; bias[o4 * 4 + 1] = bv.y;
      bias[o4 * 4 + 2] = bv.z; bias[o4 * 4 + 3] = bv.w;
    }
  }
#pragma unroll
  for (int q = 0; q < 4; ++q) {
    float* up = uvt + ((size_t)b * NPT + n0 + nq * 4 + q) * 384 + ob * 24;
#pragma unroll
    for (int o4 = 0; o4 < 6; ++o4) {
      float4 v;
      v.x = acc[q][o4 * 4 + 0] + bias[o4 * 4 + 0];
      v.y = acc[q][o4 * 4 + 1] + bias[o4 * 4 + 1];
      v.z = acc[q][o4 * 4 + 2] + bias[o4 * 4 + 2];
      v.w = acc[q][o4 * 4 + 3] + bias[o4 * 4 + 3];
      *(float4*)&up[o4 * 4] = v;
    }
  }
}

// ---------------- K5: agg_t[n][o] = relu(max_k (u[n][o] + v[idx[n][k]][o])) ------------
__global__ __launch_bounds__(192) void k_gather(const float* __restrict__ uvt,
                                                const int* __restrict__ nn_idx,
                                                float* __restrict__ aggt) {
  int bid = blockIdx.x;
  int b = bid & 7;      // XCD affinity for the per-batch v table
  int ng = bid >> 3;    // 0..783
  int tid = threadIdx.x;
  int nq = tid / 48, c4 = tid % 48;
  int n = ng * 4 + nq;
  const float* base = uvt + (size_t)b * NPT * 384;
  const int* ip = nn_idx + ((size_t)b * NPT + n) * NK;
  float4 u = *(const float4*)&base[(size_t)n * 384 + c4 * 4];
  float4 acc = make_float4(-1e30f, -1e30f, -1e30f, -1e30f);
#pragma unroll
  for (int k = 0; k < NK; ++k) {
    int j = ip[k];
    float4 v = *(const float4*)&base[(size_t)j * 384 + 192 + c4 * 4];
    acc.x = fmaxf(acc.x, u.x + v.x);
    acc.y = fmaxf(acc.y, u.y + v.y);
    acc.z = fmaxf(acc.z, u.z + v.z);
    acc.w = fmaxf(acc.w, u.w + v.w);
  }
  float4 o;
  o.x = fmaxf(acc.x, 0.f); o.y = fmaxf(acc.y, 0.f);
  o.z = fmaxf(acc.z, 0.f); o.w = fmaxf(acc.w, 0.f);
  *(float4*)&aggt[((size_t)b * NPT + n) * 192 + c4 * 4] = o;
}

// ---------------- K6: out = W2f @ agg + b2f + residual ---------------------------------
__global__ __launch_bounds__(64, 2) void k_out(const float* __restrict__ aggt,
                                               const float* __restrict__ W2f,
                                               const float* __restrict__ b2f,
                                               const float* __restrict__ x,
                                               float* __restrict__ out) {
  int bid = blockIdx.x;      // 1568
  int b = bid & 7;
  int ng = bid >> 3;
  int n0 = ng * 16;
  int lane = threadIdx.x;
  int ob = lane & 15, nq = lane >> 4;

  __shared__ float w_lds[24 * OUT_WSTR];  // 9600 B
  __shared__ float a_lds[24 * 16];        // 1536 B

  float acc[4][6];
#pragma unroll
  for (int q = 0; q < 4; ++q)
#pragma unroll
    for (int oo = 0; oo < 6; ++oo) acc[q][oo] = 0.f;

  const float* ab = aggt + ((size_t)b * NPT + n0) * 192;

  for (int ch = 0; ch < 8; ++ch) {
    __syncthreads();
    {
      const float* wsrc = W2f + ch * 24 * 96;
#pragma unroll
      for (int it = 0; it < 9; ++it) {
        int i = lane * 4 + it * 256;
        float4 v = *(const float4*)&wsrc[i];
        int cc = i / 96, o = i % 96;
        *(float4*)&w_lds[cc * OUT_WSTR + o] = v;
      }
#pragma unroll
      for (int it = 0; it < 2; ++it) {
        int i = lane + it * 64;
        if (i < 96) {
          int nn = i / 6, c4 = i % 6;
          float4 v = *(const float4*)&ab[(size_t)nn * 192 + ch * 24 + c4 * 4];
          a_lds[(c4 * 4 + 0) * 16 + nn] = v.x;
          a_lds[(c4 * 4 + 1) * 16 + nn] = v.y;
          a_lds[(c4 * 4 + 2) * 16 + nn] = v.z;
          a_lds[(c4 * 4 + 3) * 16 + nn] = v.w;
        }
      }
    }
    __syncthreads();
#pragma unroll
    for (int cc = 0; cc < 24; ++cc) {
      float4 a = *(const float4*)&a_lds[cc * 16 + nq * 4];
      const float* wp = &w_lds[cc * OUT_WSTR + ob * 6];
      float2 w01 = *(const float2*)&wp[0];
      float2 w23 = *(const float2*)&wp[2];
      float2 w45 = *(const float2*)&wp[4];
      float w[6] = {w01.x, w01.y, w23.x, w23.y, w45.x, w45.y};
#pragma unroll
      for (int oo = 0; oo < 6; ++oo) {
        acc[0][oo] = fmaf(w[oo], a.x, acc[0][oo]);
        acc[1][oo] = fmaf(w[oo], a.y, acc[1][oo]);
        acc[2][oo] = fmaf(w[oo], a.z, acc[2][oo]);
        acc[3][oo] = fmaf(w[oo], a.w, acc[3][oo]);
      }
    }
  }

  const float* xb = x + (size_t)b * NC * NPT;
  float* ob_out = out + (size_t)b * NC * NPT;
#pragma unroll
  for (int oo = 0; oo < 6; ++oo) {
    int o = ob * 6 + oo;
    float bb = b2f[o];
#pragma unroll
    for (int q = 0; q < 4; ++q) {
      int n = n0 + nq * 4 + q;
      ob_out[(size_t)o * NPT + n] = acc[q][oo] + bb + xb[(size_t)o * NPT + n];
    }
  }
}

extern "C" void kernel_launch(void* const* d_in, const int* in_sizes, int n_in,
                              void* d_out, int out_size, void* d_ws, size_t ws_size,
                              hipStream_t stream) {
  const float* x  = (const float*)d_in[0];
  const float* W1 = (const float*)d_in[1];
  const float* b1 = (const float*)d_in[2];
  const float* g1 = (const float*)d_in[3];
  const float* be1= (const float*)d_in[4];
  const float* m1 = (const float*)d_in[5];
  const float* v1 = (const float*)d_in[6];
  const float* Wg = (const float*)d_in[7];
  const float* bg = (const float*)d_in[8];
  const float* W2 = (const float*)d_in[9];
  const float* b2 = (const float*)d_in[10];
  const float* g2 = (const float*)d_in[11];
  const float* be2= (const float*)d_in[12];
  const float* m2 = (const float*)d_in[13];
  const float* v2 = (const float*)d_in[14];
  float* out = (float*)d_out;

  float* ws = (float*)d_ws;
  size_t off = 0;
  float* feat = ws + off; off += (size_t)NB * NC * NPT;             // 9.6 MB
  unsigned short* hiT = (unsigned short*)(ws + off); off += (size_t)NB * NPT * NC / 2;
  unsigned short* loT = (unsigned short*)(ws + off); off += (size_t)NB * NPT * NC / 2;
  float* uvt  = ws + off; off += (size_t)NB * NPT * 384;            // 38.5 MB
  float* aggt = ws + off; off += (size_t)NB * NPT * 192;            // 19.3 MB
  float* W1s  = ws + off; off += NC * NC;
  float* Wuv  = ws + off; off += NC * 2 * NC2;
  float* W2f  = ws + off; off += NC2 * NC;
  float* b1f  = ws + off; off += 128;
  float* b2f  = ws + off; off += 128;

  // Phase-disjoint overlays (unchanged):
  float* fnT    = aggt;
  unsigned* pk  = (unsigned*)uvt;   // 14.5 MB <= uvt; [row][list16][dep9] contiguous
  int* cand     = (int*)hiT;
  int* nn_idx   = (int*)loT;

  k_fuse<<<dim3(64), 256, 0, stream>>>(W1, b1, g1, be1, m1, v1, Wg, W2, b2, g2, be2, m2, v2,
                                       W1s, b1f, Wuv, W2f, b2f);
  k_feat<<<dim3(NB * 196), 64, 0, stream>>>(x, W1s, b1f, feat, fnT, hiT, loT);
  k_knn<<<dim3(NB * 98 * NSPL), 64, 0, stream>>>(hiT, loT, pk);
  k_nnmerge<<<dim3(NROWS / 4), 256, 0, stream>>>(pk, cand);
  k_rescore<<<dim3(NROWS / 4), 256, 0, stream>>>(fnT, cand, nn_idx);
  k_uv<<<dim3(NB * 196), 64, 0, stream>>>(feat, Wuv, bg, uvt);
  k_gather<<<dim3(NB * NPT / 4), 192, 0, stream>>>(uvt, nn_idx, aggt);
  k_out<<<dim3(NB * 196), 64, 0, stream>>>(aggt, W2f, b2f, x, out);
}

// Round 13
// 262.411 us; speedup vs baseline: 1.3388x; 1.0871x over previous
//
#include <hip/hip_runtime.h>
#include <cstdint>

#define NB 8
#define NC 96
#define NC2 192
#define NPT 3136    // 56*56
#define NK 9
#define NSPL 16     // j-splits
#define NLIST 16    // lists per row after in-wave half-merge
#define NDEP 9      // per-list depth (>= NK for superset guarantee)
#define NCAND 16    // pooled candidate count per row
#define NROWS (NB * NPT)
#define RST 104     // fnT row stride (96 fn + sq at [96] + pad)
#define UV_WSTR 292 // k_uv LDS per-ob stride
#define OUT_WSTR 100// k_out LDS cc stride
#define FT_WSTR 76  // k_feat LDS per-ob stride
static constexpr float BN_EPS = 1e-5f;
typedef unsigned long long u64;
typedef float f32x16 __attribute__((ext_vector_type(16)));
typedef short short8 __attribute__((ext_vector_type(8)));

__device__ inline unsigned short f32_to_bf16_rne(float x) {
  unsigned u = __float_as_uint(x);
  unsigned r = (u + 0x7FFFu + ((u >> 16) & 1u)) >> 16;
  return (unsigned short)r;
}

__device__ inline unsigned score_to_key_exact(float s) {
  unsigned u = __float_as_uint(s);
  u ^= 0x80000000u | (unsigned)((int)u >> 31);  // monotone increasing map
  return ~u;                                    // descending score = ascending dist
}

__device__ inline u64 shfl_xor64(u64 x, int m) {
  unsigned lo = __shfl_xor((unsigned)x, m);
  unsigned hi = __shfl_xor((unsigned)(x >> 32), m);
  return ((u64)hi << 32) | lo;
}

// ---------------- K1: fold BN into weights, build fused weight layouts ----------------
// W1s: swizzled [ch8][ob16][cc12][oo6] for k_feat staging.
__global__ void k_fuse(const float* __restrict__ W1, const float* __restrict__ b1,
                       const float* __restrict__ g1, const float* __restrict__ be1,
                       const float* __restrict__ m1, const float* __restrict__ v1,
                       const float* __restrict__ Wg,
                       const float* __restrict__ W2, const float* __restrict__ b2,
                       const float* __restrict__ g2, const float* __restrict__ be2,
                       const float* __restrict__ m2, const float* __restrict__ v2,
                       float* __restrict__ W1s, float* __restrict__ b1f,
                       float* __restrict__ Wuv,
                       float* __restrict__ W2f, float* __restrict__ b2f) {
  int t = blockIdx.x * blockDim.x + threadIdx.x;
  int nth = gridDim.x * blockDim.x;
  for (int i = t; i < NC * NC; i += nth) {
    int ch = i / 1152, r = i % 1152;
    int ob = r / 72, r2 = r % 72;
    int cc = r2 / 6, oo = r2 % 6;
    int c = ch * 12 + cc, o = ob * 6 + oo;
    float inv = g1[o] / sqrtf(v1[o] + BN_EPS);
    W1s[i] = W1[o * NC + c] * inv;
  }
  for (int o = t; o < NC; o += nth) {
    float inv = g1[o] / sqrtf(v1[o] + BN_EPS);
    b1f[o] = b1[o] * inv + be1[o] - m1[o] * inv;
    float inv2v = g2[o] / sqrtf(v2[o] + BN_EPS);
    b2f[o] = b2[o] * inv2v + be2[o] - m2[o] * inv2v;
  }
  for (int i = t; i < NC * (2 * NC2); i += nth) {
    int c = i / (2 * NC2), o4 = i % (2 * NC2);
    float val;
    if (o4 < NC2) val = Wg[o4 * NC2 + c] - Wg[o4 * NC2 + NC + c];
    else          val = Wg[(o4 - NC2) * NC2 + NC + c];
    Wuv[i] = val;
  }
  for (int i = t; i < NC2 * NC; i += nth) {
    int c = i / NC, o = i % NC;
    float inv = g2[o] / sqrtf(v2[o] + BN_EPS);
    W2f[i] = W2[o * NC2 + c] * inv;
  }
}

// ------- K2: feat = BN(W1 x + b1); fnT = f32 fn rows (+sq); hiT/loT = bf16 split -------
__global__ __launch_bounds__(64, 4) void k_feat(const float* __restrict__ x,
                                                const float* __restrict__ W1s,
                                                const float* __restrict__ b1f,
                                                float* __restrict__ feat,
                                                float* __restrict__ fnT,
                                                unsigned short* __restrict__ hiT,
                                                unsigned short* __restrict__ loT) {
  int bid = blockIdx.x;      // 1568
  int b = bid & 7;
  int ng = bid >> 3;         // 0..195
  int n0 = ng * 16;
  int lane = threadIdx.x;
  int ob = lane & 15, nq = lane >> 4;

  __shared__ float w_lds[16 * FT_WSTR];  // 4864 B
  __shared__ float f_lds[12 * 16];       // 768 B

  const float* xb = x + (size_t)b * NC * NPT;
  float acc[4][6];
#pragma unroll
  for (int oo = 0; oo < 6; ++oo) {
    float bv = b1f[ob * 6 + oo];
#pragma unroll
    for (int q = 0; q < 4; ++q) acc[q][oo] = bv;
  }

  for (int ch = 0; ch < 8; ++ch) {
    __syncthreads();
    {
      const float* wsrc = W1s + ch * 1152;
#pragma unroll
      for (int it = 0; it < 5; ++it) {
        int i = it * 256 + lane * 4;
        if (it < 4 || lane < 32) {
          float4 v = *(const float4*)&wsrc[i];
          *(float4*)&w_lds[(i / 72) * FT_WSTR + (i % 72)] = v;
        }
      }
#pragma unroll
      for (int it = 0; it < 3; ++it) {
        int i = it * 64 + lane;
        f_lds[i] = xb[(size_t)(ch * 12 + (i >> 4)) * NPT + n0 + (i & 15)];
      }
    }
    __syncthreads();
#pragma unroll
    for (int cc = 0; cc < 12; ++cc) {
      float4 a = *(const float4*)&f_lds[cc * 16 + nq * 4];
      const float* wp = &w_lds[ob * FT_WSTR + cc * 6];
      float2 w01 = *(const float2*)&wp[0];
      float2 w23 = *(const float2*)&wp[2];
      float2 w45 = *(const float2*)&wp[4];
      float w[6] = {w01.x, w01.y, w23.x, w23.y, w45.x, w45.y};
#pragma unroll
      for (int oo = 0; oo < 6; ++oo) {
        acc[0][oo] = fmaf(w[oo], a.x, acc[0][oo]);
        acc[1][oo] = fmaf(w[oo], a.y, acc[1][oo]);
        acc[2][oo] = fmaf(w[oo], a.z, acc[2][oo]);
        acc[3][oo] = fmaf(w[oo], a.w, acc[3][oo]);
      }
    }
  }

  float sq[4];
#pragma unroll
  for (int q = 0; q < 4; ++q) {
    float s = 0.f;
#pragma unroll
    for (int oo = 0; oo < 6; ++oo) s += acc[q][oo] * acc[q][oo];
    sq[q] = s;
  }
#pragma unroll
  for (int m = 1; m < 16; m <<= 1) {
#pragma unroll
    for (int q = 0; q < 4; ++q) sq[q] += __shfl_xor(sq[q], m);
  }

  float* fb = feat + (size_t)b * NC * NPT;
  float vnn[4][6];
  float sqn[4];
#pragma unroll
  for (int q = 0; q < 4; ++q) {
    float den = fmaxf(sqrtf(sq[q]), 1e-12f);
    float s = 0.f;
#pragma unroll
    for (int oo = 0; oo < 6; ++oo) {
      float v = acc[q][oo] / den;
      vnn[q][oo] = v;
      s += v * v;
    }
    sqn[q] = s;
  }
#pragma unroll
  for (int m = 1; m < 16; m <<= 1) {
#pragma unroll
    for (int q = 0; q < 4; ++q) sqn[q] += __shfl_xor(sqn[q], m);
  }

#pragma unroll
  for (int q = 0; q < 4; ++q) {
    int n = n0 + nq * 4 + q;
#pragma unroll
    for (int oo = 0; oo < 6; ++oo)
      fb[(size_t)(ob * 6 + oo) * NPT + n] = acc[q][oo];
    float* fr = fnT + ((size_t)b * NPT + n) * RST;
#pragma unroll
    for (int oo = 0; oo < 6; ++oo) fr[ob * 6 + oo] = vnn[q][oo];
    if (ob == 0) fr[96] = sqn[q];
    unsigned short* hr = hiT + ((size_t)b * NPT + n) * NC + ob * 6;
    unsigned short* lr = loT + ((size_t)b * NPT + n) * NC + ob * 6;
#pragma unroll
    for (int p2 = 0; p2 < 3; ++p2) {
      float v0 = vnn[q][p2 * 2], v1 = vnn[q][p2 * 2 + 1];
      unsigned short h0 = f32_to_bf16_rne(v0);
      unsigned short h1 = f32_to_bf16_rne(v1);
      float hv0 = __uint_as_float(((unsigned)h0) << 16);
      float hv1 = __uint_as_float(((unsigned)h1) << 16);
      unsigned short l0 = f32_to_bf16_rne(v0 - hv0);
      unsigned short l1 = f32_to_bf16_rne(v1 - hv1);
      *(unsigned*)&hr[p2 * 2] = (unsigned)h0 | ((unsigned)h1 << 16);
      *(unsigned*)&lr[p2 * 2] = (unsigned)l0 | ((unsigned)l1 << 16);
    }
  }
}

// ---------------- K3: KNN candidate gen via compensated bf16 MFMA ----------------------
// 4-wave blocks (grid 3136 = 12.25/CU; 256-thr blocks avoid the 64-thr workgroup-slot
// occupancy cap). Wave w handles jsplit = jp*4 + w. dot ~= hj.hi + hj.li (12 MFMA, two
// independent 6-chains; dropped lj.hi term ~2e-4 RMS << rank gap ~3e-2; exact f32
// rescore downstream). Selection: med3 rank-insert; epilogue in-wave half-merge.
__global__ __launch_bounds__(256, 4) void k_knn(const unsigned short* __restrict__ hiT,
                                                const unsigned short* __restrict__ loT,
                                                unsigned* __restrict__ pk) {
  int bid = blockIdx.x;
  int b = bid & 7;            // XCD affinity
  int r2 = bid >> 3;          // 0..391
  int iblk = r2 % 98;
  int jp = r2 / 98;           // 0..3
  int wq = threadIdx.x >> 6;
  int jsplit = jp * 4 + wq;   // 0..15
  int lane = threadIdx.x & 63;
  int col = lane & 31;
  int half = lane >> 5;
  int i = iblk * 32 + col;

  const unsigned short* hb = hiT + (size_t)b * NPT * NC;
  const unsigned short* lb = loT + (size_t)b * NPT * NC;

  short8 Bh[6], Bl[6];
  {
    const unsigned short* ih = hb + (size_t)i * NC + half * 8;
    const unsigned short* il = lb + (size_t)i * NC + half * 8;
#pragma unroll
    for (int ch = 0; ch < 6; ++ch) {
      Bh[ch] = *(const short8*)(ih + ch * 16);
      Bl[ch] = *(const short8*)(il + ch * 16);
    }
  }

  float kk[NDEP];
#pragma unroll
  for (int k = 0; k < NDEP; ++k) kk[k] = 0.0f;   // 0.0 < any real key (+1..3)

  int t0 = (98 * jsplit) >> 4, t1 = (98 * (jsplit + 1)) >> 4;
  int jbase = t0 * 32;
  for (int t = t0; t < t1; ++t) {
    int j0 = t * 32;
    const unsigned short* ah = hb + (size_t)(j0 + col) * NC + half * 8;
    f32x16 acc0, acc1;
#pragma unroll
    for (int r = 0; r < 16; ++r) { acc0[r] = 2.0f; acc1[r] = 0.f; }
    {
      short8 A[6];
#pragma unroll
      for (int ch = 0; ch < 6; ++ch) A[ch] = *(const short8*)(ah + ch * 16);
#pragma unroll
      for (int ch = 0; ch < 6; ++ch)
        acc0 = __builtin_amdgcn_mfma_f32_32x32x16_bf16(A[ch], Bh[ch], acc0, 0, 0, 0);
#pragma unroll
      for (int ch = 0; ch < 6; ++ch)
        acc1 = __builtin_amdgcn_mfma_f32_32x32x16_bf16(A[ch], Bl[ch], acc1, 0, 0, 0);
    }
    unsigned relbase = (unsigned)(j0 - jbase + 4 * half);
#pragma unroll
    for (int r = 0; r < 16; ++r) {
      float s = acc0[r] + acc1[r];            // = score + 2.0 (positive, in [1,3])
      unsigned kb = __float_as_uint(s);
      unsigned keyu = (kb & 0xFFFFFE00u) | (relbase + (unsigned)((r & 3) + 8 * (r >> 2)));
      float e = __uint_as_float(keyu);
#pragma unroll
      for (int s8 = NDEP - 1; s8 > 0; --s8)
        kk[s8] = __builtin_amdgcn_fmed3f(kk[s8 - 1], kk[s8], e);
      kk[0] = fmaxf(kk[0], e);
    }
  }

  // in-wave half-merge: top-9 of the two disjoint half-lists (merge-path identity)
  float c[NDEP];
#pragma unroll
  for (int k = 0; k < NDEP; ++k) {
    float pv = __shfl_xor(kk[NDEP - 1 - k], 32);
    c[k] = fmaxf(kk[k], pv);
  }
  if (half == 0) {
    unsigned* op = pk + (size_t)((size_t)b * NPT + i) * (NLIST * NDEP) + jsplit * NDEP;
#pragma unroll
    for (int k = 0; k < NDEP; ++k) op[k] = __float_as_uint(c[k]);
  }
}

// ---------------- K3b: wave-per-row tournament -> top-16 candidate set -----------------
__global__ __launch_bounds__(256) void k_nnmerge(const unsigned* __restrict__ pk,
                                                 int* __restrict__ cand) {
  int wid = threadIdx.x >> 6, lane = threadIdx.x & 63;
  int row = blockIdx.x * 4 + wid;          // grid exact: NROWS/4
  const unsigned* p = pk + (size_t)row * (NLIST * NDEP);
  u64 e0 = 0, e1 = 0, e2 = 0, e3 = 0;
  if (lane < 36) {
    uint4 v = *(const uint4*)&p[lane * 4];
    int g0 = lane * 4;
    int s0 = g0 / 9, s1 = (g0 + 1) / 9, s2 = (g0 + 2) / 9, s3 = (g0 + 3) / 9;
    int jb0 = ((98 * s0) >> 4) << 5, jb1 = ((98 * s1) >> 4) << 5;
    int jb2 = ((98 * s2) >> 4) << 5, jb3 = ((98 * s3) >> 4) << 5;
    e0 = ((u64)v.x << 16) | (unsigned)(jb0 + (int)(v.x & 0x1FFu));
    e1 = ((u64)v.y << 16) | (unsigned)(jb1 + (int)(v.y & 0x1FFu));
    e2 = ((u64)v.z << 16) | (unsigned)(jb2 + (int)(v.z & 0x1FFu));
    e3 = ((u64)v.w << 16) | (unsigned)(jb3 + (int)(v.w & 0x1FFu));
  }
  int* op = cand + (size_t)row * NCAND;
  for (int r = 0; r < NCAND; ++r) {
    u64 a = e0 > e1 ? e0 : e1;
    u64 bmx = e2 > e3 ? e2 : e3;
    u64 loc = a > bmx ? a : bmx;
#pragma unroll
    for (int m = 1; m < 64; m <<= 1) {
      u64 o = shfl_xor64(loc, m);
      loc = o > loc ? o : loc;
    }
    e0 = (e0 == loc) ? 0 : e0;
    e1 = (e1 == loc) ? 0 : e1;
    e2 = (e2 == loc) ? 0 : e2;
    e3 = (e3 == loc) ? 0 : e3;
    if (lane == 0) op[r] = (int)(loc & 0xFFFFu);
  }
}

// ---------------- K3c: f32 rescore of 16 candidates -> exact top-9 ---------------------
__global__ __launch_bounds__(256) void k_rescore(const float* __restrict__ fnT,
                                                 const int* __restrict__ cand,
                                                 int* __restrict__ nn_idx) {
  __shared__ u64 kl[4][NCAND];
  int wid = threadIdx.x >> 6, lane = threadIdx.x & 63;
  int row = blockIdx.x * 4 + wid;            // 0..25087 (grid exact)
  int b = row / NPT;
  int c = lane >> 2, sub = lane & 3;
  int j = cand[(size_t)row * NCAND + c];
  const float* fi = fnT + (size_t)row * RST + sub * 24;
  const float* fj = fnT + (size_t)(b * NPT + j) * RST + sub * 24;
  float p = 0.f;
#pragma unroll
  for (int c4 = 0; c4 < 6; ++c4) {
    float4 a = *(const float4*)&fi[c4 * 4];
    float4 v = *(const float4*)&fj[c4 * 4];
    p = fmaf(a.x, v.x, p); p = fmaf(a.y, v.y, p);
    p = fmaf(a.z, v.z, p); p = fmaf(a.w, v.w, p);
  }
  p += __shfl_xor(p, 1);
  p += __shfl_xor(p, 2);
  if (sub == 0) {
    float sqj = fnT[(size_t)(b * NPT + j) * RST + 96];
    float score = fmaf(-0.5f, sqj, p);
    kl[wid][c] = ((u64)score_to_key_exact(score) << 32) | (unsigned)j;
  }
  __syncthreads();
  if (lane == 0) {
    u64 k9[NK];
#pragma unroll
    for (int k = 0; k < NK; ++k) k9[k] = ~0ull;
#pragma unroll
    for (int t = 0; t < NCAND; ++t) {
      u64 key = kl[wid][t];
      if (key < k9[NK - 1]) {
        k9[NK - 1] = key;
#pragma unroll
        for (int q = NK - 1; q > 0; --q) {
          u64 xx = k9[q - 1], yy = k9[q];
          bool sw = yy < xx;
          k9[q - 1] = sw ? yy : xx;
          k9[q]     = sw ? xx : yy;
        }
      }
    }
    int* op = nn_idx + (size_t)row * NK;
#pragma unroll
    for (int k = 0; k < NK; ++k) op[k] = (int)(unsigned)(k9[k] & 0xFFFFFFFFu);
  }
}

// ---------------- K4: uvt = [A;B] @ feat (+bg on u-half), transposed store -------------
__global__ __launch_bounds__(64, 2) void k_uv(const float* __restrict__ feat,
                                              const float* __restrict__ Wuv,
                                              const float* __restrict__ bg,
                                              float* __restrict__ uvt) {
  int bid = blockIdx.x;      // 1568
  int b = bid & 7;
  int ng = bid >> 3;         // 0..195
  int n0 = ng * 16;
  int lane = threadIdx.x;
  int ob = lane & 15, nq = lane >> 4;

  __shared__ float w_lds[16 * UV_WSTR];   // 18688 B
  __shared__ float f_lds[12 * 16];        // 768 B

  const float* fb = feat + (size_t)b * NC * NPT;
  float acc[4][24];
#pragma unroll
  for (int q = 0; q < 4; ++q)
#pragma unroll
    for (int oo = 0; oo < 24; ++oo) acc[q][oo] = 0.f;

  for (int ch = 0; ch < 8; ++ch) {
    __syncthreads();
    {
      const float* wsrc = Wuv + ch * 12 * 384;
#pragma unroll
      for (int it = 0; it < 18; ++it) {
        int i = lane * 4 + it * 256;
        float4 v = *(const float4*)&wsrc[i];
        int cc = i / 384, o = i % 384;
        *(float4*)&w_lds[(o / 24) * UV_WSTR + cc * 24 + (o % 24)] = v;
      }
#pragma unroll
      for (int it = 0; it < 3; ++it) {
        int i = lane + it * 64;
        int cc = i >> 4, nn = i & 15;
        f_lds[i] = fb[(size_t)(ch * 12 + cc) * NPT + n0 + nn];
      }
    }
    __syncthreads();
#pragma unroll
    for (int cc = 0; cc < 12; ++cc) {
      float4 a = *(const float4*)&f_lds[cc * 16 + nq * 4];
      const float* wp = &w_lds[ob * UV_WSTR + cc * 24];
#pragma unroll
      for (int o4 = 0; o4 < 6; ++o4) {
        float4 w = *(const float4*)&wp[o4 * 4];
#pragma unroll
        for (int e = 0; e < 4; ++e) {
          float we = ((const float*)&w)[e];
          acc[0][o4 * 4 + e] = fmaf(we, a.x, acc[0][o4 * 4 + e]);
          acc[1][o4 * 4 + e] = fmaf(we, a.y, acc[1][o4 * 4 + e]);
          acc[2][o4 * 4 + e] = fmaf(we, a.z, acc[2][o4 * 4 + e]);
          acc[3][o4 * 4 + e] = fmaf(we, a.w, acc[3][o4 * 4 + e]);
        }
      }
    }
  }

  float bias[24];
#pragma unroll
  for (int oo = 0; oo < 24; ++oo) bias[oo] = 0.f;
  if (ob < 8) {
#pragma unroll
    for (int o4 = 0; o4 < 6; ++o4) {
      float4 bv = *(const float4*)&bg[ob * 24 + o4 * 4];
      bias[o4 * 4 + 0] = bv.x; bias[o4 * 4 + 1] = bv.y;
      bias[o4 * 4 + 2] = bv.z; bias[o4 * 4 + 3] = bv.w;
    }
  }
#pragma unroll
  for (int q = 0; q < 4; ++q) {
    float* up = uvt + ((size_t)b * NPT + n0 + nq * 4 + q) * 384 + ob * 24;
#pragma unroll
    for (int o4 = 0; o4 < 6; ++o4) {
      float4 v;
      v.x = acc[q][o4 * 4 + 0] + bias[o4 * 4 + 0];
      v.y = acc[q][o4 * 4 + 1] + bias[o4 * 4 + 1];
      v.z = acc[q][o4 * 4 + 2] + bias[o4 * 4 + 2];
      v.w = acc[q][o4 * 4 + 3] + bias[o4 * 4 + 3];
      *(float4*)&up[o4 * 4] = v;
    }
  }
}

// ---------------- K5: agg_t[n][o] = relu(max_k (u[n][o] + v[idx[n][k]][o])) ------------
__global__ __launch_bounds__(192) void k_gather(const float* __restrict__ uvt,
                                                const int* __restrict__ nn_idx,
                                                float* __restrict__ aggt) {
  int bid = blockIdx.x;
  int b = bid & 7;      // XCD affinity for the per-batch v table
  int ng = bid >> 3;    // 0..783
  int tid = threadIdx.x;
  int nq = tid / 48, c4 = tid % 48;
  int n = ng * 4 + nq;
  const float* base = uvt + (size_t)b * NPT * 384;
  const int* ip = nn_idx + ((size_t)b * NPT + n) * NK;
  float4 u = *(const float4*)&base[(size_t)n * 384 + c4 * 4];
  float4 acc = make_float4(-1e30f, -1e30f, -1e30f, -1e30f);
#pragma unroll
  for (int k = 0; k < NK; ++k) {
    int j = ip[k];
    float4 v = *(const float4*)&base[(size_t)j * 384 + 192 + c4 * 4];
    acc.x = fmaxf(acc.x, u.x + v.x);
    acc.y = fmaxf(acc.y, u.y + v.y);
    acc.z = fmaxf(acc.z, u.z + v.z);
    acc.w = fmaxf(acc.w, u.w + v.w);
  }
  float4 o;
  o.x = fmaxf(acc.x, 0.f); o.y = fmaxf(acc.y, 0.f);
  o.z = fmaxf(acc.z, 0.f); o.w = fmaxf(acc.w, 0.f);
  *(float4*)&aggt[((size_t)b * NPT + n) * 192 + c4 * 4] = o;
}

// ---------------- K6: out = W2f @ agg + b2f + residual ---------------------------------
__global__ __launch_bounds__(64, 2) void k_out(const float* __restrict__ aggt,
                                               const float* __restrict__ W2f,
                                               const float* __restrict__ b2f,
                                               const float* __restrict__ x,
                                               float* __restrict__ out) {
  int bid = blockIdx.x;      // 1568
  int b = bid & 7;
  int ng = bid >> 3;
  int n0 = ng * 16;
  int lane = threadIdx.x;
  int ob = lane & 15, nq = lane >> 4;

  __shared__ float w_lds[24 * OUT_WSTR];  // 9600 B
  __shared__ float a_lds[24 * 16];        // 1536 B

  float acc[4][6];
#pragma unroll
  for (int q = 0; q < 4; ++q)
#pragma unroll
    for (int oo = 0; oo < 6; ++oo) acc[q][oo] = 0.f;

  const float* ab = aggt + ((size_t)b * NPT + n0) * 192;

  for (int ch = 0; ch < 8; ++ch) {
    __syncthreads();
    {
      const float* wsrc = W2f + ch * 24 * 96;
#pragma unroll
      for (int it = 0; it < 9; ++it) {
        int i = lane * 4 + it * 256;
        float4 v = *(const float4*)&wsrc[i];
        int cc = i / 96, o = i % 96;
        *(float4*)&w_lds[cc * OUT_WSTR + o] = v;
      }
#pragma unroll
      for (int it = 0; it < 2; ++it) {
        int i = lane + it * 64;
        if (i < 96) {
          int nn = i / 6, c4 = i % 6;
          float4 v = *(const float4*)&ab[(size_t)nn * 192 + ch * 24 + c4 * 4];
          a_lds[(c4 * 4 + 0) * 16 + nn] = v.x;
          a_lds[(c4 * 4 + 1) * 16 + nn] = v.y;
          a_lds[(c4 * 4 + 2) * 16 + nn] = v.z;
          a_lds[(c4 * 4 + 3) * 16 + nn] = v.w;
        }
      }
    }
    __syncthreads();
#pragma unroll
    for (int cc = 0; cc < 24; ++cc) {
      float4 a = *(const float4*)&a_lds[cc * 16 + nq * 4];
      const float* wp = &w_lds[cc * OUT_WSTR + ob * 6];
      float2 w01 = *(const float2*)&wp[0];
      float2 w23 = *(const float2*)&wp[2];
      float2 w45 = *(const float2*)&wp[4];
      float w[6] = {w01.x, w01.y, w23.x, w23.y, w45.x, w45.y};
#pragma unroll
      for (int oo = 0; oo < 6; ++oo) {
        acc[0][oo] = fmaf(w[oo], a.x, acc[0][oo]);
        acc[1][oo] = fmaf(w[oo], a.y, acc[1][oo]);
        acc[2][oo] = fmaf(w[oo], a.z, acc[2][oo]);
        acc[3][oo] = fmaf(w[oo], a.w, acc[3][oo]);
      }
    }
  }

  const float* xb = x + (size_t)b * NC * NPT;
  float* ob_out = out + (size_t)b * NC * NPT;
#pragma unroll
  for (int oo = 0; oo < 6; ++oo) {
    int o = ob * 6 + oo;
    float bb = b2f[o];
#pragma unroll
    for (int q = 0; q < 4; ++q) {
      int n = n0 + nq * 4 + q;
      ob_out[(size_t)o * NPT + n] = acc[q][oo] + bb + xb[(size_t)o * NPT + n];
    }
  }
}

extern "C" void kernel_launch(void* const* d_in, const int* in_sizes, int n_in,
                              void* d_out, int out_size, void* d_ws, size_t ws_size,
                              hipStream_t stream) {
  const float* x  = (const float*)d_in[0];
  const float* W1 = (const float*)d_in[1];
  const float* b1 = (const float*)d_in[2];
  const float* g1 = (const float*)d_in[3];
  const float* be1= (const float*)d_in[4];
  const float* m1 = (const float*)d_in[5];
  const float* v1 = (const float*)d_in[6];
  const float* Wg = (const float*)d_in[7];
  const float* bg = (const float*)d_in[8];
  const float* W2 = (const float*)d_in[9];
  const float* b2 = (const float*)d_in[10];
  const float* g2 = (const float*)d_in[11];
  const float* be2= (const float*)d_in[12];
  const float* m2 = (const float*)d_in[13];
  const float* v2 = (const float*)d_in[14];
  float* out = (float*)d_out;

  float* ws = (float*)d_ws;
  size_t off = 0;
  float* feat = ws + off; off += (size_t)NB * NC * NPT;             // 9.6 MB
  unsigned short* hiT = (unsigned short*)(ws + off); off += (size_t)NB * NPT * NC / 2;
  unsigned short* loT = (unsigned short*)(ws + off); off += (size_t)NB * NPT * NC / 2;
  float* uvt  = ws + off; off += (size_t)NB * NPT * 384;            // 38.5 MB
  float* aggt = ws + off; off += (size_t)NB * NPT * 192;            // 19.3 MB
  float* W1s  = ws + off; off += NC * NC;
  float* Wuv  = ws + off; off += NC * 2 * NC2;
  float* W2f  = ws + off; off += NC2 * NC;
  float* b1f  = ws + off; off += 128;
  float* b2f  = ws + off; off += 128;

  // Phase-disjoint overlays (unchanged):
  float* fnT    = aggt;
  unsigned* pk  = (unsigned*)uvt;   // 14.5 MB <= uvt; [row][list16][dep9] contiguous
  int* cand     = (int*)hiT;
  int* nn_idx   = (int*)loT;

  k_fuse<<<dim3(64), 256, 0, stream>>>(W1, b1, g1, be1, m1, v1, Wg, W2, b2, g2, be2, m2, v2,
                                       W1s, b1f, Wuv, W2f, b2f);
  k_feat<<<dim3(NB * 196), 64, 0, stream>>>(x, W1s, b1f, feat, fnT, hiT, loT);
  k_knn<<<dim3(NB * 98 * 4), 256, 0, stream>>>(hiT, loT, pk);
  k_nnmerge<<<dim3(NROWS / 4), 256, 0, stream>>>(pk, cand);
  k_rescore<<<dim3(NROWS / 4), 256, 0, stream>>>(fnT, cand, nn_idx);
  k_uv<<<dim3(NB * 196), 64, 0, stream>>>(feat, Wuv, bg, uvt);
  k_gather<<<dim3(NB * NPT / 4), 192, 0, stream>>>(uvt, nn_idx, aggt);
  k_out<<<dim3(NB * 196), 64, 0, stream>>>(aggt, W2f, b2f, x, out);
}

// Round 14
// 224.131 us; speedup vs baseline: 1.5675x; 1.1708x over previous
//
#include <hip/hip_runtime.h>
#include <cstdint>

#define NB 8
#define NC 96
#define NC2 192
#define NPT 3136    // 56*56
#define NK 9
#define NSPL 16     // j-splits
#define NLIST 16    // lists per row after in-wave half-merge
#define NDEP 9      // per-list depth (>= NK for superset guarantee)
#define NCAND 16    // pooled candidate count per row
#define NROWS (NB * NPT)
#define RST 104     // fnT row stride (96 fn + sq at [96] + pad)
#define FT_WSTR 76  // k_feat LDS per-ob stride
static constexpr float BN_EPS = 1e-5f;
typedef unsigned long long u64;
typedef float f32x16 __attribute__((ext_vector_type(16)));
typedef short short8 __attribute__((ext_vector_type(8)));

__device__ inline unsigned short f32_to_bf16_rne(float x) {
  unsigned u = __float_as_uint(x);
  unsigned r = (u + 0x7FFFu + ((u >> 16) & 1u)) >> 16;
  return (unsigned short)r;
}

__device__ inline unsigned score_to_key_exact(float s) {
  unsigned u = __float_as_uint(s);
  u ^= 0x80000000u | (unsigned)((int)u >> 31);  // monotone increasing map
  return ~u;                                    // descending score = ascending dist
}

__device__ inline u64 shfl_xor64(u64 x, int m) {
  unsigned lo = __shfl_xor((unsigned)x, m);
  unsigned hi = __shfl_xor((unsigned)(x >> 32), m);
  return ((u64)hi << 32) | lo;
}

// ---------------- K1: fold BN into weights; bf16 hi/lo weight layouts ------------------
// W1s: swizzled [ch8][ob16][cc12][oo6] f32 for k_feat.
// Wuvh/Wuvl: [o4=384][c=96] bf16 hi/lo of [A;B] (A=Wg[:, :96]-Wg[:, 96:], B=Wg[:, 96:]).
// W2h/W2l:  [o=96][c=192] bf16 hi/lo of BN-folded W2.
__global__ void k_fuse(const float* __restrict__ W1, const float* __restrict__ b1,
                       const float* __restrict__ g1, const float* __restrict__ be1,
                       const float* __restrict__ m1, const float* __restrict__ v1,
                       const float* __restrict__ Wg,
                       const float* __restrict__ W2, const float* __restrict__ b2,
                       const float* __restrict__ g2, const float* __restrict__ be2,
                       const float* __restrict__ m2, const float* __restrict__ v2,
                       float* __restrict__ W1s, float* __restrict__ b1f,
                       unsigned short* __restrict__ Wuvh, unsigned short* __restrict__ Wuvl,
                       unsigned short* __restrict__ W2h, unsigned short* __restrict__ W2l,
                       float* __restrict__ b2f) {
  int t = blockIdx.x * blockDim.x + threadIdx.x;
  int nth = gridDim.x * blockDim.x;
  for (int i = t; i < NC * NC; i += nth) {
    int ch = i / 1152, r = i % 1152;
    int ob = r / 72, r2 = r % 72;
    int cc = r2 / 6, oo = r2 % 6;
    int c = ch * 12 + cc, o = ob * 6 + oo;
    float inv = g1[o] / sqrtf(v1[o] + BN_EPS);
    W1s[i] = W1[o * NC + c] * inv;
  }
  for (int o = t; o < NC; o += nth) {
    float inv = g1[o] / sqrtf(v1[o] + BN_EPS);
    b1f[o] = b1[o] * inv + be1[o] - m1[o] * inv;
    float inv2v = g2[o] / sqrtf(v2[o] + BN_EPS);
    b2f[o] = b2[o] * inv2v + be2[o] - m2[o] * inv2v;
  }
  for (int i = t; i < 2 * NC2 * NC; i += nth) {
    int o4 = i / NC, c = i % NC;
    float val;
    if (o4 < NC2) val = Wg[o4 * NC2 + c] - Wg[o4 * NC2 + NC + c];
    else          val = Wg[(o4 - NC2) * NC2 + NC + c];
    unsigned short h = f32_to_bf16_rne(val);
    float hv = __uint_as_float(((unsigned)h) << 16);
    Wuvh[i] = h;
    Wuvl[i] = f32_to_bf16_rne(val - hv);
  }
  for (int i = t; i < NC * NC2; i += nth) {
    int o = i / NC2, c = i % NC2;
    float inv = g2[o] / sqrtf(v2[o] + BN_EPS);
    float val = W2[o * NC2 + c] * inv;
    unsigned short h = f32_to_bf16_rne(val);
    float hv = __uint_as_float(((unsigned)h) << 16);
    W2h[i] = h;
    W2l[i] = f32_to_bf16_rne(val - hv);
  }
}

// ------- K2: feat = BN(W1 x + b1) -> bf16 hi/lo rows; fnT f32 norm rows; hiT/loT -------
__global__ __launch_bounds__(64, 4) void k_feat(const float* __restrict__ x,
                                                const float* __restrict__ W1s,
                                                const float* __restrict__ b1f,
                                                unsigned short* __restrict__ fth,
                                                unsigned short* __restrict__ ftl,
                                                float* __restrict__ fnT,
                                                unsigned short* __restrict__ hiT,
                                                unsigned short* __restrict__ loT) {
  int bid = blockIdx.x;      // 1568
  int b = bid & 7;
  int ng = bid >> 3;         // 0..195
  int n0 = ng * 16;
  int lane = threadIdx.x;
  int ob = lane & 15, nq = lane >> 4;

  __shared__ float w_lds[16 * FT_WSTR];  // 4864 B
  __shared__ float f_lds[12 * 16];       // 768 B

  const float* xb = x + (size_t)b * NC * NPT;
  float acc[4][6];
#pragma unroll
  for (int oo = 0; oo < 6; ++oo) {
    float bv = b1f[ob * 6 + oo];
#pragma unroll
    for (int q = 0; q < 4; ++q) acc[q][oo] = bv;
  }

  for (int ch = 0; ch < 8; ++ch) {
    __syncthreads();
    {
      const float* wsrc = W1s + ch * 1152;
#pragma unroll
      for (int it = 0; it < 5; ++it) {
        int i = it * 256 + lane * 4;
        if (it < 4 || lane < 32) {
          float4 v = *(const float4*)&wsrc[i];
          *(float4*)&w_lds[(i / 72) * FT_WSTR + (i % 72)] = v;
        }
      }
#pragma unroll
      for (int it = 0; it < 3; ++it) {
        int i = it * 64 + lane;
        f_lds[i] = xb[(size_t)(ch * 12 + (i >> 4)) * NPT + n0 + (i & 15)];
      }
    }
    __syncthreads();
#pragma unroll
    for (int cc = 0; cc < 12; ++cc) {
      float4 a = *(const float4*)&f_lds[cc * 16 + nq * 4];
      const float* wp = &w_lds[ob * FT_WSTR + cc * 6];
      float2 w01 = *(const float2*)&wp[0];
      float2 w23 = *(const float2*)&wp[2];
      float2 w45 = *(const float2*)&wp[4];
      float w[6] = {w01.x, w01.y, w23.x, w23.y, w45.x, w45.y};
#pragma unroll
      for (int oo = 0; oo < 6; ++oo) {
        acc[0][oo] = fmaf(w[oo], a.x, acc[0][oo]);
        acc[1][oo] = fmaf(w[oo], a.y, acc[1][oo]);
        acc[2][oo] = fmaf(w[oo], a.z, acc[2][oo]);
        acc[3][oo] = fmaf(w[oo], a.w, acc[3][oo]);
      }
    }
  }

  float sq[4];
#pragma unroll
  for (int q = 0; q < 4; ++q) {
    float s = 0.f;
#pragma unroll
    for (int oo = 0; oo < 6; ++oo) s += acc[q][oo] * acc[q][oo];
    sq[q] = s;
  }
#pragma unroll
  for (int m = 1; m < 16; m <<= 1) {
#pragma unroll
    for (int q = 0; q < 4; ++q) sq[q] += __shfl_xor(sq[q], m);
  }

  float vnn[4][6];
  float sqn[4];
#pragma unroll
  for (int q = 0; q < 4; ++q) {
    float den = fmaxf(sqrtf(sq[q]), 1e-12f);
    float s = 0.f;
#pragma unroll
    for (int oo = 0; oo < 6; ++oo) {
      float v = acc[q][oo] / den;
      vnn[q][oo] = v;
      s += v * v;
    }
    sqn[q] = s;
  }
#pragma unroll
  for (int m = 1; m < 16; m <<= 1) {
#pragma unroll
    for (int q = 0; q < 4; ++q) sqn[q] += __shfl_xor(sqn[q], m);
  }

#pragma unroll
  for (int q = 0; q < 4; ++q) {
    int n = n0 + nq * 4 + q;
    // raw feat -> bf16 hi/lo rows [n][96]
    unsigned short* fhr = fth + ((size_t)b * NPT + n) * NC + ob * 6;
    unsigned short* flr = ftl + ((size_t)b * NPT + n) * NC + ob * 6;
#pragma unroll
    for (int p2 = 0; p2 < 3; ++p2) {
      float v0 = acc[q][p2 * 2], v1 = acc[q][p2 * 2 + 1];
      unsigned short h0 = f32_to_bf16_rne(v0);
      unsigned short h1 = f32_to_bf16_rne(v1);
      float hv0 = __uint_as_float(((unsigned)h0) << 16);
      float hv1 = __uint_as_float(((unsigned)h1) << 16);
      unsigned short l0 = f32_to_bf16_rne(v0 - hv0);
      unsigned short l1 = f32_to_bf16_rne(v1 - hv1);
      *(unsigned*)&fhr[p2 * 2] = (unsigned)h0 | ((unsigned)h1 << 16);
      *(unsigned*)&flr[p2 * 2] = (unsigned)l0 | ((unsigned)l1 << 16);
    }
    float* fr = fnT + ((size_t)b * NPT + n) * RST;
#pragma unroll
    for (int oo = 0; oo < 6; ++oo) fr[ob * 6 + oo] = vnn[q][oo];
    if (ob == 0) fr[96] = sqn[q];
    unsigned short* hr = hiT + ((size_t)b * NPT + n) * NC + ob * 6;
    unsigned short* lr = loT + ((size_t)b * NPT + n) * NC + ob * 6;
#pragma unroll
    for (int p2 = 0; p2 < 3; ++p2) {
      float v0 = vnn[q][p2 * 2], v1 = vnn[q][p2 * 2 + 1];
      unsigned short h0 = f32_to_bf16_rne(v0);
      unsigned short h1 = f32_to_bf16_rne(v1);
      float hv0 = __uint_as_float(((unsigned)h0) << 16);
      float hv1 = __uint_as_float(((unsigned)h1) << 16);
      unsigned short l0 = f32_to_bf16_rne(v0 - hv0);
      unsigned short l1 = f32_to_bf16_rne(v1 - hv1);
      *(unsigned*)&hr[p2 * 2] = (unsigned)h0 | ((unsigned)h1 << 16);
      *(unsigned*)&lr[p2 * 2] = (unsigned)l0 | ((unsigned)l1 << 16);
    }
  }
}

// ---------------- K3: KNN candidate gen via compensated bf16 MFMA ----------------------
__global__ __launch_bounds__(256, 4) void k_knn(const unsigned short* __restrict__ hiT,
                                                const unsigned short* __restrict__ loT,
                                                unsigned* __restrict__ pk) {
  int bid = blockIdx.x;
  int b = bid & 7;            // XCD affinity
  int r2 = bid >> 3;          // 0..391
  int iblk = r2 % 98;
  int jp = r2 / 98;           // 0..3
  int wq = threadIdx.x >> 6;
  int jsplit = jp * 4 + wq;   // 0..15
  int lane = threadIdx.x & 63;
  int col = lane & 31;
  int half = lane >> 5;
  int i = iblk * 32 + col;

  const unsigned short* hb = hiT + (size_t)b * NPT * NC;
  const unsigned short* lb = loT + (size_t)b * NPT * NC;

  short8 Bh[6], Bl[6];
  {
    const unsigned short* ih = hb + (size_t)i * NC + half * 8;
    const unsigned short* il = lb + (size_t)i * NC + half * 8;
#pragma unroll
    for (int ch = 0; ch < 6; ++ch) {
      Bh[ch] = *(const short8*)(ih + ch * 16);
      Bl[ch] = *(const short8*)(il + ch * 16);
    }
  }

  float kk[NDEP];
#pragma unroll
  for (int k = 0; k < NDEP; ++k) kk[k] = 0.0f;   // 0.0 < any real key (+1..3)

  int t0 = (98 * jsplit) >> 4, t1 = (98 * (jsplit + 1)) >> 4;
  int jbase = t0 * 32;
  for (int t = t0; t < t1; ++t) {
    int j0 = t * 32;
    const unsigned short* ah = hb + (size_t)(j0 + col) * NC + half * 8;
    f32x16 acc0, acc1;
#pragma unroll
    for (int r = 0; r < 16; ++r) { acc0[r] = 2.0f; acc1[r] = 0.f; }
    {
      short8 A[6];
#pragma unroll
      for (int ch = 0; ch < 6; ++ch) A[ch] = *(const short8*)(ah + ch * 16);
#pragma unroll
      for (int ch = 0; ch < 6; ++ch)
        acc0 = __builtin_amdgcn_mfma_f32_32x32x16_bf16(A[ch], Bh[ch], acc0, 0, 0, 0);
#pragma unroll
      for (int ch = 0; ch < 6; ++ch)
        acc1 = __builtin_amdgcn_mfma_f32_32x32x16_bf16(A[ch], Bl[ch], acc1, 0, 0, 0);
    }
    unsigned relbase = (unsigned)(j0 - jbase + 4 * half);
#pragma unroll
    for (int r = 0; r < 16; ++r) {
      float s = acc0[r] + acc1[r];            // = score + 2.0 (positive, in [1,3])
      unsigned kb = __float_as_uint(s);
      unsigned keyu = (kb & 0xFFFFFE00u) | (relbase + (unsigned)((r & 3) + 8 * (r >> 2)));
      float e = __uint_as_float(keyu);
#pragma unroll
      for (int s8 = NDEP - 1; s8 > 0; --s8)
        kk[s8] = __builtin_amdgcn_fmed3f(kk[s8 - 1], kk[s8], e);
      kk[0] = fmaxf(kk[0], e);
    }
  }

  // in-wave half-merge: top-9 of the two disjoint half-lists (merge-path identity)
  float c[NDEP];
#pragma unroll
  for (int k = 0; k < NDEP; ++k) {
    float pv = __shfl_xor(kk[NDEP - 1 - k], 32);
    c[k] = fmaxf(kk[k], pv);
  }
  if (half == 0) {
    unsigned* op = pk + (size_t)((size_t)b * NPT + i) * (NLIST * NDEP) + jsplit * NDEP;
#pragma unroll
    for (int k = 0; k < NDEP; ++k) op[k] = __float_as_uint(c[k]);
  }
}

// ---------------- K3b: wave-per-row tournament -> top-16 candidate set -----------------
__global__ __launch_bounds__(256) void k_nnmerge(const unsigned* __restrict__ pk,
                                                 int* __restrict__ cand) {
  int wid = threadIdx.x >> 6, lane = threadIdx.x & 63;
  int row = blockIdx.x * 4 + wid;          // grid exact: NROWS/4
  const unsigned* p = pk + (size_t)row * (NLIST * NDEP);
  u64 e0 = 0, e1 = 0, e2 = 0, e3 = 0;
  if (lane < 36) {
    uint4 v = *(const uint4*)&p[lane * 4];
    int g0 = lane * 4;
    int s0 = g0 / 9, s1 = (g0 + 1) / 9, s2 = (g0 + 2) / 9, s3 = (g0 + 3) / 9;
    int jb0 = ((98 * s0) >> 4) << 5, jb1 = ((98 * s1) >> 4) << 5;
    int jb2 = ((98 * s2) >> 4) << 5, jb3 = ((98 * s3) >> 4) << 5;
    e0 = ((u64)v.x << 16) | (unsigned)(jb0 + (int)(v.x & 0x1FFu));
    e1 = ((u64)v.y << 16) | (unsigned)(jb1 + (int)(v.y & 0x1FFu));
    e2 = ((u64)v.z << 16) | (unsigned)(jb2 + (int)(v.z & 0x1FFu));
    e3 = ((u64)v.w << 16) | (unsigned)(jb3 + (int)(v.w & 0x1FFu));
  }
  int* op = cand + (size_t)row * NCAND;
  for (int r = 0; r < NCAND; ++r) {
    u64 a = e0 > e1 ? e0 : e1;
    u64 bmx = e2 > e3 ? e2 : e3;
    u64 loc = a > bmx ? a : bmx;
#pragma unroll
    for (int m = 1; m < 64; m <<= 1) {
      u64 o = shfl_xor64(loc, m);
      loc = o > loc ? o : loc;
    }
    e0 = (e0 == loc) ? 0 : e0;
    e1 = (e1 == loc) ? 0 : e1;
    e2 = (e2 == loc) ? 0 : e2;
    e3 = (e3 == loc) ? 0 : e3;
    if (lane == 0) op[r] = (int)(loc & 0xFFFFu);
  }
}

// ---------------- K3c: f32 rescore of 16 candidates -> exact top-9 ---------------------
__global__ __launch_bounds__(256) void k_rescore(const float* __restrict__ fnT,
                                                 const int* __restrict__ cand,
                                                 int* __restrict__ nn_idx) {
  __shared__ u64 kl[4][NCAND];
  int wid = threadIdx.x >> 6, lane = threadIdx.x & 63;
  int row = blockIdx.x * 4 + wid;            // 0..25087 (grid exact)
  int b = row / NPT;
  int c = lane >> 2, sub = lane & 3;
  int j = cand[(size_t)row * NCAND + c];
  const float* fi = fnT + (size_t)row * RST + sub * 24;
  const float* fj = fnT + (size_t)(b * NPT + j) * RST + sub * 24;
  float p = 0.f;
#pragma unroll
  for (int c4 = 0; c4 < 6; ++c4) {
    float4 a = *(const float4*)&fi[c4 * 4];
    float4 v = *(const float4*)&fj[c4 * 4];
    p = fmaf(a.x, v.x, p); p = fmaf(a.y, v.y, p);
    p = fmaf(a.z, v.z, p); p = fmaf(a.w, v.w, p);
  }
  p += __shfl_xor(p, 1);
  p += __shfl_xor(p, 2);
  if (sub == 0) {
    float sqj = fnT[(size_t)(b * NPT + j) * RST + 96];
    float score = fmaf(-0.5f, sqj, p);
    kl[wid][c] = ((u64)score_to_key_exact(score) << 32) | (unsigned)j;
  }
  __syncthreads();
  if (lane == 0) {
    u64 k9[NK];
#pragma unroll
    for (int k = 0; k < NK; ++k) k9[k] = ~0ull;
#pragma unroll
    for (int t = 0; t < NCAND; ++t) {
      u64 key = kl[wid][t];
      if (key < k9[NK - 1]) {
        k9[NK - 1] = key;
#pragma unroll
        for (int q = NK - 1; q > 0; --q) {
          u64 xx = k9[q - 1], yy = k9[q];
          bool sw = yy < xx;
          k9[q - 1] = sw ? yy : xx;
          k9[q]     = sw ? xx : yy;
        }
      }
    }
    int* op = nn_idx + (size_t)row * NK;
#pragma unroll
    for (int k = 0; k < NK; ++k) op[k] = (int)(unsigned)(k9[k] & 0xFFFFFFFFu);
  }
}

// ---------------- K4: uvt[n][o] via compensated bf16 MFMA ------------------------------
// Wave = one 32n x 32o tile. D rows = n (A = feat rows), cols = o (B = Wuv rows).
// dot = fh.wh + fh.wl + fl.wh (dropped fl.wl ~4e-6 rel).
__global__ __launch_bounds__(256, 4) void k_uv(const unsigned short* __restrict__ fth,
                                               const unsigned short* __restrict__ ftl,
                                               const unsigned short* __restrict__ Wuvh,
                                               const unsigned short* __restrict__ Wuvl,
                                               const float* __restrict__ bg,
                                               float* __restrict__ uvt) {
  int bid = blockIdx.x;        // 2352 = 8b * 98nt * 3og
  int b = bid & 7;
  int t = bid >> 3;            // 0..293
  int nt = t % 98;
  int og = t / 98;             // 0..2
  int w = threadIdx.x >> 6;
  int ot = og * 4 + w;         // 0..11
  int lane = threadIdx.x & 63;
  int col = lane & 31, half = lane >> 5;
  int n0 = nt * 32, o0 = ot * 32;

  const unsigned short* fhp = fth + ((size_t)b * NPT + n0 + col) * NC + half * 8;
  const unsigned short* flp = ftl + ((size_t)b * NPT + n0 + col) * NC + half * 8;
  const unsigned short* whp = Wuvh + (size_t)(o0 + col) * NC + half * 8;
  const unsigned short* wlp = Wuvl + (size_t)(o0 + col) * NC + half * 8;

  f32x16 acc0, acc1;
#pragma unroll
  for (int r = 0; r < 16; ++r) { acc0[r] = 0.f; acc1[r] = 0.f; }
#pragma unroll
  for (int ch = 0; ch < 6; ++ch) {
    short8 ahv = *(const short8*)(fhp + ch * 16);
    short8 alv = *(const short8*)(flp + ch * 16);
    short8 bhv = *(const short8*)(whp + ch * 16);
    short8 blv = *(const short8*)(wlp + ch * 16);
    acc0 = __builtin_amdgcn_mfma_f32_32x32x16_bf16(ahv, bhv, acc0, 0, 0, 0);
    acc1 = __builtin_amdgcn_mfma_f32_32x32x16_bf16(ahv, blv, acc1, 0, 0, 0);
    acc0 = __builtin_amdgcn_mfma_f32_32x32x16_bf16(alv, bhv, acc0, 0, 0, 0);
  }

  int o = o0 + col;
  float bias = (o < NC2) ? bg[o] : 0.f;
  float* up = uvt + ((size_t)b * NPT + n0) * 384 + o;
#pragma unroll
  for (int r = 0; r < 16; ++r) {
    int nrow = (r & 3) + 8 * (r >> 2) + 4 * half;
    up[(size_t)nrow * 384] = acc0[r] + acc1[r] + bias;
  }
}

// ---------------- K5: agg = relu(max_k (u + v[idx])) -> bf16 hi/lo rows [n][192] -------
__global__ __launch_bounds__(192) void k_gather(const float* __restrict__ uvt,
                                                const int* __restrict__ nn_idx,
                                                unsigned short* __restrict__ aggh,
                                                unsigned short* __restrict__ aggl) {
  int bid = blockIdx.x;
  int b = bid & 7;      // XCD affinity for the per-batch v table
  int ng = bid >> 3;    // 0..783
  int tid = threadIdx.x;
  int nq = tid / 48, c4 = tid % 48;
  int n = ng * 4 + nq;
  const float* base = uvt + (size_t)b * NPT * 384;
  const int* ip = nn_idx + ((size_t)b * NPT + n) * NK;
  float4 u = *(const float4*)&base[(size_t)n * 384 + c4 * 4];
  float4 acc = make_float4(-1e30f, -1e30f, -1e30f, -1e30f);
#pragma unroll
  for (int k = 0; k < NK; ++k) {
    int j = ip[k];
    float4 v = *(const float4*)&base[(size_t)j * 384 + 192 + c4 * 4];
    acc.x = fmaxf(acc.x, u.x + v.x);
    acc.y = fmaxf(acc.y, u.y + v.y);
    acc.z = fmaxf(acc.z, u.z + v.z);
    acc.w = fmaxf(acc.w, u.w + v.w);
  }
  float o4[4];
  o4[0] = fmaxf(acc.x, 0.f); o4[1] = fmaxf(acc.y, 0.f);
  o4[2] = fmaxf(acc.z, 0.f); o4[3] = fmaxf(acc.w, 0.f);
  u64 hp = 0, lp = 0;
#pragma unroll
  for (int e = 0; e < 4; ++e) {
    unsigned short h = f32_to_bf16_rne(o4[e]);
    float hv = __uint_as_float(((unsigned)h) << 16);
    unsigned short l = f32_to_bf16_rne(o4[e] - hv);
    hp |= ((u64)h) << (16 * e);
    lp |= ((u64)l) << (16 * e);
  }
  size_t off = ((size_t)b * NPT + n) * NC2 + c4 * 4;
  *(u64*)&aggh[off] = hp;
  *(u64*)&aggl[off] = lp;
}

// ---------------- K6: out = W2 @ agg + b2f + residual, via compensated bf16 MFMA -------
// Wave = one 32o x 32n tile. D rows = o (A = W2 rows), cols = n (B = agg rows).
__global__ __launch_bounds__(64, 4) void k_out(const unsigned short* __restrict__ W2h,
                                               const unsigned short* __restrict__ W2l,
                                               const unsigned short* __restrict__ aggh,
                                               const unsigned short* __restrict__ aggl,
                                               const float* __restrict__ b2f,
                                               const float* __restrict__ x,
                                               float* __restrict__ out) {
  int bid = blockIdx.x;        // 2352 = 8b * 98nt * 3ot
  int b = bid & 7;
  int t = bid >> 3;            // 0..293
  int nt = t % 98;
  int ot = t / 98;             // 0..2
  int lane = threadIdx.x;
  int col = lane & 31, half = lane >> 5;
  int n0 = nt * 32, o0 = ot * 32;

  const unsigned short* whp = W2h + (size_t)(o0 + col) * NC2 + half * 8;
  const unsigned short* wlp = W2l + (size_t)(o0 + col) * NC2 + half * 8;
  const unsigned short* ahp = aggh + ((size_t)b * NPT + n0 + col) * NC2 + half * 8;
  const unsigned short* alp = aggl + ((size_t)b * NPT + n0 + col) * NC2 + half * 8;

  f32x16 acc0, acc1;
#pragma unroll
  for (int r = 0; r < 16; ++r) { acc0[r] = 0.f; acc1[r] = 0.f; }
#pragma unroll
  for (int ch = 0; ch < 12; ++ch) {
    short8 whv = *(const short8*)(whp + ch * 16);
    short8 wlv = *(const short8*)(wlp + ch * 16);
    short8 ahv = *(const short8*)(ahp + ch * 16);
    short8 alv = *(const short8*)(alp + ch * 16);
    acc0 = __builtin_amdgcn_mfma_f32_32x32x16_bf16(whv, ahv, acc0, 0, 0, 0);
    acc1 = __builtin_amdgcn_mfma_f32_32x32x16_bf16(whv, alv, acc1, 0, 0, 0);
    acc0 = __builtin_amdgcn_mfma_f32_32x32x16_bf16(wlv, ahv, acc0, 0, 0, 0);
  }

  int n = n0 + col;
  const float* xb = x + (size_t)b * NC * NPT;
  float* ob = out + (size_t)b * NC * NPT;
#pragma unroll
  for (int r = 0; r < 16; ++r) {
    int orow = o0 + (r & 3) + 8 * (r >> 2) + 4 * half;
    float v = acc0[r] + acc1[r] + b2f[orow] + xb[(size_t)orow * NPT + n];
    ob[(size_t)orow * NPT + n] = v;
  }
}

extern "C" void kernel_launch(void* const* d_in, const int* in_sizes, int n_in,
                              void* d_out, int out_size, void* d_ws, size_t ws_size,
                              hipStream_t stream) {
  const float* x  = (const float*)d_in[0];
  const float* W1 = (const float*)d_in[1];
  const float* b1 = (const float*)d_in[2];
  const float* g1 = (const float*)d_in[3];
  const float* be1= (const float*)d_in[4];
  const float* m1 = (const float*)d_in[5];
  const float* v1 = (const float*)d_in[6];
  const float* Wg = (const float*)d_in[7];
  const float* bg = (const float*)d_in[8];
  const float* W2 = (const float*)d_in[9];
  const float* b2 = (const float*)d_in[10];
  const float* g2 = (const float*)d_in[11];
  const float* be2= (const float*)d_in[12];
  const float* m2 = (const float*)d_in[13];
  const float* v2 = (const float*)d_in[14];
  float* out = (float*)d_out;

  float* ws = (float*)d_ws;
  size_t off = 0;
  unsigned short* fth = (unsigned short*)(ws + off); off += (size_t)NB * NPT * NC / 2;  // 4.8 MB
  unsigned short* ftl = (unsigned short*)(ws + off); off += (size_t)NB * NPT * NC / 2;  // 4.8 MB
  unsigned short* hiT = (unsigned short*)(ws + off); off += (size_t)NB * NPT * NC / 2;  // 4.8 MB
  unsigned short* loT = (unsigned short*)(ws + off); off += (size_t)NB * NPT * NC / 2;  // 4.8 MB
  float* uvt  = ws + off; off += (size_t)NB * NPT * 384;            // 38.5 MB
  float* aggr = ws + off; off += (size_t)NB * NPT * 192;            // 19.3 MB (fnT / aggh+aggl)
  float* W1s  = ws + off; off += NC * NC;
  unsigned short* Wuvh = (unsigned short*)(ws + off); off += NC * NC2;      // 36864 u16
  unsigned short* Wuvl = (unsigned short*)(ws + off); off += NC * NC2;
  unsigned short* W2h  = (unsigned short*)(ws + off); off += NC * NC2 / 2;  // 18432 u16
  unsigned short* W2l  = (unsigned short*)(ws + off); off += NC * NC2 / 2;
  float* b1f  = ws + off; off += 128;
  float* b2f  = ws + off; off += 128;

  // Phase-disjoint overlays:
  //   fnT (10.4 MB) lives in aggr region; dead after k_rescore.
  //   aggh/aggl (9.6+9.6 MB) live in aggr region; written by k_gather (after rescore).
  //   pk (14.5 MB) overlays uvt; consumed by k_nnmerge before k_uv writes uvt.
  //   cand -> hiT region (dead after k_knn); nn_idx -> loT region (dead after k_knn).
  float* fnT    = aggr;
  unsigned short* aggh = (unsigned short*)aggr;
  unsigned short* aggl = aggh + (size_t)NB * NPT * NC2;
  unsigned* pk  = (unsigned*)uvt;
  int* cand     = (int*)hiT;
  int* nn_idx   = (int*)loT;

  k_fuse<<<dim3(64), 256, 0, stream>>>(W1, b1, g1, be1, m1, v1, Wg, W2, b2, g2, be2, m2, v2,
                                       W1s, b1f, Wuvh, Wuvl, W2h, W2l, b2f);
  k_feat<<<dim3(NB * 196), 64, 0, stream>>>(x, W1s, b1f, fth, ftl, fnT, hiT, loT);
  k_knn<<<dim3(NB * 98 * 4), 256, 0, stream>>>(hiT, loT, pk);
  k_nnmerge<<<dim3(NROWS / 4), 256, 0, stream>>>(pk, cand);
  k_rescore<<<dim3(NROWS / 4), 256, 0, stream>>>(fnT, cand, nn_idx);
  k_uv<<<dim3(NB * 98 * 3), 256, 0, stream>>>(fth, ftl, Wuvh, Wuvl, bg, uvt);
  k_gather<<<dim3(NB * NPT / 4), 192, 0, stream>>>(uvt, nn_idx, aggh, aggl);
  k_out<<<dim3(NB * 98 * 3), 64, 0, stream>>>(W2h, W2l, aggh, aggl, b2f, x, out);
}

// Round 15
// 220.537 us; speedup vs baseline: 1.5930x; 1.0163x over previous
//
#include <hip/hip_runtime.h>
#include <cstdint>

#define NB 8
#define NC 96
#define NC2 192
#define NPT 3136    // 56*56
#define NK 9
#define NSPL 16     // j-splits
#define NLIST 16    // lists per row after in-wave half-merge
#define NDEP 9      // per-list depth (>= NK for superset guarantee)
#define NCAND 16    // pooled candidate count per row
#define NROWS (NB * NPT)
#define RST 104     // fnT row stride (96 fn + sq at [96] + pad)
#define FT_WSTR 76  // k_feat LDS per-ob stride
static constexpr float BN_EPS = 1e-5f;
typedef unsigned long long u64;
typedef float f32x16 __attribute__((ext_vector_type(16)));
typedef short short8 __attribute__((ext_vector_type(8)));

__device__ inline unsigned short f32_to_bf16_rne(float x) {
  unsigned u = __float_as_uint(x);
  unsigned r = (u + 0x7FFFu + ((u >> 16) & 1u)) >> 16;
  return (unsigned short)r;
}

__device__ inline unsigned score_to_key_exact(float s) {
  unsigned u = __float_as_uint(s);
  u ^= 0x80000000u | (unsigned)((int)u >> 31);  // monotone increasing map
  return ~u;                                    // descending score = ascending dist
}

__device__ inline u64 shfl_xor64(u64 x, int m) {
  unsigned lo = __shfl_xor((unsigned)x, m);
  unsigned hi = __shfl_xor((unsigned)(x >> 32), m);
  return ((u64)hi << 32) | lo;
}

// ---------------- K1: fold BN into weights; bf16 hi/lo weight layouts ------------------
__global__ void k_fuse(const float* __restrict__ W1, const float* __restrict__ b1,
                       const float* __restrict__ g1, const float* __restrict__ be1,
                       const float* __restrict__ m1, const float* __restrict__ v1,
                       const float* __restrict__ Wg,
                       const float* __restrict__ W2, const float* __restrict__ b2,
                       const float* __restrict__ g2, const float* __restrict__ be2,
                       const float* __restrict__ m2, const float* __restrict__ v2,
                       float* __restrict__ W1s, float* __restrict__ b1f,
                       unsigned short* __restrict__ Wuvh, unsigned short* __restrict__ Wuvl,
                       unsigned short* __restrict__ W2h, unsigned short* __restrict__ W2l,
                       float* __restrict__ b2f) {
  int t = blockIdx.x * blockDim.x + threadIdx.x;
  int nth = gridDim.x * blockDim.x;
  for (int i = t; i < NC * NC; i += nth) {
    int ch = i / 1152, r = i % 1152;
    int ob = r / 72, r2 = r % 72;
    int cc = r2 / 6, oo = r2 % 6;
    int c = ch * 12 + cc, o = ob * 6 + oo;
    float inv = g1[o] / sqrtf(v1[o] + BN_EPS);
    W1s[i] = W1[o * NC + c] * inv;
  }
  for (int o = t; o < NC; o += nth) {
    float inv = g1[o] / sqrtf(v1[o] + BN_EPS);
    b1f[o] = b1[o] * inv + be1[o] - m1[o] * inv;
    float inv2v = g2[o] / sqrtf(v2[o] + BN_EPS);
    b2f[o] = b2[o] * inv2v + be2[o] - m2[o] * inv2v;
  }
  for (int i = t; i < 2 * NC2 * NC; i += nth) {
    int o4 = i / NC, c = i % NC;
    float val;
    if (o4 < NC2) val = Wg[o4 * NC2 + c] - Wg[o4 * NC2 + NC + c];
    else          val = Wg[(o4 - NC2) * NC2 + NC + c];
    unsigned short h = f32_to_bf16_rne(val);
    float hv = __uint_as_float(((unsigned)h) << 16);
    Wuvh[i] = h;
    Wuvl[i] = f32_to_bf16_rne(val - hv);
  }
  for (int i = t; i < NC * NC2; i += nth) {
    int o = i / NC2, c = i % NC2;
    float inv = g2[o] / sqrtf(v2[o] + BN_EPS);
    float val = W2[o * NC2 + c] * inv;
    unsigned short h = f32_to_bf16_rne(val);
    float hv = __uint_as_float(((unsigned)h) << 16);
    W2h[i] = h;
    W2l[i] = f32_to_bf16_rne(val - hv);
  }
}

// ------- K2: feat = BN(W1 x + b1) -> bf16 hi/lo rows; fnT f32 norm rows; hiT/loT -------
__global__ __launch_bounds__(64, 4) void k_feat(const float* __restrict__ x,
                                                const float* __restrict__ W1s,
                                                const float* __restrict__ b1f,
                                                unsigned short* __restrict__ fth,
                                                unsigned short* __restrict__ ftl,
                                                float* __restrict__ fnT,
                                                unsigned short* __restrict__ hiT,
                                                unsigned short* __restrict__ loT) {
  int bid = blockIdx.x;      // 1568
  int b = bid & 7;
  int ng = bid >> 3;         // 0..195
  int n0 = ng * 16;
  int lane = threadIdx.x;
  int ob = lane & 15, nq = lane >> 4;

  __shared__ float w_lds[16 * FT_WSTR];  // 4864 B
  __shared__ float f_lds[12 * 16];       // 768 B

  const float* xb = x + (size_t)b * NC * NPT;
  float acc[4][6];
#pragma unroll
  for (int oo = 0; oo < 6; ++oo) {
    float bv = b1f[ob * 6 + oo];
#pragma unroll
    for (int q = 0; q < 4; ++q) acc[q][oo] = bv;
  }

  for (int ch = 0; ch < 8; ++ch) {
    __syncthreads();
    {
      const float* wsrc = W1s + ch * 1152;
#pragma unroll
      for (int it = 0; it < 5; ++it) {
        int i = it * 256 + lane * 4;
        if (it < 4 || lane < 32) {
          float4 v = *(const float4*)&wsrc[i];
          *(float4*)&w_lds[(i / 72) * FT_WSTR + (i % 72)] = v;
        }
      }
#pragma unroll
      for (int it = 0; it < 3; ++it) {
        int i = it * 64 + lane;
        f_lds[i] = xb[(size_t)(ch * 12 + (i >> 4)) * NPT + n0 + (i & 15)];
      }
    }
    __syncthreads();
#pragma unroll
    for (int cc = 0; cc < 12; ++cc) {
      float4 a = *(const float4*)&f_lds[cc * 16 + nq * 4];
      const float* wp = &w_lds[ob * FT_WSTR + cc * 6];
      float2 w01 = *(const float2*)&wp[0];
      float2 w23 = *(const float2*)&wp[2];
      float2 w45 = *(const float2*)&wp[4];
      float w[6] = {w01.x, w01.y, w23.x, w23.y, w45.x, w45.y};
#pragma unroll
      for (int oo = 0; oo < 6; ++oo) {
        acc[0][oo] = fmaf(w[oo], a.x, acc[0][oo]);
        acc[1][oo] = fmaf(w[oo], a.y, acc[1][oo]);
        acc[2][oo] = fmaf(w[oo], a.z, acc[2][oo]);
        acc[3][oo] = fmaf(w[oo], a.w, acc[3][oo]);
      }
    }
  }

  float sq[4];
#pragma unroll
  for (int q = 0; q < 4; ++q) {
    float s = 0.f;
#pragma unroll
    for (int oo = 0; oo < 6; ++oo) s += acc[q][oo] * acc[q][oo];
    sq[q] = s;
  }
#pragma unroll
  for (int m = 1; m < 16; m <<= 1) {
#pragma unroll
    for (int q = 0; q < 4; ++q) sq[q] += __shfl_xor(sq[q], m);
  }

  float vnn[4][6];
  float sqn[4];
#pragma unroll
  for (int q = 0; q < 4; ++q) {
    float den = fmaxf(sqrtf(sq[q]), 1e-12f);
    float s = 0.f;
#pragma unroll
    for (int oo = 0; oo < 6; ++oo) {
      float v = acc[q][oo] / den;
      vnn[q][oo] = v;
      s += v * v;
    }
    sqn[q] = s;
  }
#pragma unroll
  for (int m = 1; m < 16; m <<= 1) {
#pragma unroll
    for (int q = 0; q < 4; ++q) sqn[q] += __shfl_xor(sqn[q], m);
  }

#pragma unroll
  for (int q = 0; q < 4; ++q) {
    int n = n0 + nq * 4 + q;
    unsigned short* fhr = fth + ((size_t)b * NPT + n) * NC + ob * 6;
    unsigned short* flr = ftl + ((size_t)b * NPT + n) * NC + ob * 6;
#pragma unroll
    for (int p2 = 0; p2 < 3; ++p2) {
      float v0 = acc[q][p2 * 2], v1 = acc[q][p2 * 2 + 1];
      unsigned short h0 = f32_to_bf16_rne(v0);
      unsigned short h1 = f32_to_bf16_rne(v1);
      float hv0 = __uint_as_float(((unsigned)h0) << 16);
      float hv1 = __uint_as_float(((unsigned)h1) << 16);
      unsigned short l0 = f32_to_bf16_rne(v0 - hv0);
      unsigned short l1 = f32_to_bf16_rne(v1 - hv1);
      *(unsigned*)&fhr[p2 * 2] = (unsigned)h0 | ((unsigned)h1 << 16);
      *(unsigned*)&flr[p2 * 2] = (unsigned)l0 | ((unsigned)l1 << 16);
    }
    float* fr = fnT + ((size_t)b * NPT + n) * RST;
#pragma unroll
    for (int oo = 0; oo < 6; ++oo) fr[ob * 6 + oo] = vnn[q][oo];
    if (ob == 0) fr[96] = sqn[q];
    unsigned short* hr = hiT + ((size_t)b * NPT + n) * NC + ob * 6;
    unsigned short* lr = loT + ((size_t)b * NPT + n) * NC + ob * 6;
#pragma unroll
    for (int p2 = 0; p2 < 3; ++p2) {
      float v0 = vnn[q][p2 * 2], v1 = vnn[q][p2 * 2 + 1];
      unsigned short h0 = f32_to_bf16_rne(v0);
      unsigned short h1 = f32_to_bf16_rne(v1);
      float hv0 = __uint_as_float(((unsigned)h0) << 16);
      float hv1 = __uint_as_float(((unsigned)h1) << 16);
      unsigned short l0 = f32_to_bf16_rne(v0 - hv0);
      unsigned short l1 = f32_to_bf16_rne(v1 - hv1);
      *(unsigned*)&hr[p2 * 2] = (unsigned)h0 | ((unsigned)h1 << 16);
      *(unsigned*)&lr[p2 * 2] = (unsigned)l0 | ((unsigned)l1 << 16);
    }
  }
}

// ---------------- K3: KNN candidate gen via compensated bf16 MFMA ----------------------
__global__ __launch_bounds__(256, 4) void k_knn(const unsigned short* __restrict__ hiT,
                                                const unsigned short* __restrict__ loT,
                                                unsigned* __restrict__ pk) {
  int bid = blockIdx.x;
  int b = bid & 7;            // XCD affinity
  int r2 = bid >> 3;          // 0..391
  int iblk = r2 % 98;
  int jp = r2 / 98;           // 0..3
  int wq = threadIdx.x >> 6;
  int jsplit = jp * 4 + wq;   // 0..15
  int lane = threadIdx.x & 63;
  int col = lane & 31;
  int half = lane >> 5;
  int i = iblk * 32 + col;

  const unsigned short* hb = hiT + (size_t)b * NPT * NC;
  const unsigned short* lb = loT + (size_t)b * NPT * NC;

  short8 Bh[6], Bl[6];
  {
    const unsigned short* ih = hb + (size_t)i * NC + half * 8;
    const unsigned short* il = lb + (size_t)i * NC + half * 8;
#pragma unroll
    for (int ch = 0; ch < 6; ++ch) {
      Bh[ch] = *(const short8*)(ih + ch * 16);
      Bl[ch] = *(const short8*)(il + ch * 16);
    }
  }

  float kk[NDEP];
#pragma unroll
  for (int k = 0; k < NDEP; ++k) kk[k] = 0.0f;   // 0.0 < any real key (+1..3)

  int t0 = (98 * jsplit) >> 4, t1 = (98 * (jsplit + 1)) >> 4;
  int jbase = t0 * 32;
  for (int t = t0; t < t1; ++t) {
    int j0 = t * 32;
    const unsigned short* ah = hb + (size_t)(j0 + col) * NC + half * 8;
    f32x16 acc0, acc1;
#pragma unroll
    for (int r = 0; r < 16; ++r) { acc0[r] = 2.0f; acc1[r] = 0.f; }
    {
      short8 A[6];
#pragma unroll
      for (int ch = 0; ch < 6; ++ch) A[ch] = *(const short8*)(ah + ch * 16);
#pragma unroll
      for (int ch = 0; ch < 6; ++ch)
        acc0 = __builtin_amdgcn_mfma_f32_32x32x16_bf16(A[ch], Bh[ch], acc0, 0, 0, 0);
#pragma unroll
      for (int ch = 0; ch < 6; ++ch)
        acc1 = __builtin_amdgcn_mfma_f32_32x32x16_bf16(A[ch], Bl[ch], acc1, 0, 0, 0);
    }
    unsigned relbase = (unsigned)(j0 - jbase + 4 * half);
#pragma unroll
    for (int r = 0; r < 16; ++r) {
      float s = acc0[r] + acc1[r];            // = score + 2.0 (positive, in [1,3])
      unsigned kb = __float_as_uint(s);
      unsigned keyu = (kb & 0xFFFFFE00u) | (relbase + (unsigned)((r & 3) + 8 * (r >> 2)));
      float e = __uint_as_float(keyu);
#pragma unroll
      for (int s8 = NDEP - 1; s8 > 0; --s8)
        kk[s8] = __builtin_amdgcn_fmed3f(kk[s8 - 1], kk[s8], e);
      kk[0] = fmaxf(kk[0], e);
    }
  }

  // in-wave half-merge: top-9 of the two disjoint half-lists (merge-path identity)
  float c[NDEP];
#pragma unroll
  for (int k = 0; k < NDEP; ++k) {
    float pv = __shfl_xor(kk[NDEP - 1 - k], 32);
    c[k] = fmaxf(kk[k], pv);
  }
  if (half == 0) {
    unsigned* op = pk + (size_t)((size_t)b * NPT + i) * (NLIST * NDEP) + jsplit * NDEP;
#pragma unroll
    for (int k = 0; k < NDEP; ++k) op[k] = __float_as_uint(c[k]);
  }
}

// ------- K3b: fused select: tournament top-16 -> f32 rescore -> exact top-9 ------------
// Wave per row. Phase A: 16 rounds of butterfly-max over 144 decoded keys; round-r
// winner retained by lane group r. Phase B: 4 lanes/cand f32 dot + shfl reduce.
// Phase C: 9 rounds of butterfly-min on exact (score,j) u64 keys (keys unique by j).
__global__ __launch_bounds__(256) void k_select(const unsigned* __restrict__ pk,
                                                const float* __restrict__ fnT,
                                                int* __restrict__ nn_idx) {
  int wid = threadIdx.x >> 6, lane = threadIdx.x & 63;
  int row = blockIdx.x * 4 + wid;          // grid exact: NROWS/4
  int b = row / NPT;
  const unsigned* p = pk + (size_t)row * (NLIST * NDEP);
  u64 e0 = 0, e1 = 0, e2 = 0, e3 = 0;
  if (lane < 36) {
    uint4 v = *(const uint4*)&p[lane * 4];
    int g0 = lane * 4;
    int s0 = g0 / 9, s1 = (g0 + 1) / 9, s2 = (g0 + 2) / 9, s3 = (g0 + 3) / 9;
    int jb0 = ((98 * s0) >> 4) << 5, jb1 = ((98 * s1) >> 4) << 5;
    int jb2 = ((98 * s2) >> 4) << 5, jb3 = ((98 * s3) >> 4) << 5;
    e0 = ((u64)v.x << 16) | (unsigned)(jb0 + (int)(v.x & 0x1FFu));
    e1 = ((u64)v.y << 16) | (unsigned)(jb1 + (int)(v.y & 0x1FFu));
    e2 = ((u64)v.z << 16) | (unsigned)(jb2 + (int)(v.z & 0x1FFu));
    e3 = ((u64)v.w << 16) | (unsigned)(jb3 + (int)(v.w & 0x1FFu));
  }
  int myj = 0;
  for (int r = 0; r < NCAND; ++r) {
    u64 a = e0 > e1 ? e0 : e1;
    u64 bmx = e2 > e3 ? e2 : e3;
    u64 loc = a > bmx ? a : bmx;
#pragma unroll
    for (int m = 1; m < 64; m <<= 1) {
      u64 o = shfl_xor64(loc, m);
      loc = o > loc ? o : loc;
    }
    e0 = (e0 == loc) ? 0 : e0;
    e1 = (e1 == loc) ? 0 : e1;
    e2 = (e2 == loc) ? 0 : e2;
    e3 = (e3 == loc) ? 0 : e3;
    if ((lane >> 2) == r) myj = (int)(loc & 0xFFFFu);
  }
  // Phase B: rescore candidate myj (4 lanes per candidate group)
  int sub = lane & 3;
  const float* fi = fnT + (size_t)row * RST + sub * 24;
  const float* fj = fnT + (size_t)((size_t)b * NPT + myj) * RST + sub * 24;
  float pd = 0.f;
#pragma unroll
  for (int c4 = 0; c4 < 6; ++c4) {
    float4 a4 = *(const float4*)&fi[c4 * 4];
    float4 v4 = *(const float4*)&fj[c4 * 4];
    pd = fmaf(a4.x, v4.x, pd); pd = fmaf(a4.y, v4.y, pd);
    pd = fmaf(a4.z, v4.z, pd); pd = fmaf(a4.w, v4.w, pd);
  }
  pd += __shfl_xor(pd, 1);
  pd += __shfl_xor(pd, 2);
  u64 mykey = ~0ull;
  if (sub == 0) {
    float sqj = fnT[(size_t)((size_t)b * NPT + myj) * RST + 96];
    float score = fmaf(-0.5f, sqj, pd);
    mykey = ((u64)score_to_key_exact(score) << 32) | (unsigned)myj;
  }
  // Phase C: extract 9 smallest keys in order
  int* op = nn_idx + (size_t)row * NK;
  for (int k = 0; k < NK; ++k) {
    u64 loc = mykey;
#pragma unroll
    for (int m = 1; m < 64; m <<= 1) {
      u64 o = shfl_xor64(loc, m);
      loc = o < loc ? o : loc;
    }
    if (mykey == loc) mykey = ~0ull;
    if (lane == 0) op[k] = (int)(unsigned)(loc & 0xFFFFFFFFu);
  }
}

// ---------------- K4: u (f32, +bg) and v (bf16) halves via compensated bf16 MFMA -------
__global__ __launch_bounds__(256, 4) void k_uv(const unsigned short* __restrict__ fth,
                                               const unsigned short* __restrict__ ftl,
                                               const unsigned short* __restrict__ Wuvh,
                                               const unsigned short* __restrict__ Wuvl,
                                               const float* __restrict__ bg,
                                               float* __restrict__ uvu,
                                               unsigned short* __restrict__ uvv) {
  int bid = blockIdx.x;        // 2352 = 8b * 98nt * 3og
  int b = bid & 7;
  int t = bid >> 3;            // 0..293
  int nt = t % 98;
  int og = t / 98;             // 0..2
  int w = threadIdx.x >> 6;
  int ot = og * 4 + w;         // 0..11
  int lane = threadIdx.x & 63;
  int col = lane & 31, half = lane >> 5;
  int n0 = nt * 32, o0 = ot * 32;

  const unsigned short* fhp = fth + ((size_t)b * NPT + n0 + col) * NC + half * 8;
  const unsigned short* flp = ftl + ((size_t)b * NPT + n0 + col) * NC + half * 8;
  const unsigned short* whp = Wuvh + (size_t)(o0 + col) * NC + half * 8;
  const unsigned short* wlp = Wuvl + (size_t)(o0 + col) * NC + half * 8;

  f32x16 acc0, acc1;
#pragma unroll
  for (int r = 0; r < 16; ++r) { acc0[r] = 0.f; acc1[r] = 0.f; }
#pragma unroll
  for (int ch = 0; ch < 6; ++ch) {
    short8 ahv = *(const short8*)(fhp + ch * 16);
    short8 alv = *(const short8*)(flp + ch * 16);
    short8 bhv = *(const short8*)(whp + ch * 16);
    short8 blv = *(const short8*)(wlp + ch * 16);
    acc0 = __builtin_amdgcn_mfma_f32_32x32x16_bf16(ahv, bhv, acc0, 0, 0, 0);
    acc1 = __builtin_amdgcn_mfma_f32_32x32x16_bf16(ahv, blv, acc1, 0, 0, 0);
    acc0 = __builtin_amdgcn_mfma_f32_32x32x16_bf16(alv, bhv, acc0, 0, 0, 0);
  }

  int o = o0 + col;
  if (o0 < NC2) {  // u half: f32 + bias
    float bias = bg[o];
    float* up = uvu + ((size_t)b * NPT + n0) * NC2 + o;
#pragma unroll
    for (int r = 0; r < 16; ++r) {
      int nrow = (r & 3) + 8 * (r >> 2) + 4 * half;
      up[(size_t)nrow * NC2] = acc0[r] + acc1[r] + bias;
    }
  } else {         // v half: bf16
    unsigned short* vp = uvv + ((size_t)b * NPT + n0) * NC2 + (o - NC2);
#pragma unroll
    for (int r = 0; r < 16; ++r) {
      int nrow = (r & 3) + 8 * (r >> 2) + 4 * half;
      vp[(size_t)nrow * NC2] = f32_to_bf16_rne(acc0[r] + acc1[r]);
    }
  }
}

// ---------------- K5: agg = relu(max_k (u + v[idx])) -> bf16 hi/lo rows [n][192] -------
__global__ __launch_bounds__(192) void k_gather(const float* __restrict__ uvu,
                                                const unsigned short* __restrict__ uvv,
                                                const int* __restrict__ nn_idx,
                                                unsigned short* __restrict__ aggh,
                                                unsigned short* __restrict__ aggl) {
  int bid = blockIdx.x;
  int b = bid & 7;      // XCD affinity: per-batch v table (1.2 MB bf16) is L2-resident
  int ng = bid >> 3;    // 0..783
  int tid = threadIdx.x;
  int nq = tid / 48, c4 = tid % 48;
  int n = ng * 4 + nq;
  const float* ub = uvu + (size_t)b * NPT * NC2;
  const unsigned short* vb = uvv + (size_t)b * NPT * NC2;
  const int* ip = nn_idx + ((size_t)b * NPT + n) * NK;
  float4 u = *(const float4*)&ub[(size_t)n * NC2 + c4 * 4];
  float4 acc = make_float4(-1e30f, -1e30f, -1e30f, -1e30f);
#pragma unroll
  for (int k = 0; k < NK; ++k) {
    int j = ip[k];
    ushort4 vv = *(const ushort4*)&vb[(size_t)j * NC2 + c4 * 4];
    float vx = __uint_as_float(((unsigned)vv.x) << 16);
    float vy = __uint_as_float(((unsigned)vv.y) << 16);
    float vz = __uint_as_float(((unsigned)vv.z) << 16);
    float vw = __uint_as_float(((unsigned)vv.w) << 16);
    acc.x = fmaxf(acc.x, u.x + vx);
    acc.y = fmaxf(acc.y, u.y + vy);
    acc.z = fmaxf(acc.z, u.z + vz);
    acc.w = fmaxf(acc.w, u.w + vw);
  }
  float o4[4];
  o4[0] = fmaxf(acc.x, 0.f); o4[1] = fmaxf(acc.y, 0.f);
  o4[2] = fmaxf(acc.z, 0.f); o4[3] = fmaxf(acc.w, 0.f);
  u64 hp = 0, lp = 0;
#pragma unroll
  for (int e = 0; e < 4; ++e) {
    unsigned short h = f32_to_bf16_rne(o4[e]);
    float hv = __uint_as_float(((unsigned)h) << 16);
    unsigned short l = f32_to_bf16_rne(o4[e] - hv);
    hp |= ((u64)h) << (16 * e);
    lp |= ((u64)l) << (16 * e);
  }
  size_t off = ((size_t)b * NPT + n) * NC2 + c4 * 4;
  *(u64*)&aggh[off] = hp;
  *(u64*)&aggl[off] = lp;
}

// ---------------- K6: out = W2 @ agg + b2f + residual, via compensated bf16 MFMA -------
__global__ __launch_bounds__(64, 4) void k_out(const unsigned short* __restrict__ W2h,
                                               const unsigned short* __restrict__ W2l,
                                               const unsigned short* __restrict__ aggh,
                                               const unsigned short* __restrict__ aggl,
                                               const float* __restrict__ b2f,
                                               const float* __restrict__ x,
                                               float* __restrict__ out) {
  int bid = blockIdx.x;        // 2352 = 8b * 98nt * 3ot
  int b = bid & 7;
  int t = bid >> 3;            // 0..293
  int nt = t % 98;
  int ot = t / 98;             // 0..2
  int lane = threadIdx.x;
  int col = lane & 31, half = lane >> 5;
  int n0 = nt * 32, o0 = ot * 32;

  const unsigned short* whp = W2h + (size_t)(o0 + col) * NC2 + half * 8;
  const unsigned short* wlp = W2l + (size_t)(o0 + col) * NC2 + half * 8;
  const unsigned short* ahp = aggh + ((size_t)b * NPT + n0 + col) * NC2 + half * 8;
  const unsigned short* alp = aggl + ((size_t)b * NPT + n0 + col) * NC2 + half * 8;

  f32x16 acc0, acc1;
#pragma unroll
  for (int r = 0; r < 16; ++r) { acc0[r] = 0.f; acc1[r] = 0.f; }
#pragma unroll
  for (int ch = 0; ch < 12; ++ch) {
    short8 whv = *(const short8*)(whp + ch * 16);
    short8 wlv = *(const short8*)(wlp + ch * 16);
    short8 ahv = *(const short8*)(ahp + ch * 16);
    short8 alv = *(const short8*)(alp + ch * 16);
    acc0 = __builtin_amdgcn_mfma_f32_32x32x16_bf16(whv, ahv, acc0, 0, 0, 0);
    acc1 = __builtin_amdgcn_mfma_f32_32x32x16_bf16(whv, alv, acc1, 0, 0, 0);
    acc0 = __builtin_amdgcn_mfma_f32_32x32x16_bf16(wlv, ahv, acc0, 0, 0, 0);
  }

  int n = n0 + col;
  const float* xb = x + (size_t)b * NC * NPT;
  float* ob = out + (size_t)b * NC * NPT;
#pragma unroll
  for (int r = 0; r < 16; ++r) {
    int orow = o0 + (r & 3) + 8 * (r >> 2) + 4 * half;
    float v = acc0[r] + acc1[r] + b2f[orow] + xb[(size_t)orow * NPT + n];
    ob[(size_t)orow * NPT + n] = v;
  }
}

extern "C" void kernel_launch(void* const* d_in, const int* in_sizes, int n_in,
                              void* d_out, int out_size, void* d_ws, size_t ws_size,
                              hipStream_t stream) {
  const float* x  = (const float*)d_in[0];
  const float* W1 = (const float*)d_in[1];
  const float* b1 = (const float*)d_in[2];
  const float* g1 = (const float*)d_in[3];
  const float* be1= (const float*)d_in[4];
  const float* m1 = (const float*)d_in[5];
  const float* v1 = (const float*)d_in[6];
  const float* Wg = (const float*)d_in[7];
  const float* bg = (const float*)d_in[8];
  const float* W2 = (const float*)d_in[9];
  const float* b2 = (const float*)d_in[10];
  const float* g2 = (const float*)d_in[11];
  const float* be2= (const float*)d_in[12];
  const float* m2 = (const float*)d_in[13];
  const float* v2 = (const float*)d_in[14];
  float* out = (float*)d_out;

  float* ws = (float*)d_ws;
  size_t off = 0;
  unsigned short* fth = (unsigned short*)(ws + off); off += (size_t)NB * NPT * NC / 2;  // 4.8 MB
  unsigned short* ftl = (unsigned short*)(ws + off); off += (size_t)NB * NPT * NC / 2;  // 4.8 MB
  unsigned short* hiT = (unsigned short*)(ws + off); off += (size_t)NB * NPT * NC / 2;  // 4.8 MB
  unsigned short* loT = (unsigned short*)(ws + off); off += (size_t)NB * NPT * NC / 2;  // 4.8 MB
  float* uvu  = ws + off; off += (size_t)NB * NPT * NC2;            // 19.3 MB (u half, f32)
  unsigned short* uvv = (unsigned short*)(ws + off); off += (size_t)NB * NPT * NC2 / 2; // 9.6 MB
  float* aggr = ws + off; off += (size_t)NB * NPT * NC2;            // 19.3 MB (fnT / aggh+aggl)
  float* W1s  = ws + off; off += NC * NC;
  unsigned short* Wuvh = (unsigned short*)(ws + off); off += NC * NC2;      // 36864 u16
  unsigned short* Wuvl = (unsigned short*)(ws + off); off += NC * NC2;
  unsigned short* W2h  = (unsigned short*)(ws + off); off += NC * NC2 / 2;  // 18432 u16
  unsigned short* W2l  = (unsigned short*)(ws + off); off += NC * NC2 / 2;
  float* b1f  = ws + off; off += 128;
  float* b2f  = ws + off; off += 128;

  // Phase-disjoint overlays:
  //   fnT (10.4 MB) in aggr region; dead after k_select.
  //   aggh/aggl (9.6+9.6 MB) in aggr region; written by k_gather (after select).
  //   pk (14.5 MB) overlays uvu (19.3 MB); consumed by k_select before k_uv writes.
  //   nn_idx -> loT region (dead after k_knn).
  float* fnT    = aggr;
  unsigned short* aggh = (unsigned short*)aggr;
  unsigned short* aggl = aggh + (size_t)NB * NPT * NC2;
  unsigned* pk  = (unsigned*)uvu;
  int* nn_idx   = (int*)loT;

  k_fuse<<<dim3(64), 256, 0, stream>>>(W1, b1, g1, be1, m1, v1, Wg, W2, b2, g2, be2, m2, v2,
                                       W1s, b1f, Wuvh, Wuvl, W2h, W2l, b2f);
  k_feat<<<dim3(NB * 196), 64, 0, stream>>>(x, W1s, b1f, fth, ftl, fnT, hiT, loT);
  k_knn<<<dim3(NB * 98 * 4), 256, 0, stream>>>(hiT, loT, pk);
  k_select<<<dim3(NROWS / 4), 256, 0, stream>>>(pk, fnT, nn_idx);
  k_uv<<<dim3(NB * 98 * 3), 256, 0, stream>>>(fth, ftl, Wuvh, Wuvl, bg, uvu, uvv);
  k_gather<<<dim3(NB * NPT / 4), 192, 0, stream>>>(uvu, uvv, nn_idx, aggh, aggl);
  k_out<<<dim3(NB * 98 * 3), 64, 0, stream>>>(W2h, W2l, aggh, aggl, b2f, x, out);
}

// Round 16
// 211.921 us; speedup vs baseline: 1.6578x; 1.0407x over previous
//
#include <hip/hip_runtime.h>
#include <cstdint>

#define NB 8
#define NC 96
#define NC2 192
#define NPT 3136    // 56*56
#define NK 9
#define NSPL 16     // j-splits
#define NLIST 16    // lists per row after in-wave half-merge
#define NDEP 9      // per-list depth (>= NK for superset guarantee)
#define NCAND 16    // pooled candidate count per row
#define NROWS (NB * NPT)
#define RST 104     // fnT row stride (96 fn + sq at [96] + pad)
#define FT_WSTR 76  // k_feat LDS per-ob stride
static constexpr float BN_EPS = 1e-5f;
typedef unsigned long long u64;
typedef float f32x16 __attribute__((ext_vector_type(16)));
typedef short short8 __attribute__((ext_vector_type(8)));

__device__ inline unsigned short f32_to_bf16_rne(float x) {
  unsigned u = __float_as_uint(x);
  unsigned r = (u + 0x7FFFu + ((u >> 16) & 1u)) >> 16;
  return (unsigned short)r;
}

__device__ inline unsigned score_to_key_exact(float s) {
  unsigned u = __float_as_uint(s);
  u ^= 0x80000000u | (unsigned)((int)u >> 31);  // monotone increasing map
  return ~u;                                    // descending score = ascending dist
}

__device__ inline u64 shfl_xor64(u64 x, int m) {
  unsigned lo = __shfl_xor((unsigned)x, m);
  unsigned hi = __shfl_xor((unsigned)(x >> 32), m);
  return ((u64)hi << 32) | lo;
}

__device__ inline u64 shfl64(u64 x, int src) {
  unsigned lo = __shfl((unsigned)x, src);
  unsigned hi = __shfl((unsigned)(x >> 32), src);
  return ((u64)hi << 32) | lo;
}

// ---------------- K1: fold BN into weights; bf16 hi/lo weight layouts ------------------
__global__ void k_fuse(const float* __restrict__ W1, const float* __restrict__ b1,
                       const float* __restrict__ g1, const float* __restrict__ be1,
                       const float* __restrict__ m1, const float* __restrict__ v1,
                       const float* __restrict__ Wg,
                       const float* __restrict__ W2, const float* __restrict__ b2,
                       const float* __restrict__ g2, const float* __restrict__ be2,
                       const float* __restrict__ m2, const float* __restrict__ v2,
                       float* __restrict__ W1s, float* __restrict__ b1f,
                       unsigned short* __restrict__ Wuvh, unsigned short* __restrict__ Wuvl,
                       unsigned short* __restrict__ W2h, unsigned short* __restrict__ W2l,
                       float* __restrict__ b2f) {
  int t = blockIdx.x * blockDim.x + threadIdx.x;
  int nth = gridDim.x * blockDim.x;
  for (int i = t; i < NC * NC; i += nth) {
    int ch = i / 1152, r = i % 1152;
    int ob = r / 72, r2 = r % 72;
    int cc = r2 / 6, oo = r2 % 6;
    int c = ch * 12 + cc, o = ob * 6 + oo;
    float inv = g1[o] / sqrtf(v1[o] + BN_EPS);
    W1s[i] = W1[o * NC + c] * inv;
  }
  for (int o = t; o < NC; o += nth) {
    float inv = g1[o] / sqrtf(v1[o] + BN_EPS);
    b1f[o] = b1[o] * inv + be1[o] - m1[o] * inv;
    float inv2v = g2[o] / sqrtf(v2[o] + BN_EPS);
    b2f[o] = b2[o] * inv2v + be2[o] - m2[o] * inv2v;
  }
  for (int i = t; i < 2 * NC2 * NC; i += nth) {
    int o4 = i / NC, c = i % NC;
    float val;
    if (o4 < NC2) val = Wg[o4 * NC2 + c] - Wg[o4 * NC2 + NC + c];
    else          val = Wg[(o4 - NC2) * NC2 + NC + c];
    unsigned short h = f32_to_bf16_rne(val);
    float hv = __uint_as_float(((unsigned)h) << 16);
    Wuvh[i] = h;
    Wuvl[i] = f32_to_bf16_rne(val - hv);
  }
  for (int i = t; i < NC * NC2; i += nth) {
    int o = i / NC2, c = i % NC2;
    float inv = g2[o] / sqrtf(v2[o] + BN_EPS);
    float val = W2[o * NC2 + c] * inv;
    unsigned short h = f32_to_bf16_rne(val);
    float hv = __uint_as_float(((unsigned)h) << 16);
    W2h[i] = h;
    W2l[i] = f32_to_bf16_rne(val - hv);
  }
}

// ------- K2: feat = BN(W1 x + b1) -> bf16 hi/lo rows; fnT f32 norm rows; hiT/loT -------
__global__ __launch_bounds__(64, 4) void k_feat(const float* __restrict__ x,
                                                const float* __restrict__ W1s,
                                                const float* __restrict__ b1f,
                                                unsigned short* __restrict__ fth,
                                                unsigned short* __restrict__ ftl,
                                                float* __restrict__ fnT,
                                                unsigned short* __restrict__ hiT,
                                                unsigned short* __restrict__ loT) {
  int bid = blockIdx.x;      // 1568
  int b = bid & 7;
  int ng = bid >> 3;         // 0..195
  int n0 = ng * 16;
  int lane = threadIdx.x;
  int ob = lane & 15, nq = lane >> 4;

  __shared__ float w_lds[16 * FT_WSTR];  // 4864 B
  __shared__ float f_lds[12 * 16];       // 768 B

  const float* xb = x + (size_t)b * NC * NPT;
  float acc[4][6];
#pragma unroll
  for (int oo = 0; oo < 6; ++oo) {
    float bv = b1f[ob * 6 + oo];
#pragma unroll
    for (int q = 0; q < 4; ++q) acc[q][oo] = bv;
  }

  for (int ch = 0; ch < 8; ++ch) {
    __syncthreads();
    {
      const float* wsrc = W1s + ch * 1152;
#pragma unroll
      for (int it = 0; it < 5; ++it) {
        int i = it * 256 + lane * 4;
        if (it < 4 || lane < 32) {
          float4 v = *(const float4*)&wsrc[i];
          *(float4*)&w_lds[(i / 72) * FT_WSTR + (i % 72)] = v;
        }
      }
#pragma unroll
      for (int it = 0; it < 3; ++it) {
        int i = it * 64 + lane;
        f_lds[i] = xb[(size_t)(ch * 12 + (i >> 4)) * NPT + n0 + (i & 15)];
      }
    }
    __syncthreads();
#pragma unroll
    for (int cc = 0; cc < 12; ++cc) {
      float4 a = *(const float4*)&f_lds[cc * 16 + nq * 4];
      const float* wp = &w_lds[ob * FT_WSTR + cc * 6];
      float2 w01 = *(const float2*)&wp[0];
      float2 w23 = *(const float2*)&wp[2];
      float2 w45 = *(const float2*)&wp[4];
      float w[6] = {w01.x, w01.y, w23.x, w23.y, w45.x, w45.y};
#pragma unroll
      for (int oo = 0; oo < 6; ++oo) {
        acc[0][oo] = fmaf(w[oo], a.x, acc[0][oo]);
        acc[1][oo] = fmaf(w[oo], a.y, acc[1][oo]);
        acc[2][oo] = fmaf(w[oo], a.z, acc[2][oo]);
        acc[3][oo] = fmaf(w[oo], a.w, acc[3][oo]);
      }
    }
  }

  float sq[4];
#pragma unroll
  for (int q = 0; q < 4; ++q) {
    float s = 0.f;
#pragma unroll
    for (int oo = 0; oo < 6; ++oo) s += acc[q][oo] * acc[q][oo];
    sq[q] = s;
  }
#pragma unroll
  for (int m = 1; m < 16; m <<= 1) {
#pragma unroll
    for (int q = 0; q < 4; ++q) sq[q] += __shfl_xor(sq[q], m);
  }

  float vnn[4][6];
  float sqn[4];
#pragma unroll
  for (int q = 0; q < 4; ++q) {
    float den = fmaxf(sqrtf(sq[q]), 1e-12f);
    float s = 0.f;
#pragma unroll
    for (int oo = 0; oo < 6; ++oo) {
      float v = acc[q][oo] / den;
      vnn[q][oo] = v;
      s += v * v;
    }
    sqn[q] = s;
  }
#pragma unroll
  for (int m = 1; m < 16; m <<= 1) {
#pragma unroll
    for (int q = 0; q < 4; ++q) sqn[q] += __shfl_xor(sqn[q], m);
  }

#pragma unroll
  for (int q = 0; q < 4; ++q) {
    int n = n0 + nq * 4 + q;
    unsigned short* fhr = fth + ((size_t)b * NPT + n) * NC + ob * 6;
    unsigned short* flr = ftl + ((size_t)b * NPT + n) * NC + ob * 6;
#pragma unroll
    for (int p2 = 0; p2 < 3; ++p2) {
      float v0 = acc[q][p2 * 2], v1 = acc[q][p2 * 2 + 1];
      unsigned short h0 = f32_to_bf16_rne(v0);
      unsigned short h1 = f32_to_bf16_rne(v1);
      float hv0 = __uint_as_float(((unsigned)h0) << 16);
      float hv1 = __uint_as_float(((unsigned)h1) << 16);
      unsigned short l0 = f32_to_bf16_rne(v0 - hv0);
      unsigned short l1 = f32_to_bf16_rne(v1 - hv1);
      *(unsigned*)&fhr[p2 * 2] = (unsigned)h0 | ((unsigned)h1 << 16);
      *(unsigned*)&flr[p2 * 2] = (unsigned)l0 | ((unsigned)l1 << 16);
    }
    float* fr = fnT + ((size_t)b * NPT + n) * RST;
#pragma unroll
    for (int oo = 0; oo < 6; ++oo) fr[ob * 6 + oo] = vnn[q][oo];
    if (ob == 0) fr[96] = sqn[q];
    unsigned short* hr = hiT + ((size_t)b * NPT + n) * NC + ob * 6;
    unsigned short* lr = loT + ((size_t)b * NPT + n) * NC + ob * 6;
#pragma unroll
    for (int p2 = 0; p2 < 3; ++p2) {
      float v0 = vnn[q][p2 * 2], v1 = vnn[q][p2 * 2 + 1];
      unsigned short h0 = f32_to_bf16_rne(v0);
      unsigned short h1 = f32_to_bf16_rne(v1);
      float hv0 = __uint_as_float(((unsigned)h0) << 16);
      float hv1 = __uint_as_float(((unsigned)h1) << 16);
      unsigned short l0 = f32_to_bf16_rne(v0 - hv0);
      unsigned short l1 = f32_to_bf16_rne(v1 - hv1);
      *(unsigned*)&hr[p2 * 2] = (unsigned)h0 | ((unsigned)h1 << 16);
      *(unsigned*)&lr[p2 * 2] = (unsigned)l0 | ((unsigned)l1 << 16);
    }
  }
}

// ---------------- K3: KNN candidate gen via compensated bf16 MFMA ----------------------
__global__ __launch_bounds__(256, 4) void k_knn(const unsigned short* __restrict__ hiT,
                                                const unsigned short* __restrict__ loT,
                                                unsigned* __restrict__ pk) {
  int bid = blockIdx.x;
  int b = bid & 7;            // XCD affinity
  int r2 = bid >> 3;          // 0..391
  int iblk = r2 % 98;
  int jp = r2 / 98;           // 0..3
  int wq = threadIdx.x >> 6;
  int jsplit = jp * 4 + wq;   // 0..15
  int lane = threadIdx.x & 63;
  int col = lane & 31;
  int half = lane >> 5;
  int i = iblk * 32 + col;

  const unsigned short* hb = hiT + (size_t)b * NPT * NC;
  const unsigned short* lb = loT + (size_t)b * NPT * NC;

  short8 Bh[6], Bl[6];
  {
    const unsigned short* ih = hb + (size_t)i * NC + half * 8;
    const unsigned short* il = lb + (size_t)i * NC + half * 8;
#pragma unroll
    for (int ch = 0; ch < 6; ++ch) {
      Bh[ch] = *(const short8*)(ih + ch * 16);
      Bl[ch] = *(const short8*)(il + ch * 16);
    }
  }

  float kk[NDEP];
#pragma unroll
  for (int k = 0; k < NDEP; ++k) kk[k] = 0.0f;   // 0.0 < any real key (+1..3)

  int t0 = (98 * jsplit) >> 4, t1 = (98 * (jsplit + 1)) >> 4;
  int jbase = t0 * 32;
  for (int t = t0; t < t1; ++t) {
    int j0 = t * 32;
    const unsigned short* ah = hb + (size_t)(j0 + col) * NC + half * 8;
    f32x16 acc0, acc1;
#pragma unroll
    for (int r = 0; r < 16; ++r) { acc0[r] = 2.0f; acc1[r] = 0.f; }
    {
      short8 A[6];
#pragma unroll
      for (int ch = 0; ch < 6; ++ch) A[ch] = *(const short8*)(ah + ch * 16);
#pragma unroll
      for (int ch = 0; ch < 6; ++ch)
        acc0 = __builtin_amdgcn_mfma_f32_32x32x16_bf16(A[ch], Bh[ch], acc0, 0, 0, 0);
#pragma unroll
      for (int ch = 0; ch < 6; ++ch)
        acc1 = __builtin_amdgcn_mfma_f32_32x32x16_bf16(A[ch], Bl[ch], acc1, 0, 0, 0);
    }
    unsigned relbase = (unsigned)(j0 - jbase + 4 * half);
#pragma unroll
    for (int r = 0; r < 16; ++r) {
      float s = acc0[r] + acc1[r];            // = score + 2.0 (positive, in [1,3])
      unsigned kb = __float_as_uint(s);
      unsigned keyu = (kb & 0xFFFFFE00u) | (relbase + (unsigned)((r & 3) + 8 * (r >> 2)));
      float e = __uint_as_float(keyu);
#pragma unroll
      for (int s8 = NDEP - 1; s8 > 0; --s8)
        kk[s8] = __builtin_amdgcn_fmed3f(kk[s8 - 1], kk[s8], e);
      kk[0] = fmaxf(kk[0], e);
    }
  }

  // in-wave half-merge: top-9 of the two disjoint half-lists (bitonic split)
  float c[NDEP];
#pragma unroll
  for (int k = 0; k < NDEP; ++k) {
    float pv = __shfl_xor(kk[NDEP - 1 - k], 32);
    c[k] = fmaxf(kk[k], pv);
  }
  if (half == 0) {
    unsigned* op = pk + (size_t)((size_t)b * NPT + i) * (NLIST * NDEP) + jsplit * NDEP;
#pragma unroll
    for (int k = 0; k < NDEP; ++k) op[k] = __float_as_uint(c[k]);
  }
}

// ------- K3b: fused select: tournament top-16 -> f32 rescore -> exact top-9 ------------
// XCD-affinity: b = bid&7 so each XCD's L2 holds only its batch's fnT slice (1.3 MB).
// Phase A: 16 rounds of butterfly-max over 144 decoded keys; round-r winner kept by
// lane group r. Phase B: 4 lanes/cand f32 dot + shfl reduce. Phase C: rank-based
// ordering — 16 independent leader-key broadcasts, rank = #(smaller keys), lane with
// rank k<9 writes op[k]. Keys unique (distinct j in low bits) -> ranks unique.
__global__ __launch_bounds__(256) void k_select(const unsigned* __restrict__ pk,
                                                const float* __restrict__ fnT,
                                                int* __restrict__ nn_idx) {
  int wid = threadIdx.x >> 6, lane = threadIdx.x & 63;
  int bid = blockIdx.x;                    // grid exact: NROWS/4
  int b = bid & 7;                         // XCD affinity
  int rg = bid >> 3;                       // 0..783
  int row = b * NPT + rg * 4 + wid;
  const unsigned* p = pk + (size_t)row * (NLIST * NDEP);
  u64 e0 = 0, e1 = 0, e2 = 0, e3 = 0;
  if (lane < 36) {
    uint4 v = *(const uint4*)&p[lane * 4];
    int g0 = lane * 4;
    int s0 = g0 / 9, s1 = (g0 + 1) / 9, s2 = (g0 + 2) / 9, s3 = (g0 + 3) / 9;
    int jb0 = ((98 * s0) >> 4) << 5, jb1 = ((98 * s1) >> 4) << 5;
    int jb2 = ((98 * s2) >> 4) << 5, jb3 = ((98 * s3) >> 4) << 5;
    e0 = ((u64)v.x << 16) | (unsigned)(jb0 + (int)(v.x & 0x1FFu));
    e1 = ((u64)v.y << 16) | (unsigned)(jb1 + (int)(v.y & 0x1FFu));
    e2 = ((u64)v.z << 16) | (unsigned)(jb2 + (int)(v.z & 0x1FFu));
    e3 = ((u64)v.w << 16) | (unsigned)(jb3 + (int)(v.w & 0x1FFu));
  }
  int myj = 0;
  for (int r = 0; r < NCAND; ++r) {
    u64 a = e0 > e1 ? e0 : e1;
    u64 bmx = e2 > e3 ? e2 : e3;
    u64 loc = a > bmx ? a : bmx;
#pragma unroll
    for (int m = 1; m < 64; m <<= 1) {
      u64 o = shfl_xor64(loc, m);
      loc = o > loc ? o : loc;
    }
    e0 = (e0 == loc) ? 0 : e0;
    e1 = (e1 == loc) ? 0 : e1;
    e2 = (e2 == loc) ? 0 : e2;
    e3 = (e3 == loc) ? 0 : e3;
    if ((lane >> 2) == r) myj = (int)(loc & 0xFFFFu);
  }
  // Phase B: rescore candidate myj (4 lanes per candidate group)
  int sub = lane & 3;
  const float* fi = fnT + (size_t)row * RST + sub * 24;
  const float* fj = fnT + (size_t)((size_t)b * NPT + myj) * RST + sub * 24;
  float pd = 0.f;
#pragma unroll
  for (int c4 = 0; c4 < 6; ++c4) {
    float4 a4 = *(const float4*)&fi[c4 * 4];
    float4 v4 = *(const float4*)&fj[c4 * 4];
    pd = fmaf(a4.x, v4.x, pd); pd = fmaf(a4.y, v4.y, pd);
    pd = fmaf(a4.z, v4.z, pd); pd = fmaf(a4.w, v4.w, pd);
  }
  pd += __shfl_xor(pd, 1);
  pd += __shfl_xor(pd, 2);
  u64 mykey = ~0ull;
  if (sub == 0) {
    float sqj = fnT[(size_t)((size_t)b * NPT + myj) * RST + 96];
    float score = fmaf(-0.5f, sqj, pd);
    mykey = ((u64)score_to_key_exact(score) << 32) | (unsigned)myj;
  }
  // Phase C: rank-based top-9 ordering (independent broadcasts, no serial chain)
  u64 kt[NCAND];
#pragma unroll
  for (int t = 0; t < NCAND; ++t) kt[t] = shfl64(mykey, t * 4);
  if (sub == 0) {
    int rank = 0;
#pragma unroll
    for (int t = 0; t < NCAND; ++t) rank += (kt[t] < mykey) ? 1 : 0;
    if (rank < NK) {
      int* op = nn_idx + (size_t)row * NK;
      op[rank] = (int)(mykey & 0xFFFFu);
    }
  }
}

// ---------------- K4: u (f32, +bg) and v (bf16) halves via compensated bf16 MFMA -------
__global__ __launch_bounds__(256, 4) void k_uv(const unsigned short* __restrict__ fth,
                                               const unsigned short* __restrict__ ftl,
                                               const unsigned short* __restrict__ Wuvh,
                                               const unsigned short* __restrict__ Wuvl,
                                               const float* __restrict__ bg,
                                               float* __restrict__ uvu,
                                               unsigned short* __restrict__ uvv) {
  int bid = blockIdx.x;        // 2352 = 8b * 98nt * 3og
  int b = bid & 7;
  int t = bid >> 3;            // 0..293
  int nt = t % 98;
  int og = t / 98;             // 0..2
  int w = threadIdx.x >> 6;
  int ot = og * 4 + w;         // 0..11
  int lane = threadIdx.x & 63;
  int col = lane & 31, half = lane >> 5;
  int n0 = nt * 32, o0 = ot * 32;

  const unsigned short* fhp = fth + ((size_t)b * NPT + n0 + col) * NC + half * 8;
  const unsigned short* flp = ftl + ((size_t)b * NPT + n0 + col) * NC + half * 8;
  const unsigned short* whp = Wuvh + (size_t)(o0 + col) * NC + half * 8;
  const unsigned short* wlp = Wuvl + (size_t)(o0 + col) * NC + half * 8;

  f32x16 acc0, acc1;
#pragma unroll
  for (int r = 0; r < 16; ++r) { acc0[r] = 0.f; acc1[r] = 0.f; }
#pragma unroll
  for (int ch = 0; ch < 6; ++ch) {
    short8 ahv = *(const short8*)(fhp + ch * 16);
    short8 alv = *(const short8*)(flp + ch * 16);
    short8 bhv = *(const short8*)(whp + ch * 16);
    short8 blv = *(const short8*)(wlp + ch * 16);
    acc0 = __builtin_amdgcn_mfma_f32_32x32x16_bf16(ahv, bhv, acc0, 0, 0, 0);
    acc1 = __builtin_amdgcn_mfma_f32_32x32x16_bf16(ahv, blv, acc1, 0, 0, 0);
    acc0 = __builtin_amdgcn_mfma_f32_32x32x16_bf16(alv, bhv, acc0, 0, 0, 0);
  }

  int o = o0 + col;
  if (o0 < NC2) {  // u half: f32 + bias
    float bias = bg[o];
    float* up = uvu + ((size_t)b * NPT + n0) * NC2 + o;
#pragma unroll
    for (int r = 0; r < 16; ++r) {
      int nrow = (r & 3) + 8 * (r >> 2) + 4 * half;
      up[(size_t)nrow * NC2] = acc0[r] + acc1[r] + bias;
    }
  } else {         // v half: bf16
    unsigned short* vp = uvv + ((size_t)b * NPT + n0) * NC2 + (o - NC2);
#pragma unroll
    for (int r = 0; r < 16; ++r) {
      int nrow = (r & 3) + 8 * (r >> 2) + 4 * half;
      vp[(size_t)nrow * NC2] = f32_to_bf16_rne(acc0[r] + acc1[r]);
    }
  }
}

// ---------------- K5: agg = relu(max_k (u + v[idx])) -> bf16 hi/lo rows [n][192] -------
__global__ __launch_bounds__(192) void k_gather(const float* __restrict__ uvu,
                                                const unsigned short* __restrict__ uvv,
                                                const int* __restrict__ nn_idx,
                                                unsigned short* __restrict__ aggh,
                                                unsigned short* __restrict__ aggl) {
  int bid = blockIdx.x;
  int b = bid & 7;      // XCD affinity: per-batch v table (1.2 MB bf16) is L2-resident
  int ng = bid >> 3;    // 0..783
  int tid = threadIdx.x;
  int nq = tid / 48, c4 = tid % 48;
  int n = ng * 4 + nq;
  const float* ub = uvu + (size_t)b * NPT * NC2;
  const unsigned short* vb = uvv + (size_t)b * NPT * NC2;
  const int* ip = nn_idx + ((size_t)b * NPT + n) * NK;
  float4 u = *(const float4*)&ub[(size_t)n * NC2 + c4 * 4];
  float4 acc = make_float4(-1e30f, -1e30f, -1e30f, -1e30f);
#pragma unroll
  for (int k = 0; k < NK; ++k) {
    int j = ip[k];
    ushort4 vv = *(const ushort4*)&vb[(size_t)j * NC2 + c4 * 4];
    float vx = __uint_as_float(((unsigned)vv.x) << 16);
    float vy = __uint_as_float(((unsigned)vv.y) << 16);
    float vz = __uint_as_float(((unsigned)vv.z) << 16);
    float vw = __uint_as_float(((unsigned)vv.w) << 16);
    acc.x = fmaxf(acc.x, u.x + vx);
    acc.y = fmaxf(acc.y, u.y + vy);
    acc.z = fmaxf(acc.z, u.z + vz);
    acc.w = fmaxf(acc.w, u.w + vw);
  }
  float o4[4];
  o4[0] = fmaxf(acc.x, 0.f); o4[1] = fmaxf(acc.y, 0.f);
  o4[2] = fmaxf(acc.z, 0.f); o4[3] = fmaxf(acc.w, 0.f);
  u64 hp = 0, lp = 0;
#pragma unroll
  for (int e = 0; e < 4; ++e) {
    unsigned short h = f32_to_bf16_rne(o4[e]);
    float hv = __uint_as_float(((unsigned)h) << 16);
    unsigned short l = f32_to_bf16_rne(o4[e] - hv);
    hp |= ((u64)h) << (16 * e);
    lp |= ((u64)l) << (16 * e);
  }
  size_t off = ((size_t)b * NPT + n) * NC2 + c4 * 4;
  *(u64*)&aggh[off] = hp;
  *(u64*)&aggl[off] = lp;
}

// ---------------- K6: out = W2 @ agg + b2f + residual, via compensated bf16 MFMA -------
__global__ __launch_bounds__(64, 4) void k_out(const unsigned short* __restrict__ W2h,
                                               const unsigned short* __restrict__ W2l,
                                               const unsigned short* __restrict__ aggh,
                                               const unsigned short* __restrict__ aggl,
                                               const float* __restrict__ b2f,
                                               const float* __restrict__ x,
                                               float* __restrict__ out) {
  int bid = blockIdx.x;        // 2352 = 8b * 98nt * 3ot
  int b = bid & 7;
  int t = bid >> 3;            // 0..293
  int nt = t % 98;
  int ot = t / 98;             // 0..2
  int lane = threadIdx.x;
  int col = lane & 31, half = lane >> 5;
  int n0 = nt * 32, o0 = ot * 32;

  const unsigned short* whp = W2h + (size_t)(o0 + col) * NC2 + half * 8;
  const unsigned short* wlp = W2l + (size_t)(o0 + col) * NC2 + half * 8;
  const unsigned short* ahp = aggh + ((size_t)b * NPT + n0 + col) * NC2 + half * 8;
  const unsigned short* alp = aggl + ((size_t)b * NPT + n0 + col) * NC2 + half * 8;

  f32x16 acc0, acc1;
#pragma unroll
  for (int r = 0; r < 16; ++r) { acc0[r] = 0.f; acc1[r] = 0.f; }
#pragma unroll
  for (int ch = 0; ch < 12; ++ch) {
    short8 whv = *(const short8*)(whp + ch * 16);
    short8 wlv = *(const short8*)(wlp + ch * 16);
    short8 ahv = *(const short8*)(ahp + ch * 16);
    short8 alv = *(const short8*)(alp + ch * 16);
    acc0 = __builtin_amdgcn_mfma_f32_32x32x16_bf16(whv, ahv, acc0, 0, 0, 0);
    acc1 = __builtin_amdgcn_mfma_f32_32x32x16_bf16(whv, alv, acc1, 0, 0, 0);
    acc0 = __builtin_amdgcn_mfma_f32_32x32x16_bf16(wlv, ahv, acc0, 0, 0, 0);
  }

  int n = n0 + col;
  const float* xb = x + (size_t)b * NC * NPT;
  float* ob = out + (size_t)b * NC * NPT;
#pragma unroll
  for (int r = 0; r < 16; ++r) {
    int orow = o0 + (r & 3) + 8 * (r >> 2) + 4 * half;
    float v = acc0[r] + acc1[r] + b2f[orow] + xb[(size_t)orow * NPT + n];
    ob[(size_t)orow * NPT + n] = v;
  }
}

extern "C" void kernel_launch(void* const* d_in, const int* in_sizes, int n_in,
                              void* d_out, int out_size, void* d_ws, size_t ws_size,
                              hipStream_t stream) {
  const float* x  = (const float*)d_in[0];
  const float* W1 = (const float*)d_in[1];
  const float* b1 = (const float*)d_in[2];
  const float* g1 = (const float*)d_in[3];
  const float* be1= (const float*)d_in[4];
  const float* m1 = (const float*)d_in[5];
  const float* v1 = (const float*)d_in[6];
  const float* Wg = (const float*)d_in[7];
  const float* bg = (const float*)d_in[8];
  const float* W2 = (const float*)d_in[9];
  const float* b2 = (const float*)d_in[10];
  const float* g2 = (const float*)d_in[11];
  const float* be2= (const float*)d_in[12];
  const float* m2 = (const float*)d_in[13];
  const float* v2 = (const float*)d_in[14];
  float* out = (float*)d_out;

  float* ws = (float*)d_ws;
  size_t off = 0;
  unsigned short* fth = (unsigned short*)(ws + off); off += (size_t)NB * NPT * NC / 2;  // 4.8 MB
  unsigned short* ftl = (unsigned short*)(ws + off); off += (size_t)NB * NPT * NC / 2;  // 4.8 MB
  unsigned short* hiT = (unsigned short*)(ws + off); off += (size_t)NB * NPT * NC / 2;  // 4.8 MB
  unsigned short* loT = (unsigned short*)(ws + off); off += (size_t)NB * NPT * NC / 2;  // 4.8 MB
  float* uvu  = ws + off; off += (size_t)NB * NPT * NC2;            // 19.3 MB (u half, f32)
  unsigned short* uvv = (unsigned short*)(ws + off); off += (size_t)NB * NPT * NC2 / 2; // 9.6 MB
  float* aggr = ws + off; off += (size_t)NB * NPT * NC2;            // 19.3 MB (fnT / aggh+aggl)
  float* W1s  = ws + off; off += NC * NC;
  unsigned short* Wuvh = (unsigned short*)(ws + off); off += NC * NC2;      // 36864 u16
  unsigned short* Wuvl = (unsigned short*)(ws + off); off += NC * NC2;
  unsigned short* W2h  = (unsigned short*)(ws + off); off += NC * NC2 / 2;  // 18432 u16
  unsigned short* W2l  = (unsigned short*)(ws + off); off += NC * NC2 / 2;
  float* b1f  = ws + off; off += 128;
  float* b2f  = ws + off; off += 128;

  // Phase-disjoint overlays:
  //   fnT (10.4 MB) in aggr region; dead after k_select.
  //   aggh/aggl (9.6+9.6 MB) in aggr region; written by k_gather (after select).
  //   pk (14.5 MB) overlays uvu (19.3 MB); consumed by k_select before k_uv writes.
  //   nn_idx -> loT region (dead after k_knn).
  float* fnT    = aggr;
  unsigned short* aggh = (unsigned short*)aggr;
  unsigned short* aggl = aggh + (size_t)NB * NPT * NC2;
  unsigned* pk  = (unsigned*)uvu;
  int* nn_idx   = (int*)loT;

  k_fuse<<<dim3(64), 256, 0, stream>>>(W1, b1, g1, be1, m1, v1, Wg, W2, b2, g2, be2, m2, v2,
                                       W1s, b1f, Wuvh, Wuvl, W2h, W2l, b2f);
  k_feat<<<dim3(NB * 196), 64, 0, stream>>>(x, W1s, b1f, fth, ftl, fnT, hiT, loT);
  k_knn<<<dim3(NB * 98 * 4), 256, 0, stream>>>(hiT, loT, pk);
  k_select<<<dim3(NROWS / 4), 256, 0, stream>>>(pk, fnT, nn_idx);
  k_uv<<<dim3(NB * 98 * 3), 256, 0, stream>>>(fth, ftl, Wuvh, Wuvl, bg, uvu, uvv);
  k_gather<<<dim3(NB * NPT / 4), 192, 0, stream>>>(uvu, uvv, nn_idx, aggh, aggl);
  k_out<<<dim3(NB * 98 * 3), 64, 0, stream>>>(W2h, W2l, aggh, aggl, b2f, x, out);
}

// Round 17
// 173.397 us; speedup vs baseline: 2.0261x; 1.2222x over previous
//
#include <hip/hip_runtime.h>
#include <cstdint>

#define NB 8
#define NC 96
#define NC2 192
#define NPT 3136    // 56*56
#define NK 9
#define NSPL 16     // j-splits
#define NLIST 16    // lists per row after in-wave half-merge
#define NDEP 9      // per-list depth (>= NK for superset guarantee)
#define NCAND 16    // pooled candidate count per row
#define NROWS (NB * NPT)
#define RST 104     // fnT row stride (96 fn + sq at [96] + pad)
#define FT_WSTR 76  // k_feat LDS per-ob stride
static constexpr float BN_EPS = 1e-5f;
typedef unsigned long long u64;
typedef float f32x16 __attribute__((ext_vector_type(16)));
typedef short short8 __attribute__((ext_vector_type(8)));

__device__ inline unsigned short f32_to_bf16_rne(float x) {
  unsigned u = __float_as_uint(x);
  unsigned r = (u + 0x7FFFu + ((u >> 16) & 1u)) >> 16;
  return (unsigned short)r;
}

__device__ inline unsigned score_to_key_exact(float s) {
  unsigned u = __float_as_uint(s);
  u ^= 0x80000000u | (unsigned)((int)u >> 31);  // monotone increasing map
  return ~u;                                    // descending score = ascending dist
}

__device__ inline u64 shfl64(u64 x, int src) {
  unsigned lo = __shfl((unsigned)x, src);
  unsigned hi = __shfl((unsigned)(x >> 32), src);
  return ((u64)hi << 32) | lo;
}

// ---------------- K1: fold BN into weights; bf16 hi/lo weight layouts ------------------
__global__ void k_fuse(const float* __restrict__ W1, const float* __restrict__ b1,
                       const float* __restrict__ g1, const float* __restrict__ be1,
                       const float* __restrict__ m1, const float* __restrict__ v1,
                       const float* __restrict__ Wg,
                       const float* __restrict__ W2, const float* __restrict__ b2,
                       const float* __restrict__ g2, const float* __restrict__ be2,
                       const float* __restrict__ m2, const float* __restrict__ v2,
                       float* __restrict__ W1s, float* __restrict__ b1f,
                       unsigned short* __restrict__ Wuvh, unsigned short* __restrict__ Wuvl,
                       unsigned short* __restrict__ W2h, unsigned short* __restrict__ W2l,
                       float* __restrict__ b2f) {
  int t = blockIdx.x * blockDim.x + threadIdx.x;
  int nth = gridDim.x * blockDim.x;
  for (int i = t; i < NC * NC; i += nth) {
    int ch = i / 1152, r = i % 1152;
    int ob = r / 72, r2 = r % 72;
    int cc = r2 / 6, oo = r2 % 6;
    int c = ch * 12 + cc, o = ob * 6 + oo;
    float inv = g1[o] / sqrtf(v1[o] + BN_EPS);
    W1s[i] = W1[o * NC + c] * inv;
  }
  for (int o = t; o < NC; o += nth) {
    float inv = g1[o] / sqrtf(v1[o] + BN_EPS);
    b1f[o] = b1[o] * inv + be1[o] - m1[o] * inv;
    float inv2v = g2[o] / sqrtf(v2[o] + BN_EPS);
    b2f[o] = b2[o] * inv2v + be2[o] - m2[o] * inv2v;
  }
  for (int i = t; i < 2 * NC2 * NC; i += nth) {
    int o4 = i / NC, c = i % NC;
    float val;
    if (o4 < NC2) val = Wg[o4 * NC2 + c] - Wg[o4 * NC2 + NC + c];
    else          val = Wg[(o4 - NC2) * NC2 + NC + c];
    unsigned short h = f32_to_bf16_rne(val);
    float hv = __uint_as_float(((unsigned)h) << 16);
    Wuvh[i] = h;
    Wuvl[i] = f32_to_bf16_rne(val - hv);
  }
  for (int i = t; i < NC * NC2; i += nth) {
    int o = i / NC2, c = i % NC2;
    float inv = g2[o] / sqrtf(v2[o] + BN_EPS);
    float val = W2[o * NC2 + c] * inv;
    unsigned short h = f32_to_bf16_rne(val);
    float hv = __uint_as_float(((unsigned)h) << 16);
    W2h[i] = h;
    W2l[i] = f32_to_bf16_rne(val - hv);
  }
}

// ------- K2: feat = BN(W1 x + b1) -> bf16 hi/lo rows; fnT f32 norm rows; hiT/loT -------
__global__ __launch_bounds__(64, 4) void k_feat(const float* __restrict__ x,
                                                const float* __restrict__ W1s,
                                                const float* __restrict__ b1f,
                                                unsigned short* __restrict__ fth,
                                                unsigned short* __restrict__ ftl,
                                                float* __restrict__ fnT,
                                                unsigned short* __restrict__ hiT,
                                                unsigned short* __restrict__ loT) {
  int bid = blockIdx.x;      // 1568
  int b = bid & 7;
  int ng = bid >> 3;         // 0..195
  int n0 = ng * 16;
  int lane = threadIdx.x;
  int ob = lane & 15, nq = lane >> 4;

  __shared__ float w_lds[16 * FT_WSTR];  // 4864 B
  __shared__ float f_lds[12 * 16];       // 768 B

  const float* xb = x + (size_t)b * NC * NPT;
  float acc[4][6];
#pragma unroll
  for (int oo = 0; oo < 6; ++oo) {
    float bv = b1f[ob * 6 + oo];
#pragma unroll
    for (int q = 0; q < 4; ++q) acc[q][oo] = bv;
  }

  for (int ch = 0; ch < 8; ++ch) {
    __syncthreads();
    {
      const float* wsrc = W1s + ch * 1152;
#pragma unroll
      for (int it = 0; it < 5; ++it) {
        int i = it * 256 + lane * 4;
        if (it < 4 || lane < 32) {
          float4 v = *(const float4*)&wsrc[i];
          *(float4*)&w_lds[(i / 72) * FT_WSTR + (i % 72)] = v;
        }
      }
#pragma unroll
      for (int it = 0; it < 3; ++it) {
        int i = it * 64 + lane;
        f_lds[i] = xb[(size_t)(ch * 12 + (i >> 4)) * NPT + n0 + (i & 15)];
      }
    }
    __syncthreads();
#pragma unroll
    for (int cc = 0; cc < 12; ++cc) {
      float4 a = *(const float4*)&f_lds[cc * 16 + nq * 4];
      const float* wp = &w_lds[ob * FT_WSTR + cc * 6];
      float2 w01 = *(const float2*)&wp[0];
      float2 w23 = *(const float2*)&wp[2];
      float2 w45 = *(const float2*)&wp[4];
      float w[6] = {w01.x, w01.y, w23.x, w23.y, w45.x, w45.y};
#pragma unroll
      for (int oo = 0; oo < 6; ++oo) {
        acc[0][oo] = fmaf(w[oo], a.x, acc[0][oo]);
        acc[1][oo] = fmaf(w[oo], a.y, acc[1][oo]);
        acc[2][oo] = fmaf(w[oo], a.z, acc[2][oo]);
        acc[3][oo] = fmaf(w[oo], a.w, acc[3][oo]);
      }
    }
  }

  float sq[4];
#pragma unroll
  for (int q = 0; q < 4; ++q) {
    float s = 0.f;
#pragma unroll
    for (int oo = 0; oo < 6; ++oo) s += acc[q][oo] * acc[q][oo];
    sq[q] = s;
  }
#pragma unroll
  for (int m = 1; m < 16; m <<= 1) {
#pragma unroll
    for (int q = 0; q < 4; ++q) sq[q] += __shfl_xor(sq[q], m);
  }

  float vnn[4][6];
  float sqn[4];
#pragma unroll
  for (int q = 0; q < 4; ++q) {
    float den = fmaxf(sqrtf(sq[q]), 1e-12f);
    float s = 0.f;
#pragma unroll
    for (int oo = 0; oo < 6; ++oo) {
      float v = acc[q][oo] / den;
      vnn[q][oo] = v;
      s += v * v;
    }
    sqn[q] = s;
  }
#pragma unroll
  for (int m = 1; m < 16; m <<= 1) {
#pragma unroll
    for (int q = 0; q < 4; ++q) sqn[q] += __shfl_xor(sqn[q], m);
  }

#pragma unroll
  for (int q = 0; q < 4; ++q) {
    int n = n0 + nq * 4 + q;
    unsigned short* fhr = fth + ((size_t)b * NPT + n) * NC + ob * 6;
    unsigned short* flr = ftl + ((size_t)b * NPT + n) * NC + ob * 6;
#pragma unroll
    for (int p2 = 0; p2 < 3; ++p2) {
      float v0 = acc[q][p2 * 2], v1 = acc[q][p2 * 2 + 1];
      unsigned short h0 = f32_to_bf16_rne(v0);
      unsigned short h1 = f32_to_bf16_rne(v1);
      float hv0 = __uint_as_float(((unsigned)h0) << 16);
      float hv1 = __uint_as_float(((unsigned)h1) << 16);
      unsigned short l0 = f32_to_bf16_rne(v0 - hv0);
      unsigned short l1 = f32_to_bf16_rne(v1 - hv1);
      *(unsigned*)&fhr[p2 * 2] = (unsigned)h0 | ((unsigned)h1 << 16);
      *(unsigned*)&flr[p2 * 2] = (unsigned)l0 | ((unsigned)l1 << 16);
    }
    float* fr = fnT + ((size_t)b * NPT + n) * RST;
#pragma unroll
    for (int oo = 0; oo < 6; ++oo) fr[ob * 6 + oo] = vnn[q][oo];
    if (ob == 0) fr[96] = sqn[q];
    unsigned short* hr = hiT + ((size_t)b * NPT + n) * NC + ob * 6;
    unsigned short* lr = loT + ((size_t)b * NPT + n) * NC + ob * 6;
#pragma unroll
    for (int p2 = 0; p2 < 3; ++p2) {
      float v0 = vnn[q][p2 * 2], v1 = vnn[q][p2 * 2 + 1];
      unsigned short h0 = f32_to_bf16_rne(v0);
      unsigned short h1 = f32_to_bf16_rne(v1);
      float hv0 = __uint_as_float(((unsigned)h0) << 16);
      float hv1 = __uint_as_float(((unsigned)h1) << 16);
      unsigned short l0 = f32_to_bf16_rne(v0 - hv0);
      unsigned short l1 = f32_to_bf16_rne(v1 - hv1);
      *(unsigned*)&hr[p2 * 2] = (unsigned)h0 | ((unsigned)h1 << 16);
      *(unsigned*)&lr[p2 * 2] = (unsigned)l0 | ((unsigned)l1 << 16);
    }
  }
}

// ---------------- K3: KNN candidate gen via compensated bf16 MFMA ----------------------
__global__ __launch_bounds__(256, 4) void k_knn(const unsigned short* __restrict__ hiT,
                                                const unsigned short* __restrict__ loT,
                                                unsigned* __restrict__ pk) {
  int bid = blockIdx.x;
  int b = bid & 7;            // XCD affinity
  int r2 = bid >> 3;          // 0..391
  int iblk = r2 % 98;
  int jp = r2 / 98;           // 0..3
  int wq = threadIdx.x >> 6;
  int jsplit = jp * 4 + wq;   // 0..15
  int lane = threadIdx.x & 63;
  int col = lane & 31;
  int half = lane >> 5;
  int i = iblk * 32 + col;

  const unsigned short* hb = hiT + (size_t)b * NPT * NC;
  const unsigned short* lb = loT + (size_t)b * NPT * NC;

  short8 Bh[6], Bl[6];
  {
    const unsigned short* ih = hb + (size_t)i * NC + half * 8;
    const unsigned short* il = lb + (size_t)i * NC + half * 8;
#pragma unroll
    for (int ch = 0; ch < 6; ++ch) {
      Bh[ch] = *(const short8*)(ih + ch * 16);
      Bl[ch] = *(const short8*)(il + ch * 16);
    }
  }

  float kk[NDEP];
#pragma unroll
  for (int k = 0; k < NDEP; ++k) kk[k] = 0.0f;   // 0.0 < any real key (+1..3)

  int t0 = (98 * jsplit) >> 4, t1 = (98 * (jsplit + 1)) >> 4;
  int jbase = t0 * 32;
  for (int t = t0; t < t1; ++t) {
    int j0 = t * 32;
    const unsigned short* ah = hb + (size_t)(j0 + col) * NC + half * 8;
    f32x16 acc0, acc1;
#pragma unroll
    for (int r = 0; r < 16; ++r) { acc0[r] = 2.0f; acc1[r] = 0.f; }
    {
      short8 A[6];
#pragma unroll
      for (int ch = 0; ch < 6; ++ch) A[ch] = *(const short8*)(ah + ch * 16);
#pragma unroll
      for (int ch = 0; ch < 6; ++ch)
        acc0 = __builtin_amdgcn_mfma_f32_32x32x16_bf16(A[ch], Bh[ch], acc0, 0, 0, 0);
#pragma unroll
      for (int ch = 0; ch < 6; ++ch)
        acc1 = __builtin_amdgcn_mfma_f32_32x32x16_bf16(A[ch], Bl[ch], acc1, 0, 0, 0);
    }
    unsigned relbase = (unsigned)(j0 - jbase + 4 * half);
#pragma unroll
    for (int r = 0; r < 16; ++r) {
      float s = acc0[r] + acc1[r];            // = score + 2.0 (positive, in [1,3])
      unsigned kb = __float_as_uint(s);
      unsigned keyu = (kb & 0xFFFFFE00u) | (relbase + (unsigned)((r & 3) + 8 * (r >> 2)));
      float e = __uint_as_float(keyu);
#pragma unroll
      for (int s8 = NDEP - 1; s8 > 0; --s8)
        kk[s8] = __builtin_amdgcn_fmed3f(kk[s8 - 1], kk[s8], e);
      kk[0] = fmaxf(kk[0], e);
    }
  }

  // in-wave half-merge: top-9 of the two disjoint half-lists (merge-path identity)
  float c[NDEP];
#pragma unroll
  for (int k = 0; k < NDEP; ++k) {
    float pv = __shfl_xor(kk[NDEP - 1 - k], 32);
    c[k] = fmaxf(kk[k], pv);
  }
  if (half == 0) {
    unsigned* op = pk + (size_t)((size_t)b * NPT + i) * (NLIST * NDEP) + jsplit * NDEP;
#pragma unroll
    for (int k = 0; k < NDEP; ++k) op[k] = __float_as_uint(c[k]);
  }
}

// ------- K3b: fused select: u32 tournament top-16 -> f32 rescore -> exact top-9 --------
// XCD-affinity (b = bid&7). Phase A: u32 keys (score20 | j12) — unique by j, single
// shfl per butterfly step. Phase B: 4 lanes/cand f32 dot + shfl reduce. Phase C:
// rank-based ordering on exact u64 keys via 16 independent broadcasts.
__global__ __launch_bounds__(256) void k_select(const unsigned* __restrict__ pk,
                                                const float* __restrict__ fnT,
                                                int* __restrict__ nn_idx) {
  int wid = threadIdx.x >> 6, lane = threadIdx.x & 63;
  int bid = blockIdx.x;                    // grid exact: NROWS/4
  int b = bid & 7;                         // XCD affinity
  int rg = bid >> 3;                       // 0..783
  int row = b * NPT + rg * 4 + wid;
  const unsigned* p = pk + (size_t)row * (NLIST * NDEP);
  unsigned e0 = 0, e1 = 0, e2 = 0, e3 = 0;
  if (lane < 36) {
    uint4 v = *(const uint4*)&p[lane * 4];
    int g0 = lane * 4;
    int s0 = g0 / 9, s1 = (g0 + 1) / 9, s2 = (g0 + 2) / 9, s3 = (g0 + 3) / 9;
    int jb0 = ((98 * s0) >> 4) << 5, jb1 = ((98 * s1) >> 4) << 5;
    int jb2 = ((98 * s2) >> 4) << 5, jb3 = ((98 * s3) >> 4) << 5;
    // key = score bits[31:12] | global j (12 bits); unique since j unique
    e0 = (v.x & 0xFFFFF000u) | (unsigned)(jb0 + (int)(v.x & 0x1FFu));
    e1 = (v.y & 0xFFFFF000u) | (unsigned)(jb1 + (int)(v.y & 0x1FFu));
    e2 = (v.z & 0xFFFFF000u) | (unsigned)(jb2 + (int)(v.z & 0x1FFu));
    e3 = (v.w & 0xFFFFF000u) | (unsigned)(jb3 + (int)(v.w & 0x1FFu));
  }
  int myj = 0;
  for (int r = 0; r < NCAND; ++r) {
    unsigned a = e0 > e1 ? e0 : e1;
    unsigned bmx = e2 > e3 ? e2 : e3;
    unsigned loc = a > bmx ? a : bmx;
#pragma unroll
    for (int m = 1; m < 64; m <<= 1) {
      unsigned o = __shfl_xor(loc, m);
      loc = o > loc ? o : loc;
    }
    e0 = (e0 == loc) ? 0 : e0;
    e1 = (e1 == loc) ? 0 : e1;
    e2 = (e2 == loc) ? 0 : e2;
    e3 = (e3 == loc) ? 0 : e3;
    if ((lane >> 2) == r) myj = (int)(loc & 0xFFFu);
  }
  // Phase B: rescore candidate myj (4 lanes per candidate group)
  int sub = lane & 3;
  const float* fi = fnT + (size_t)row * RST + sub * 24;
  const float* fj = fnT + (size_t)((size_t)b * NPT + myj) * RST + sub * 24;
  float pd = 0.f;
#pragma unroll
  for (int c4 = 0; c4 < 6; ++c4) {
    float4 a4 = *(const float4*)&fi[c4 * 4];
    float4 v4 = *(const float4*)&fj[c4 * 4];
    pd = fmaf(a4.x, v4.x, pd); pd = fmaf(a4.y, v4.y, pd);
    pd = fmaf(a4.z, v4.z, pd); pd = fmaf(a4.w, v4.w, pd);
  }
  pd += __shfl_xor(pd, 1);
  pd += __shfl_xor(pd, 2);
  u64 mykey = ~0ull;
  if (sub == 0) {
    float sqj = fnT[(size_t)((size_t)b * NPT + myj) * RST + 96];
    float score = fmaf(-0.5f, sqj, pd);
    mykey = ((u64)score_to_key_exact(score) << 32) | (unsigned)myj;
  }
  // Phase C: rank-based top-9 ordering (independent broadcasts, no serial chain)
  u64 kt[NCAND];
#pragma unroll
  for (int t = 0; t < NCAND; ++t) kt[t] = shfl64(mykey, t * 4);
  if (sub == 0) {
    int rank = 0;
#pragma unroll
    for (int t = 0; t < NCAND; ++t) rank += (kt[t] < mykey) ? 1 : 0;
    if (rank < NK) {
      int* op = nn_idx + (size_t)row * NK;
      op[rank] = (int)(mykey & 0xFFFu);
    }
  }
}

// ---------------- K4: u (f32, +bg) and v (bf16) halves via compensated bf16 MFMA -------
__global__ __launch_bounds__(256, 4) void k_uv(const unsigned short* __restrict__ fth,
                                               const unsigned short* __restrict__ ftl,
                                               const unsigned short* __restrict__ Wuvh,
                                               const unsigned short* __restrict__ Wuvl,
                                               const float* __restrict__ bg,
                                               float* __restrict__ uvu,
                                               unsigned short* __restrict__ uvv) {
  int bid = blockIdx.x;        // 2352 = 8b * 98nt * 3og
  int b = bid & 7;
  int t = bid >> 3;            // 0..293
  int nt = t % 98;
  int og = t / 98;             // 0..2
  int w = threadIdx.x >> 6;
  int ot = og * 4 + w;         // 0..11
  int lane = threadIdx.x & 63;
  int col = lane & 31, half = lane >> 5;
  int n0 = nt * 32, o0 = ot * 32;

  const unsigned short* fhp = fth + ((size_t)b * NPT + n0 + col) * NC + half * 8;
  const unsigned short* flp = ftl + ((size_t)b * NPT + n0 + col) * NC + half * 8;
  const unsigned short* whp = Wuvh + (size_t)(o0 + col) * NC + half * 8;
  const unsigned short* wlp = Wuvl + (size_t)(o0 + col) * NC + half * 8;

  f32x16 acc0, acc1;
#pragma unroll
  for (int r = 0; r < 16; ++r) { acc0[r] = 0.f; acc1[r] = 0.f; }
#pragma unroll
  for (int ch = 0; ch < 6; ++ch) {
    short8 ahv = *(const short8*)(fhp + ch * 16);
    short8 alv = *(const short8*)(flp + ch * 16);
    short8 bhv = *(const short8*)(whp + ch * 16);
    short8 blv = *(const short8*)(wlp + ch * 16);
    acc0 = __builtin_amdgcn_mfma_f32_32x32x16_bf16(ahv, bhv, acc0, 0, 0, 0);
    acc1 = __builtin_amdgcn_mfma_f32_32x32x16_bf16(ahv, blv, acc1, 0, 0, 0);
    acc0 = __builtin_amdgcn_mfma_f32_32x32x16_bf16(alv, bhv, acc0, 0, 0, 0);
  }

  int o = o0 + col;
  if (o0 < NC2) {  // u half: f32 + bias
    float bias = bg[o];
    float* up = uvu + ((size_t)b * NPT + n0) * NC2 + o;
#pragma unroll
    for (int r = 0; r < 16; ++r) {
      int nrow = (r & 3) + 8 * (r >> 2) + 4 * half;
      up[(size_t)nrow * NC2] = acc0[r] + acc1[r] + bias;
    }
  } else {         // v half: bf16
    unsigned short* vp = uvv + ((size_t)b * NPT + n0) * NC2 + (o - NC2);
#pragma unroll
    for (int r = 0; r < 16; ++r) {
      int nrow = (r & 3) + 8 * (r >> 2) + 4 * half;
      vp[(size_t)nrow * NC2] = f32_to_bf16_rne(acc0[r] + acc1[r]);
    }
  }
}

// ---------------- K5: agg = relu(max_k (u + v[idx])) -> bf16 hi/lo rows [n][192] -------
__global__ __launch_bounds__(192) void k_gather(const float* __restrict__ uvu,
                                                const unsigned short* __restrict__ uvv,
                                                const int* __restrict__ nn_idx,
                                                unsigned short* __restrict__ aggh,
                                                unsigned short* __restrict__ aggl) {
  int bid = blockIdx.x;
  int b = bid & 7;      // XCD affinity: per-batch v table (1.2 MB bf16) is L2-resident
  int ng = bid >> 3;    // 0..783
  int tid = threadIdx.x;
  int nq = tid / 48, c4 = tid % 48;
  int n = ng * 4 + nq;
  const float* ub = uvu + (size_t)b * NPT * NC2;
  const unsigned short* vb = uvv + (size_t)b * NPT * NC2;
  const int* ip = nn_idx + ((size_t)b * NPT + n) * NK;
  float4 u = *(const float4*)&ub[(size_t)n * NC2 + c4 * 4];
  float4 acc = make_float4(-1e30f, -1e30f, -1e30f, -1e30f);
#pragma unroll
  for (int k = 0; k < NK; ++k) {
    int j = ip[k];
    ushort4 vv = *(const ushort4*)&vb[(size_t)j * NC2 + c4 * 4];
    float vx = __uint_as_float(((unsigned)vv.x) << 16);
    float vy = __uint_as_float(((unsigned)vv.y) << 16);
    float vz = __uint_as_float(((unsigned)vv.z) << 16);
    float vw = __uint_as_float(((unsigned)vv.w) << 16);
    acc.x = fmaxf(acc.x, u.x + vx);
    acc.y = fmaxf(acc.y, u.y + vy);
    acc.z = fmaxf(acc.z, u.z + vz);
    acc.w = fmaxf(acc.w, u.w + vw);
  }
  float o4[4];
  o4[0] = fmaxf(acc.x, 0.f); o4[1] = fmaxf(acc.y, 0.f);
  o4[2] = fmaxf(acc.z, 0.f); o4[3] = fmaxf(acc.w, 0.f);
  u64 hp = 0, lp = 0;
#pragma unroll
  for (int e = 0; e < 4; ++e) {
    unsigned short h = f32_to_bf16_rne(o4[e]);
    float hv = __uint_as_float(((unsigned)h) << 16);
    unsigned short l = f32_to_bf16_rne(o4[e] - hv);
    hp |= ((u64)h) << (16 * e);
    lp |= ((u64)l) << (16 * e);
  }
  size_t off = ((size_t)b * NPT + n) * NC2 + c4 * 4;
  *(u64*)&aggh[off] = hp;
  *(u64*)&aggl[off] = lp;
}

// ---------------- K6: out = W2 @ agg + b2f + residual, via compensated bf16 MFMA -------
__global__ __launch_bounds__(64, 4) void k_out(const unsigned short* __restrict__ W2h,
                                               const unsigned short* __restrict__ W2l,
                                               const unsigned short* __restrict__ aggh,
                                               const unsigned short* __restrict__ aggl,
                                               const float* __restrict__ b2f,
                                               const float* __restrict__ x,
                                               float* __restrict__ out) {
  int bid = blockIdx.x;        // 2352 = 8b * 98nt * 3ot
  int b = bid & 7;
  int t = bid >> 3;            // 0..293
  int nt = t % 98;
  int ot = t / 98;             // 0..2
  int lane = threadIdx.x;
  int col = lane & 31, half = lane >> 5;
  int n0 = nt * 32, o0 = ot * 32;

  const unsigned short* whp = W2h + (size_t)(o0 + col) * NC2 + half * 8;
  const unsigned short* wlp = W2l + (size_t)(o0 + col) * NC2 + half * 8;
  const unsigned short* ahp = aggh + ((size_t)b * NPT + n0 + col) * NC2 + half * 8;
  const unsigned short* alp = aggl + ((size_t)b * NPT + n0 + col) * NC2 + half * 8;

  f32x16 acc0, acc1;
#pragma unroll
  for (int r = 0; r < 16; ++r) { acc0[r] = 0.f; acc1[r] = 0.f; }
#pragma unroll
  for (int ch = 0; ch < 12; ++ch) {
    short8 whv = *(const short8*)(whp + ch * 16);
    short8 wlv = *(const short8*)(wlp + ch * 16);
    short8 ahv = *(const short8*)(ahp + ch * 16);
    short8 alv = *(const short8*)(alp + ch * 16);
    acc0 = __builtin_amdgcn_mfma_f32_32x32x16_bf16(whv, ahv, acc0, 0, 0, 0);
    acc1 = __builtin_amdgcn_mfma_f32_32x32x16_bf16(whv, alv, acc1, 0, 0, 0);
    acc0 = __builtin_amdgcn_mfma_f32_32x32x16_bf16(wlv, ahv, acc0, 0, 0, 0);
  }

  int n = n0 + col;
  const float* xb = x + (size_t)b * NC * NPT;
  float* ob = out + (size_t)b * NC * NPT;
#pragma unroll
  for (int r = 0; r < 16; ++r) {
    int orow = o0 + (r & 3) + 8 * (r >> 2) + 4 * half;
    float v = acc0[r] + acc1[r] + b2f[orow] + xb[(size_t)orow * NPT + n];
    ob[(size_t)orow * NPT + n] = v;
  }
}

extern "C" void kernel_launch(void* const* d_in, const int* in_sizes, int n_in,
                              void* d_out, int out_size, void* d_ws, size_t ws_size,
                              hipStream_t stream) {
  const float* x  = (const float*)d_in[0];
  const float* W1 = (const float*)d_in[1];
  const float* b1 = (const float*)d_in[2];
  const float* g1 = (const float*)d_in[3];
  const float* be1= (const float*)d_in[4];
  const float* m1 = (const float*)d_in[5];
  const float* v1 = (const float*)d_in[6];
  const float* Wg = (const float*)d_in[7];
  const float* bg = (const float*)d_in[8];
  const float* W2 = (const float*)d_in[9];
  const float* b2 = (const float*)d_in[10];
  const float* g2 = (const float*)d_in[11];
  const float* be2= (const float*)d_in[12];
  const float* m2 = (const float*)d_in[13];
  const float* v2 = (const float*)d_in[14];
  float* out = (float*)d_out;

  float* ws = (float*)d_ws;
  size_t off = 0;
  unsigned short* fth = (unsigned short*)(ws + off); off += (size_t)NB * NPT * NC / 2;  // 4.8 MB
  unsigned short* ftl = (unsigned short*)(ws + off); off += (size_t)NB * NPT * NC / 2;  // 4.8 MB
  unsigned short* hiT = (unsigned short*)(ws + off); off += (size_t)NB * NPT * NC / 2;  // 4.8 MB
  unsigned short* loT = (unsigned short*)(ws + off); off += (size_t)NB * NPT * NC / 2;  // 4.8 MB
  float* uvu  = ws + off; off += (size_t)NB * NPT * NC2;            // 19.3 MB (u half, f32)
  unsigned short* uvv = (unsigned short*)(ws + off); off += (size_t)NB * NPT * NC2 / 2; // 9.6 MB
  float* aggr = ws + off; off += (size_t)NB * NPT * NC2;            // 19.3 MB (fnT / aggh+aggl)
  float* W1s  = ws + off; off += NC * NC;
  unsigned short* Wuvh = (unsigned short*)(ws + off); off += NC * NC2;      // 36864 u16
  unsigned short* Wuvl = (unsigned short*)(ws + off); off += NC * NC2;
  unsigned short* W2h  = (unsigned short*)(ws + off); off += NC * NC2 / 2;  // 18432 u16
  unsigned short* W2l  = (unsigned short*)(ws + off); off += NC * NC2 / 2;
  float* b1f  = ws + off; off += 128;
  float* b2f  = ws + off; off += 128;

  // Phase-disjoint overlays:
  //   fnT (10.4 MB) in aggr region; dead after k_select.
  //   aggh/aggl (9.6+9.6 MB) in aggr region; written by k_gather (after select).
  //   pk (14.5 MB) overlays uvu (19.3 MB); consumed by k_select before k_uv writes.
  //   nn_idx -> loT region (dead after k_knn).
  float* fnT    = aggr;
  unsigned short* aggh = (unsigned short*)aggr;
  unsigned short* aggl = aggh + (size_t)NB * NPT * NC2;
  unsigned* pk  = (unsigned*)uvu;
  int* nn_idx   = (int*)loT;

  k_fuse<<<dim3(64), 256, 0, stream>>>(W1, b1, g1, be1, m1, v1, Wg, W2, b2, g2, be2, m2, v2,
                                       W1s, b1f, Wuvh, Wuvl, W2h, W2l, b2f);
  k_feat<<<dim3(NB * 196), 64, 0, stream>>>(x, W1s, b1f, fth, ftl, fnT, hiT, loT);
  k_knn<<<dim3(NB * 98 * 4), 256, 0, stream>>>(hiT, loT, pk);
  k_select<<<dim3(NROWS / 4), 256, 0, stream>>>(pk, fnT, nn_idx);
  k_uv<<<dim3(NB * 98 * 3), 256, 0, stream>>>(fth, ftl, Wuvh, Wuvl, bg, uvu, uvv);
  k_gather<<<dim3(NB * NPT / 4), 192, 0, stream>>>(uvu, uvv, nn_idx, aggh, aggl);
  k_out<<<dim3(NB * 98 * 3), 64, 0, stream>>>(W2h, W2l, aggh, aggl, b2f, x, out);
}